// Round 8
// baseline (3333.515 us; speedup 1.0000x reference)
//
#include <hip/hip_runtime.h>
#include <hip/hip_bf16.h>
#include <float.h>

typedef __hip_bfloat16 bf16;
typedef unsigned short u16;
typedef unsigned long long u64;
typedef __attribute__((ext_vector_type(8))) short bh8;   // 8 bf16 = 4 VGPRs (MFMA A/B frag)
typedef __attribute__((ext_vector_type(4))) float fx4;   // MFMA C/D frag

#define NEG_BIG (-1.0e30f)

__device__ __forceinline__ bf16 f2b(float v){ return __float2bfloat16(v); }
__device__ __forceinline__ float lrelu(float x){ return x >= 0.f ? x : 0.2f*x; }

// round-to-nearest-even fp32 -> bf16 bits
__device__ __forceinline__ u16 f2bf_rne(float x){
  unsigned u = __float_as_uint(x);
  unsigned r = (u + 0x7FFFu + ((u >> 16) & 1u)) >> 16;
  return (u16)r;
}

// dtype-flexible sanitized load from a raw INPUT buffer (element index)
__device__ __forceinline__ float ldx(const void* p, size_t i, int isbf){
  float v = isbf ? __bfloat162float(((const bf16*)p)[i]) : ((const float*)p)[i];
  return (v == v && fabsf(v) < 1e30f) ? v : 0.f;
}
// dtype-flexible store to the OUTPUT buffer (element index)
__device__ __forceinline__ void stout(void* p, size_t i, float v, int isbf){
  if (isbf) ((bf16*)p)[i] = f2b(v);
  else      ((float*)p)[i] = v;
}

// ---- packed sort keys: (value desc, index asc) lexicographic == u64 '>' ----
// key = ord(d)<<32 | ~j  where ord is the monotone float->uint map.
// Keys are unique per (d,j) since j is unique -> no tie edge cases on '>'.
// IMPORTANT (round-7 lesson): pack ONLY on filter survivors — packing per
// candidate taxes the common path more than the key-insert saves.
__device__ __forceinline__ u64 dkey(float d, int j){
  unsigned u = __float_as_uint(d);
  u ^= (unsigned)(((int)u) >> 31) | 0x80000000u;
  return ((u64)u << 32) | (u64)(~(unsigned)j);
}
__device__ __forceinline__ float key_d(u64 k){
  unsigned u = (unsigned)(k >> 32);
  u = (u & 0x80000000u) ? (u ^ 0x80000000u) : ~u;
  return __uint_as_float(u);
}
__device__ __forceinline__ int key_j(u64 k){ return (int)~(unsigned)k; }

// carry-chain sorted top-K insert on packed keys (kv descending, kv[K-1] = min).
// Single compare chain + single select chain (~half the old float+int dual cost).
template<int K>
__device__ __forceinline__ void topk_key(u64 (&kv)[K], u64 k){
  if (k > kv[K-1]){
    bool gt[K];
    #pragma unroll
    for (int s = 0; s < K; s++) gt[s] = k > kv[s];
    #pragma unroll
    for (int s = K-1; s > 0; s--){
      u64 nv = gt[s-1] ? kv[s-1] : k;
      kv[s] = gt[s] ? nv : kv[s];
    }
    if (gt[0]) kv[0] = k;
  }
}

// legacy float/int insert (knn64 path only): strict >, ascending-scan tie semantics
template<int K>
__device__ __forceinline__ void topk_ins(float (&bv)[K], int (&bi)[K], float d, int j){
  if (d > bv[K-1]){
    bool gt[K];
    #pragma unroll
    for (int s = 0; s < K; s++) gt[s] = d > bv[s];
    #pragma unroll
    for (int s = K-1; s > 0; s--){
      float nv = gt[s-1] ? bv[s-1] : d;
      int   ni = gt[s-1] ? bi[s-1] : j;
      bv[s] = gt[s] ? nv : bv[s];
      bi[s] = gt[s] ? ni : bi[s];
    }
    if (gt[0]){ bv[0] = d; bi[0] = j; }
  }
}

// ---------------- input dtype detector ----------------
__global__ void detect_kernel(const unsigned int* __restrict__ X, int* __restrict__ flag){
  __shared__ int cnt;
  if (threadIdx.x == 0) cnt = 0;
  __syncthreads();
  int hits = 0;
  for (int i = threadIdx.x; i < 8192; i += 256){
    unsigned w = X[i];
    unsigned lo = w & 0xFFFFu;
    unsigned e = (lo >> 7) & 0xFFu;
    if ((e >= 0x76u && e <= 0x84u) || lo == 0u) hits++;
  }
  atomicAdd(&cnt, hits);
  __syncthreads();
  if (threadIdx.x == 0) flag[0] = (cnt > 4096) ? 1 : 0;
}

// ---------------- weight prep ----------------
__global__ void wt_kernel(const void* __restrict__ W, const int* __restrict__ dtf,
                          int Cout, int pitch, int coff, int Cin, float* __restrict__ WT){
  int i = blockIdx.x*256 + threadIdx.x;
  if (i >= Cin*Cout) return;
  int isbf = *dtf;
  int c = i / Cout, o = i - c*Cout;
  WT[i] = ldx(W, (size_t)o*pitch + coff + c, isbf);
}

__global__ void w0_kernel(const void* __restrict__ W0, const int* __restrict__ dtf,
                          int C, float* __restrict__ WaT, float* __restrict__ WqT){
  int i = blockIdx.x*256 + threadIdx.x;
  if (i >= C*64) return;
  int isbf = *dtf;
  int c = i >> 6, o = i & 63;
  float a = ldx(W0, (size_t)o*2*C + c, isbf);
  float q = ldx(W0, (size_t)o*2*C + C + c, isbf);
  WaT[i] = a; WqT[i] = q - a;
}

__global__ void xconv_kernel(const void* __restrict__ x, const int* __restrict__ dtf,
                             float* __restrict__ xfT){
  int i = blockIdx.x*256 + threadIdx.x;
  if (i >= 4*4096) return;
  int isbf = *dtf;
  int b = i >> 12, n = i & 4095;
  for (int c = 0; c < 9; c++)
    xfT[((size_t)b*4096 + n)*9 + c] = ldx(x, ((size_t)b*9 + c)*4096 + n, isbf);
}

__global__ void nodecopy_kernel(const void* __restrict__ x, const int* __restrict__ dtf,
                                void* __restrict__ out){
  int i = blockIdx.x*256 + threadIdx.x;
  int isbf = *dtf;
  if (i < 12288){
    int b = i / 3072, r = i % 3072; int c = r / 1024, m = r % 1024;
    stout(out, 212992 + i, ldx(x, ((size_t)b*9 + c)*4096 + m, isbf), isbf);
  } else if (i < 15360){
    int j = i - 12288; int b = j / 768, r = j % 768; int c = r / 256, m = r % 256;
    stout(out, 212992 + i, ldx(x, ((size_t)b*9 + c)*4096 + m, isbf), isbf);
  } else if (i < 16128){
    int j = i - 15360; int b = j / 192, r = j % 192; int c = r / 64, m = r % 64;
    stout(out, 212992 + i, ldx(x, ((size_t)b*9 + c)*4096 + m, isbf), isbf);
  }
}

// ---------------- kNN ----------------
__global__ void rownorm_kernel(const float* __restrict__ T, int pitch, size_t bs,
                               int C, int N, float* __restrict__ rr){
  int n = blockIdx.x*256 + threadIdx.x;
  int b = blockIdx.y;
  if (n >= N) return;
  const float* row = T + (size_t)b*bs + (size_t)n*pitch;
  float s = 0.f;
  for (int c = 0; c < C; c++) s = fmaf(row[c], row[c], s);
  rr[b*N + n] = s;
}

// small-C chunked kNN (C=3/9; per-thread query in registers, refs staged in LDS).
// Refs staged TRANSPOSED [c][t]: wave-uniform ds_read_b128 broadcasts (4 cands/read).
// K>=8: FLOAT-gated (d >= tau, 1 cmp) per-thread LDS FIFO of packed keys (pack only
//   on survivors) + per-tile drains + overflow drain.  Exact: tau = value(kv[K-1])
//   at last drain is only more permissive; key insert is order-independent with
//   (value, lower-j) semantics.
// REQUIREMENT: len = N/NC must be a multiple of TN.
template<int C, int K, int TN>
__global__ void knn_chunk_kernel(const float* __restrict__ qT, int qpitch, size_t qbs,
                                 const float* __restrict__ rT, int rpitch, size_t rbs,
                                 const float* __restrict__ rr, int M, int N, int NC,
                                 float* __restrict__ cval, int* __restrict__ cidx){
  constexpr bool FIFO = (K >= 8);
  constexpr int CAP = 16;
  __shared__ __align__(16) float sRT[C*TN];   // [c][t]
  __shared__ __align__(16) float sN[TN];
  __shared__ u64 sQ[FIFO ? 256*(CAP+1) : 1];  // per-thread FIFO, stride 17 u64
  int tid = threadIdx.x;
  int m = blockIdx.x*256 + tid;
  int cid = blockIdx.y, b = blockIdx.z;
  int len = N / NC;
  int n0 = cid * len;
  bool active = (m < M);
  float q[C]; float qq = 0.f;
  if (active){
    const float* qrow = qT + (size_t)b*qbs + (size_t)m*qpitch;
    #pragma unroll
    for (int c = 0; c < C; c++){ q[c] = qrow[c]; qq = fmaf(q[c], q[c], qq); }
  }
  u64 kv[K];
  #pragma unroll
  for (int j = 0; j < K; j++) kv[j] = dkey(NEG_BIG, n0);
  float tau = NEG_BIG;
  u64* qb = FIFO ? &sQ[tid*(CAP+1)] : (u64*)nullptr;
  int qcnt = 0;
  const float* rbase = rT + (size_t)b*rbs;
  const float* rrb = rr + b*N;

  auto drain = [&](){
    int k = 0;
    while (__any(k < qcnt)){
      if (k < qcnt) topk_key<K>(kv, qb[k]);
      k++;
    }
    qcnt = 0;
    tau = key_d(kv[K-1]);
  };

  for (int t0 = 0; t0 < len; t0 += TN){
    __syncthreads();
    for (int i = tid; i < TN*C; i += 256){
      int c = i / TN, t = i - c*TN;
      sRT[i] = rbase[(size_t)(n0 + t0 + t)*rpitch + c];
    }
    for (int i = tid; i < TN; i += 256) sN[i] = rrb[n0 + t0 + i];
    __syncthreads();
    if (active){
      for (int t = 0; t < TN; t += 4){
        float a0 = 0.f, a1 = 0.f, a2 = 0.f, a3 = 0.f;
        #pragma unroll
        for (int c = 0; c < C; c++){
          float4 rv = *(const float4*)&sRT[c*TN + t];
          float qc = q[c];
          a0 = fmaf(qc, rv.x, a0); a1 = fmaf(qc, rv.y, a1);
          a2 = fmaf(qc, rv.z, a2); a3 = fmaf(qc, rv.w, a3);
        }
        float4 nn = *(const float4*)&sN[t];
        int jb = n0 + t0 + t;
        float d0 = 2.f*a0 - qq - nn.x;
        float d1 = 2.f*a1 - qq - nn.y;
        float d2 = 2.f*a2 - qq - nn.z;
        float d3 = 2.f*a3 - qq - nn.w;
        if constexpr (FIFO){
          if (__any(qcnt >= CAP-4)) drain();    // guarantees room for 4
          if (d0 >= tau){ qb[qcnt] = dkey(d0, jb+0); qcnt++; }
          if (d1 >= tau){ qb[qcnt] = dkey(d1, jb+1); qcnt++; }
          if (d2 >= tau){ qb[qcnt] = dkey(d2, jb+2); qcnt++; }
          if (d3 >= tau){ qb[qcnt] = dkey(d3, jb+3); qcnt++; }
        } else {
          // K=1 path: strict > keeps earlier (lower) index on ascending scan
          if (d0 > tau){ topk_key<K>(kv, dkey(d0, jb+0)); tau = key_d(kv[K-1]); }
          if (d1 > tau){ topk_key<K>(kv, dkey(d1, jb+1)); tau = key_d(kv[K-1]); }
          if (d2 > tau){ topk_key<K>(kv, dkey(d2, jb+2)); tau = key_d(kv[K-1]); }
          if (d3 > tau){ topk_key<K>(kv, dkey(d3, jb+3)); tau = key_d(kv[K-1]); }
        }
      }
    }
    if constexpr (FIFO){ drain(); }             // inactive lanes: qcnt==0, no-op
  }
  if (active){
    float* ov = cval + ((size_t)((size_t)b*M + m)*NC + cid)*K;
    int*   oi = cidx + ((size_t)((size_t)b*M + m)*NC + cid)*K;
    #pragma unroll
    for (int j = 0; j < K; j++){ ov[j] = key_d(kv[j]); oi[j] = key_j(kv[j]); }
  }
}

// C=64 self-kNN scan (legacy path, kept for N<=256): 1-wave blocks, queries in VGPRs.
template<int K>
__launch_bounds__(64, 2)
__global__ void knn64_kernel(const float* __restrict__ fT, const float* __restrict__ rr,
                             int N, int NC, float* __restrict__ cval, int* __restrict__ cidx){
  int lane = threadIdx.x;
  int q0 = blockIdx.x*64;
  int cid = blockIdx.y, b = blockIdx.z;
  int m = q0 + lane;
  int len = N / NC;
  int n0 = cid*len;
  float4 q4[16];
  {
    const float4* qp = (const float4*)(fT + ((size_t)b*N + m)*64);
    #pragma unroll
    for (int i = 0; i < 16; i++) q4[i] = qp[i];
  }
  float qq = rr[(size_t)b*N + m];   // self-kNN (M==N)
  float bv[K]; int bi[K];
  #pragma unroll
  for (int j = 0; j < K; j++){ bv[j] = NEG_BIG; bi[j] = n0; }
  const float4* rbase = (const float4*)(fT + ((size_t)b*N + n0)*64);
  const float* rrb = rr + (size_t)b*N + n0;
  for (int t0 = 0; t0 < len; t0 += 4){
    const float4* r4 = rbase + (size_t)t0*16;
    float a0=0.f, a1=0.f, a2=0.f, a3=0.f;
    #pragma unroll
    for (int ct = 0; ct < 16; ct++){
      float4 v0 = r4[ct], v1 = r4[16+ct], v2 = r4[32+ct], v3 = r4[48+ct];
      float4 qv = q4[ct];
      a0 = fmaf(qv.x,v0.x,a0); a0 = fmaf(qv.y,v0.y,a0); a0 = fmaf(qv.z,v0.z,a0); a0 = fmaf(qv.w,v0.w,a0);
      a1 = fmaf(qv.x,v1.x,a1); a1 = fmaf(qv.y,v1.y,a1); a1 = fmaf(qv.z,v1.z,a1); a1 = fmaf(qv.w,v1.w,a1);
      a2 = fmaf(qv.x,v2.x,a2); a2 = fmaf(qv.y,v2.y,a2); a2 = fmaf(qv.z,v2.z,a2); a2 = fmaf(qv.w,v2.w,a2);
      a3 = fmaf(qv.x,v3.x,a3); a3 = fmaf(qv.y,v3.y,a3); a3 = fmaf(qv.z,v3.z,a3); a3 = fmaf(qv.w,v3.w,a3);
    }
    topk_ins<K>(bv, bi, 2.f*a0 - qq - rrb[t0+0], n0+t0+0);
    topk_ins<K>(bv, bi, 2.f*a1 - qq - rrb[t0+1], n0+t0+1);
    topk_ins<K>(bv, bi, 2.f*a2 - qq - rrb[t0+2], n0+t0+2);
    topk_ins<K>(bv, bi, 2.f*a3 - qq - rrb[t0+3], n0+t0+3);
  }
  float* ov = cval + ((size_t)((size_t)b*N + m)*NC + cid)*K;
  int*   oi = cidx + ((size_t)((size_t)b*N + m)*NC + cid)*K;
  #pragma unroll
  for (int j = 0; j < K; j++){ ov[j] = bv[j]; oi[j] = bi[j]; }
}

// fp32 -> (hi, lo) bf16 split, stored PRE-SWIZZLED (c ^= (row&7)<<3) so that the
// kNN MFMA kernel can stage LDS tiles with linear copies and read ds_read_b128
// fragments bank-conflict-optimally (G4/T2 recipe).
__global__ void bfsplit_kernel(const float* __restrict__ fT, int N,
                               u16* __restrict__ hi, u16* __restrict__ lo){
  int i = blockIdx.x*256 + threadIdx.x;      // over 4*N*64
  if (i >= 4*N*64) return;
  int c = i & 63;
  int n = i >> 6;                            // combined row b*N + ln; N % 8 == 0 so n&7 == ln&7
  float x = fT[i];
  u16 h = f2bf_rne(x);
  float hf = __uint_as_float((unsigned)h << 16);
  u16 l = f2bf_rne(x - hf);
  size_t o = ((size_t)n << 6) + (c ^ ((n & 7) << 3));
  hi[o] = h; lo[o] = l;
}

// MFMA feature-space self-kNN (C=64).  exact-ish distances via bf16 hi/lo split:
// inner = hi·hi + hi·lo + lo·hi (3x mfma_f32_16x16x32_bf16, fp32 accum, rel err ~2^-17).
// D[ref][query] orientation: lane = (g=l>>4, lm=l&15) holds query (qblk+w*16+lm)'s
// distances for refs {tile + m*16 + 4g + i}.
// Selection: FLOAT threshold tau = fmax over the 4 partition-lanes of value(kv[K-1])
// (2x shfl_xor), refreshed per tile; candidates with d >= tau (1 cmp) get packed
// (pack-on-survivor only) into a per-thread 16-entry LDS FIFO (cap proof: drained
// every tile, max 16 pushes/tile); drain runs the single-chain u64 insert.
// Exact: skipped => d < tau <= global-20th value => not in answer; keys make the
// insert order-independent (value, lower-j); cross-partition merge by key.
template<int K>
__launch_bounds__(256, 2)
__global__ void knnmf_kernel(const u16* __restrict__ hi, const u16* __restrict__ lo,
                             const float* __restrict__ rr, int N, int NC,
                             float* __restrict__ cval, int* __restrict__ cidx){
  __shared__ __align__(16) u16 sHi[64*64];     // 8 KB, swizzled rows
  __shared__ __align__(16) u16 sLo[64*64];     // 8 KB
  __shared__ float sRR[64];
  __shared__ u64 sQ[256*17];                   // per-thread 16-entry FIFO, stride 17 (34 KB)

  const int tid  = threadIdx.x;
  const int lane = tid & 63, w = tid >> 6;
  const int g    = lane >> 4;                  // 0..3
  const int lm   = lane & 15;
  const int qblk = blockIdx.x * 64;
  const int cid  = blockIdx.y, b = blockIdx.z;
  const int len  = N / NC, n0 = cid * len;

  const u16*  hib = hi + (size_t)b*N*64;
  const u16*  lob = lo + (size_t)b*N*64;
  const float* rrb = rr + (size_t)b*N;

  // ---- stage this block's 64 query rows, pull B-fragments into registers ----
  {
    const float4* sh = (const float4*)(hib + (size_t)qblk*64);
    const float4* sl = (const float4*)(lob + (size_t)qblk*64);
    float4* dh = (float4*)sHi; float4* dl = (float4*)sLo;
    for (int i = tid; i < 512; i += 256){ dh[i] = sh[i]; dl[i] = sl[i]; }
  }
  __syncthreads();
  const int qrow = w*16 + lm;                  // wave w owns queries qblk + w*16 .. +15
  const int kb0 = 8*g, kb1 = 32 + 8*g;         // frag k-offsets: k = koff + 8*(lane>>4) + i
  const int qsw = (qrow & 7) << 3;
  const bh8 qh0 = *(const bh8*)&sHi[qrow*64 + (kb0 ^ qsw)];
  const bh8 qh1 = *(const bh8*)&sHi[qrow*64 + (kb1 ^ qsw)];
  const bh8 ql0 = *(const bh8*)&sLo[qrow*64 + (kb0 ^ qsw)];
  const bh8 ql1 = *(const bh8*)&sLo[qrow*64 + (kb1 ^ qsw)];
  const float qq = rrb[qblk + qrow];

  u64 kv[K];
  #pragma unroll
  for (int j = 0; j < K; j++) kv[j] = dkey(NEG_BIG, n0);
  float tau = NEG_BIG;                         // permissive until first drain
  u64* qbase = &sQ[tid*17];
  int qcnt = 0;

  for (int t0 = n0; t0 < n0 + len; t0 += 64){
    __syncthreads();                           // previous tile's frag reads done
    {
      const float4* sh = (const float4*)(hib + (size_t)t0*64);
      const float4* sl = (const float4*)(lob + (size_t)t0*64);
      float4* dh = (float4*)sHi; float4* dl = (float4*)sLo;
      for (int i = tid; i < 512; i += 256){ dh[i] = sh[i]; dl[i] = sl[i]; }
      if (tid < 64) sRR[tid] = rrb[t0 + tid];
    }
    __syncthreads();
    for (int m = 0; m < 4; m++){
      const int rrow = m*16 + lm;              // A-frag row owned by this lane
      const int sw = (rrow & 7) << 3;
      const bh8 ah0 = *(const bh8*)&sHi[rrow*64 + (kb0 ^ sw)];
      const bh8 ah1 = *(const bh8*)&sHi[rrow*64 + (kb1 ^ sw)];
      const bh8 al0 = *(const bh8*)&sLo[rrow*64 + (kb0 ^ sw)];
      const bh8 al1 = *(const bh8*)&sLo[rrow*64 + (kb1 ^ sw)];
      fx4 acc = {0.f, 0.f, 0.f, 0.f};
      acc = __builtin_amdgcn_mfma_f32_16x16x32_bf16(ah0, qh0, acc, 0, 0, 0);
      acc = __builtin_amdgcn_mfma_f32_16x16x32_bf16(ah1, qh1, acc, 0, 0, 0);
      acc = __builtin_amdgcn_mfma_f32_16x16x32_bf16(ah0, ql0, acc, 0, 0, 0);
      acc = __builtin_amdgcn_mfma_f32_16x16x32_bf16(ah1, ql1, acc, 0, 0, 0);
      acc = __builtin_amdgcn_mfma_f32_16x16x32_bf16(al0, qh0, acc, 0, 0, 0);
      acc = __builtin_amdgcn_mfma_f32_16x16x32_bf16(al1, qh1, acc, 0, 0, 0);
      const float4 rr4 = *(const float4*)&sRR[m*16 + 4*g];   // broadcast within 16-lane group
      const float rrv[4] = {rr4.x, rr4.y, rr4.z, rr4.w};
      const int jb = t0 + m*16 + 4*g;          // C/D rows: lane holds rows 4g+i
      #pragma unroll
      for (int i = 0; i < 4; i++){
        float d = fmaf(2.f, acc[i], -(qq + rrv[i]));
        if (d >= tau){                         // float gate; pack only on survivors
          qbase[qcnt] = dkey(d, jb + i);
          qcnt++;                              // <=16 pushes/tile, CAP=16
        }
      }
    }
    // per-tile FIFO drain (key order-independent, exact)
    {
      int k = 0;
      while (__any(k < qcnt)){
        if (k < qcnt) topk_key<K>(kv, qbase[k]);
        k++;
      }
      qcnt = 0;
    }
    // refresh shared threshold: float max of the 4 partition-lanes' K-th values
    {
      float t = key_d(kv[K-1]);
      t = fmaxf(t, __shfl_xor(t, 16));
      t = fmaxf(t, __shfl_xor(t, 32));
      tau = t;
    }
  }
  const int q = qblk + qrow;
  const size_t rowo = (((size_t)b*N + q)*(size_t)(NC*4) + (size_t)(cid*4 + g))*(size_t)K;
  float* ov = cval + rowo; int* oi = cidx + rowo;
  #pragma unroll
  for (int j = 0; j < K; j++){ ov[j] = key_d(kv[j]); oi[j] = key_j(kv[j]); }
}

// key-based merge: (value desc, index asc) == u64 '>' -- order-independent, serves
// all producers (reproduces old TB=false semantics too, since equal-value keeps
// the smaller index regardless of scan order).
template<int K>
__global__ void knn_merge_kernel(const float* __restrict__ cval, const int* __restrict__ cidx,
                                 int M, int NC, int* __restrict__ idxo){
  int i = blockIdx.x*256 + threadIdx.x;   // b*M + m
  if (i >= 4*M) return;
  const float* cv = cval + (size_t)i*NC*K;
  const int*   ci = cidx + (size_t)i*NC*K;
  u64 kv[K];
  #pragma unroll
  for (int j = 0; j < K; j++) kv[j] = dkey(NEG_BIG, 0);
  int T = NC*K;
  for (int t = 0; t < T; t++)
    topk_key<K>(kv, dkey(cv[t], ci[t]));
  int* orow = idxo + (size_t)i*K;
  #pragma unroll
  for (int j = 0; j < K; j++) orow[j] = key_j(kv[j]);
}

// ---------------- edge conv ----------------
__global__ void pq_kernel(const float* __restrict__ xT, int pitch, int C,
                          const float* __restrict__ WaT,
                          float* __restrict__ P, int N){
  int o = threadIdx.x & 63;
  int n = blockIdx.x*4 + (threadIdx.x >> 6);
  int b = blockIdx.y;
  if (n >= N) return;
  const float* row = xT + ((size_t)b*N + n)*pitch;
  float ap = 0.f;
  for (int c = 0; c < C; c++) ap = fmaf(WaT[c*64 + o], row[c], ap);
  P[((size_t)b*N + n)*64 + o] = ap;
}

// 4 points per 256-thread block: shared W1 tile, per-point sH. N % 4 == 0.
__global__ void edge2_kernel(const float* __restrict__ P, const float* __restrict__ featT,
                             int pitch, int C, const float* __restrict__ WqT,
                             const int* __restrict__ idx, const float* __restrict__ W1T,
                             float* __restrict__ outT, int N, int mask){
  __shared__ float sW[64*64];     // [c][o]
  __shared__ float sH[4*20*64];   // [t][kk][c]
  __shared__ float sx[4*64];
  int tid = threadIdx.x;
  int o = tid & 63, t = tid >> 6;
  int n = blockIdx.x*4 + t;
  int b = blockIdx.y;
  const float4* w4 = (const float4*)W1T;
  float4* s4 = (float4*)sW;
  for (int i = tid; i < 1024; i += 256) s4[i] = w4[i];
  if (o < C) sx[t*64 + o] = featT[((size_t)b*N + n)*pitch + o];
  __syncthreads();
  float qv = 0.f;
  for (int c = 0; c < C; c++) qv = fmaf(WqT[c*64 + o], sx[t*64 + c], qv);
  const float* Pb = P + (size_t)b*N*64;
  const int* irow = idx + ((size_t)b*N + n)*20;
  float* sHt = sH + t*1280;
  for (int kk = 0; kk < 20; kk++){
    int j = irow[kk] & mask;
    float h = Pb[(size_t)j*64 + o] + qv;
    sHt[kk*64 + o] = h >= 0.f ? h : 0.2f*h;
  }
  __syncthreads();
  float acc[20];
  #pragma unroll
  for (int kk = 0; kk < 20; kk++) acc[kk] = 0.f;
  for (int c = 0; c < 64; c += 4){
    float w0 = sW[c*64+o], w1 = sW[(c+1)*64+o], w2 = sW[(c+2)*64+o], w3 = sW[(c+3)*64+o];
    #pragma unroll
    for (int kk = 0; kk < 20; kk++){
      float4 h4 = *(const float4*)&sHt[kk*64 + c];
      float a = acc[kk];
      a = fmaf(w0, h4.x, a); a = fmaf(w1, h4.y, a);
      a = fmaf(w2, h4.z, a); a = fmaf(w3, h4.w, a);
      acc[kk] = a;
    }
  }
  float m = NEG_BIG;
  #pragma unroll
  for (int kk = 0; kk < 20; kk++) m = fmaxf(m, acc[kk]);
  outT[((size_t)b*N + n)*64 + o] = lrelu(m);
}

// 4 points per 256-thread block. N % 4 == 0.
__global__ void edge1_kernel(const float* __restrict__ P, const float* __restrict__ featT,
                             int pitch, int C, const float* __restrict__ WqT,
                             const int* __restrict__ idx, float* __restrict__ outT,
                             int N, int K, int mask){
  __shared__ float sx[4*64];
  int tid = threadIdx.x;
  int o = tid & 63, t = tid >> 6;
  int n = blockIdx.x*4 + t;
  int b = blockIdx.y;
  if (o < C) sx[t*64 + o] = featT[((size_t)b*N + n)*pitch + o];
  __syncthreads();
  float qv = 0.f;
  for (int c = 0; c < C; c++) qv = fmaf(WqT[c*64 + o], sx[t*64 + c], qv);
  const float* Pb = P + (size_t)b*N*64;
  const int* irow = idx + ((size_t)b*N + n)*K;
  float m = NEG_BIG;
  for (int kk = 0; kk < K; kk++){
    int j = irow[kk] & mask;
    m = fmaxf(m, Pb[(size_t)j*64 + o] + qv);
  }
  outT[((size_t)b*N + n)*64 + o] = lrelu(m);
}

__global__ void gmax_kernel(const float* __restrict__ inT, const int* __restrict__ idx,
                            float* __restrict__ outT, int Nin, int M, int K, int mask){
  int o = threadIdx.x; int m = blockIdx.x; int b = blockIdx.y;
  const float* ib = inT + (size_t)b*Nin*64;
  const int* irow = idx + ((size_t)b*M + m)*K;
  float v = NEG_BIG;
  for (int kk = 0; kk < K; kk++){
    int j = irow[kk] & mask;
    v = fmaxf(v, ib[(size_t)j*64 + o]);
  }
  outT[((size_t)b*M + m)*64 + o] = v;
}

__global__ void reluadd_kernel(float* __restrict__ x, const float* __restrict__ f, int total){
  int i = blockIdx.x*256 + threadIdx.x;
  if (i >= total) return;
  float v = x[i] + f[i];
  x[i] = v > 0.f ? v : 0.f;
}

// ---------------- global feature path ----------------
// W row (64 floats) held in REGISTERS per thread; x chunk staged in LDS and read via
// ds_read_b128 wave-broadcast (all lanes same address -> conflict-free, 4 vals/instr).
__launch_bounds__(256, 4)
__global__ void pool_kernel(const float* __restrict__ xT, const void* __restrict__ W,
                            const int* __restrict__ dtf, float* __restrict__ partial,
                            int N, int npts, int segbase){
  __shared__ __align__(16) float sX[32*64];   // 8 KB
  int tid = threadIdx.x;
  int ot = blockIdx.x, chunk = blockIdx.y, b = blockIdx.z;
  int isbf = *dtf;
  int o = ot*256 + tid;
  float wr[64];
  #pragma unroll
  for (int c = 0; c < 64; c++) wr[c] = ldx(W, (size_t)o*64 + c, isbf);
  int n0 = chunk * npts;
  float m = NEG_BIG;
  for (int s0 = 0; s0 < npts; s0 += 32){
    __syncthreads();
    const float4* src = (const float4*)(xT + ((size_t)b*N + n0 + s0)*64);
    float4* dst = (float4*)sX;
    for (int i = tid; i < 512; i += 256) dst[i] = src[i];
    __syncthreads();
    for (int t = 0; t < 32; t += 4){
      float a0 = 0.f, a1 = 0.f, a2 = 0.f, a3 = 0.f;
      #pragma unroll
      for (int c4 = 0; c4 < 16; c4++){
        float4 x0 = *(const float4*)&sX[(t+0)*64 + c4*4];
        float4 x1 = *(const float4*)&sX[(t+1)*64 + c4*4];
        float4 x2 = *(const float4*)&sX[(t+2)*64 + c4*4];
        float4 x3 = *(const float4*)&sX[(t+3)*64 + c4*4];
        float w0 = wr[c4*4+0], w1 = wr[c4*4+1], w2 = wr[c4*4+2], w3 = wr[c4*4+3];
        a0 = fmaf(w0, x0.x, a0); a0 = fmaf(w1, x0.y, a0); a0 = fmaf(w2, x0.z, a0); a0 = fmaf(w3, x0.w, a0);
        a1 = fmaf(w0, x1.x, a1); a1 = fmaf(w1, x1.y, a1); a1 = fmaf(w2, x1.z, a1); a1 = fmaf(w3, x1.w, a1);
        a2 = fmaf(w0, x2.x, a2); a2 = fmaf(w1, x2.y, a2); a2 = fmaf(w2, x2.z, a2); a2 = fmaf(w3, x2.w, a2);
        a3 = fmaf(w0, x3.x, a3); a3 = fmaf(w1, x3.y, a3); a3 = fmaf(w2, x3.z, a3); a3 = fmaf(w3, x3.w, a3);
      }
      m = fmaxf(m, fmaxf(fmaxf(a0,a1), fmaxf(a2,a3)));
    }
  }
  partial[((size_t)b*1024 + o)*22 + segbase + chunk] = m;
}

__global__ void gred_kernel(const float* __restrict__ partial, float* __restrict__ g, int S){
  int i = blockIdx.x*256 + threadIdx.x;
  if (i >= 4*1024) return;
  const float* p = partial + (size_t)i*22;
  float m = NEG_BIG;
  for (int s = 0; s < S; s++) m = fmaxf(m, p[s]);
  g[i] = lrelu(m);
}

__global__ void gw_kernel(const float* __restrict__ g, const void* __restrict__ W13,
                          const int* __restrict__ dtf, float* __restrict__ gW){
  int o = blockIdx.x, b = blockIdx.y;
  int lane = threadIdx.x;
  int isbf = *dtf;
  const float* gb = g + b*1024;
  float acc = 0.f;
  for (int c = lane; c < 1024; c += 64)
    acc = fmaf(ldx(W13, (size_t)o*1088 + c, isbf), gb[c], acc);
  for (int s = 32; s > 0; s >>= 1) acc += __shfl_down(acc, s, 64);
  if (lane == 0) gW[b*256 + o] = acc;
}

// ---------------- decoder MLPs (fused unpool gather) ----------------
__global__ void mlp_kernel(const float* __restrict__ base,
    const float* __restrict__ in1, const int* __restrict__ idx1, int N1, int C1,
    const float* __restrict__ W1T,
    const float* __restrict__ in2, int C2, const float* __restrict__ W2T,
    float* __restrict__ outT, int N, int Cout){
  __shared__ float sIn[4*320];
  int o = threadIdx.x, b = blockIdx.y;
  int n0 = blockIdx.x*4;
  int Cin = C1 + C2;
  int mask1 = N1 - 1;
  for (int t = 0; t < 4; t++){
    int n = n0 + t;
    int r1 = idx1 ? (idx1[(size_t)b*N + n] & mask1) : n;
    const float* p1 = in1 + ((size_t)b*N1 + r1)*C1;
    for (int c = o; c < C1; c += Cout) sIn[t*Cin + c] = p1[c];
    if (in2){
      const float* p2 = in2 + ((size_t)b*N + n)*C2;
      for (int c = o; c < C2; c += Cout) sIn[t*Cin + C1 + c] = p2[c];
    }
  }
  __syncthreads();
  float init = base ? base[b*Cout + o] : 0.f;
  float a0 = init, a1 = init, a2 = init, a3 = init;
  for (int c = 0; c < C1; c++){
    float wv = W1T[c*Cout + o];
    a0 = fmaf(wv, sIn[0*Cin + c], a0);
    a1 = fmaf(wv, sIn[1*Cin + c], a1);
    a2 = fmaf(wv, sIn[2*Cin + c], a2);
    a3 = fmaf(wv, sIn[3*Cin + c], a3);
  }
  for (int c = 0; c < C2; c++){
    float wv = W2T[c*Cout + o];
    a0 = fmaf(wv, sIn[0*Cin + C1 + c], a0);
    a1 = fmaf(wv, sIn[1*Cin + C1 + c], a1);
    a2 = fmaf(wv, sIn[2*Cin + C1 + c], a2);
    a3 = fmaf(wv, sIn[3*Cin + C1 + c], a3);
  }
  size_t ob = ((size_t)b*N + n0)*Cout + o;
  outT[ob]          = lrelu(a0);
  outT[ob + Cout]   = lrelu(a1);
  outT[ob + 2*Cout] = lrelu(a2);
  outT[ob + 3*Cout] = lrelu(a3);
}

__global__ void dec0_kernel(const float* __restrict__ h1T, const int* __restrict__ idxU0,
                            const float* __restrict__ x0T, const float* __restrict__ W16T,
                            const void* __restrict__ W17, const int* __restrict__ dtf,
                            void* __restrict__ out){
  __shared__ float sIn[4*320];
  __shared__ float sH0[4*128];
  int o = threadIdx.x;   // 128 threads
  int b = blockIdx.y; int n0 = blockIdx.x*4;
  for (int t = 0; t < 4; t++){
    int n = n0 + t;
    int r1 = idxU0[(size_t)b*4096 + n] & 1023;
    const float* p1 = h1T + ((size_t)b*1024 + r1)*256;
    for (int c = o; c < 256; c += 128) sIn[t*320 + c] = p1[c];
    const float* p2 = x0T + ((size_t)b*4096 + n)*64;
    if (o < 64) sIn[t*320 + 256 + o] = p2[o];
  }
  __syncthreads();
  float a0 = 0.f, a1 = 0.f, a2 = 0.f, a3 = 0.f;
  for (int c = 0; c < 256; c++){
    float wv = W16T[c*128 + o];
    a0 = fmaf(wv, sIn[0*320 + c], a0);
    a1 = fmaf(wv, sIn[1*320 + c], a1);
    a2 = fmaf(wv, sIn[2*320 + c], a2);
    a3 = fmaf(wv, sIn[3*320 + c], a3);
  }
  for (int c = 0; c < 64; c++){
    float wv = W16T[(256 + c)*128 + o];
    a0 = fmaf(wv, sIn[0*320 + 256 + c], a0);
    a1 = fmaf(wv, sIn[1*320 + 256 + c], a1);
    a2 = fmaf(wv, sIn[2*320 + 256 + c], a2);
    a3 = fmaf(wv, sIn[3*320 + 256 + c], a3);
  }
  sH0[0*128 + o] = lrelu(a0);
  sH0[1*128 + o] = lrelu(a1);
  sH0[2*128 + o] = lrelu(a2);
  sH0[3*128 + o] = lrelu(a3);
  __syncthreads();
  if (o < 52){
    int isbf = *dtf;
    int p = o / 13, cc = o % 13;
    float acc = 0.f;
    for (int c2 = 0; c2 < 128; c2++)
      acc = fmaf(ldx(W17, (size_t)cc*128 + c2, isbf), sH0[p*128 + c2], acc);
    if (!(acc == acc && fabsf(acc) < 1e30f)) acc = 0.f;
    stout(out, ((size_t)b*13 + cc)*4096 + (n0 + p), acc, isbf);
  }
}

// ---------------- host ----------------
extern "C" void kernel_launch(void* const* d_in, const int* in_sizes, int n_in,
                              void* d_out, int out_size, void* d_ws, size_t ws_size,
                              hipStream_t stream){
  (void)in_sizes; (void)n_in; (void)out_size;
  const int B = 4;
  const void* X       = d_in[0];
  const void* w_ec1_0 = d_in[1];
  const void* w_ec1_1 = d_in[2];
  const void* w_ec2_0 = d_in[3];
  const void* w_ec2_1 = d_in[4];
  const void* w_ec4_0 = d_in[5];
  const void* w_ec4_1 = d_in[6];
  const void* w_ec5_0 = d_in[7];
  const void* w_ec5_1 = d_in[8];
  const void* w_ec7   = d_in[9];
  const void* w_ec8   = d_in[10];
  const void* w_ec10  = d_in[11];
  const void* w_ec11  = d_in[12];
  const void* w_pn3   = d_in[13];
  const void* w_pn6   = d_in[14];
  const void* w_pn9   = d_in[15];
  const void* w_pn12  = d_in[16];
  const void* w_pn13  = d_in[17];
  const void* w_pn14  = d_in[18];
  const void* w_pn15  = d_in[19];
  const void* w_pn16  = d_in[20];
  const void* w_c17   = d_in[21];
  void* out = d_out;

  // ---- workspace layout (fp32 words; lifetime-aliased) ----
  float* wsf = (float*)d_ws;
  size_t off = 0;
  auto alloc = [&](size_t n)->float*{
    float* p = wsf + off; off += (n + 63) & ~(size_t)63; return p;
  };
  int*   dtf = (int*)alloc(64);
  float* xfT = alloc(4*4096*9);
  float* rr  = alloc(4*4096);
  float* partial = alloc(4*1024*22);
  float* g   = alloc(4*1024);
  float* gW  = alloc(4*256);
  int*   idx = (int*)alloc(4*4096*20);
  int*   idxU2 = (int*)alloc(4*256);
  int*   idxU1 = (int*)alloc(4*1024);
  int*   idxU0 = (int*)alloc(4*4096);
  float* ec1a = alloc(9*64);  float* ec1q = alloc(9*64);  float* ec1w1 = alloc(64*64);
  float* ec2a = alloc(64*64); float* ec2q = alloc(64*64); float* ec2w1 = alloc(64*64);
  float* ec4a = alloc(64*64); float* ec4q = alloc(64*64); float* ec4w1 = alloc(64*64);
  float* ec5a = alloc(64*64); float* ec5q = alloc(64*64); float* ec5w1 = alloc(64*64);
  float* ec7a = alloc(64*64); float* ec7q = alloc(64*64);
  float* ec8a = alloc(64*64); float* ec8q = alloc(64*64);
  float* ec10a = alloc(64*64); float* ec10q = alloc(64*64);
  float* ec11a = alloc(64*64); float* ec11q = alloc(64*64);
  float* wp13 = alloc(64*256);
  float* wt14 = alloc(320*256);
  float* wt15 = alloc(320*256);
  float* wt16 = alloc(320*128);
  float* P   = alloc(4*4096*64);
  float* hA  = alloc(4*4096*64);    // decoder: h1T alias (exact size)
  float* x0T = alloc(4*4096*64);
  float* x1T = alloc(4*1024*64);
  float* x2T = alloc(4*256*64);
  float* x3T = alloc(4*64*64);
  float* n1f = alloc(4*1024*64);    // decoder: h3T + head of h2T
  float* n2f = alloc(4*256*64);     // contiguous after n1f; h2T tail
  float* n3f = alloc(4*64*64);
  u16*   bhi = (u16*)alloc(4*4096*64/2);   // bf16 hi split (pre-swizzled), 2 MB
  u16*   blo = (u16*)alloc(4*4096*64/2);   // bf16 lo split (pre-swizzled), 2 MB
  float* h1T = hA;
  float* h3T = n1f;
  float* h2T = n1f + 65536;

  // ws-aware candidate sizing (ws_size constant across calls)
  size_t rem = (ws_size/4 > off + 256) ? (ws_size/4 - off - 256) : 0;
  size_t half = rem / 2;
  int NCbig = (half >= (size_t)4*4096*16*20) ? 16 :
              (half >= (size_t)4*4096*8*20)  ? 8  : 4;
  size_t E = (size_t)4*4096*20*NCbig;
  float* cval = alloc(E);
  int*   cidx = (int*)alloc(E);

  detect_kernel<<<dim3(1), 256, 0, stream>>>((const unsigned int*)X, dtf);

  // ---- weight prep ----
  w0_kernel<<<dim3(3), 256, 0, stream>>>(w_ec1_0, dtf, 9, ec1a, ec1q);
  w0_kernel<<<dim3(16), 256, 0, stream>>>(w_ec2_0, dtf, 64, ec2a, ec2q);
  w0_kernel<<<dim3(16), 256, 0, stream>>>(w_ec4_0, dtf, 64, ec4a, ec4q);
  w0_kernel<<<dim3(16), 256, 0, stream>>>(w_ec5_0, dtf, 64, ec5a, ec5q);
  w0_kernel<<<dim3(16), 256, 0, stream>>>(w_ec7, dtf, 64, ec7a, ec7q);
  w0_kernel<<<dim3(16), 256, 0, stream>>>(w_ec8, dtf, 64, ec8a, ec8q);
  w0_kernel<<<dim3(16), 256, 0, stream>>>(w_ec10, dtf, 64, ec10a, ec10q);
  w0_kernel<<<dim3(16), 256, 0, stream>>>(w_ec11, dtf, 64, ec11a, ec11q);
  wt_kernel<<<dim3(16), 256, 0, stream>>>(w_ec1_1, dtf, 64, 64, 0, 64, ec1w1);
  wt_kernel<<<dim3(16), 256, 0, stream>>>(w_ec2_1, dtf, 64, 64, 0, 64, ec2w1);
  wt_kernel<<<dim3(16), 256, 0, stream>>>(w_ec4_1, dtf, 64, 64, 0, 64, ec4w1);
  wt_kernel<<<dim3(16), 256, 0, stream>>>(w_ec5_1, dtf, 64, 64, 0, 64, ec5w1);
  wt_kernel<<<dim3(64), 256, 0, stream>>>(w_pn13, dtf, 256, 1088, 1024, 64, wp13);
  wt_kernel<<<dim3(320), 256, 0, stream>>>(w_pn14, dtf, 256, 320, 0, 320, wt14);
  wt_kernel<<<dim3(320), 256, 0, stream>>>(w_pn15, dtf, 256, 320, 0, 320, wt15);
  wt_kernel<<<dim3(160), 256, 0, stream>>>(w_pn16, dtf, 128, 320, 0, 320, wt16);

  xconv_kernel<<<dim3(64), 256, 0, stream>>>(X, dtf, xfT);
  nodecopy_kernel<<<dim3(64), 256, 0, stream>>>(X, dtf, out);

  const size_t xbs = (size_t)4096*9;
  // coord-space kNN on xfT (pitch 9). len=N/NC must be multiple of 64.
  auto knn_f = [&](int C, int K, int M, int N, int NC, int* io){
    rownorm_kernel<<<dim3((N+255)/256, B), 256, 0, stream>>>(xfT, 9, xbs, C, N, rr);
    dim3 gd((M+255)/256, NC, B);
    if (C == 9)      knn_chunk_kernel<9,20,64><<<gd,256,0,stream>>>(xfT,9,xbs,xfT,9,xbs,rr,M,N,NC,cval,cidx);
    else if (K==20)  knn_chunk_kernel<3,20,64><<<gd,256,0,stream>>>(xfT,9,xbs,xfT,9,xbs,rr,M,N,NC,cval,cidx);
    else             knn_chunk_kernel<3,1,64><<<gd,256,0,stream>>>(xfT,9,xbs,xfT,9,xbs,rr,M,N,NC,cval,cidx);
    dim3 gm((4*M+255)/256);
    if (K == 20)     knn_merge_kernel<20><<<gm,256,0,stream>>>(cval,cidx,M,NC,io);
    else             knn_merge_kernel<1><<<gm,256,0,stream>>>(cval,cidx,M,NC,io);
  };
  // feature-space self-kNN (C=64).
  // N>=1024: MFMA path (bf16 hi/lo split + float-gated key-FIFO selection), emits
  //          NC*4 virtual chunks, exact key-based merge.
  // N<=256 : legacy scalar knn64 path (already cheap).
  auto knn_b = [&](int K, const float* fT, int N, int NC, int* io){
    rownorm_kernel<<<dim3((N+255)/256, B), 256, 0, stream>>>(fT, 64, (size_t)N*64, 64, N, rr);
    if (K == 20 && N >= 1024){
      int NCm = NCbig / 4; if (NCm < 1) NCm = 1;     // NC*4 virtual chunks must fit cval
      int cap = (N == 4096) ? 2 : 4;
      if (NCm > cap) NCm = cap;
      bfsplit_kernel<<<dim3((4*N*64)/256), 256, 0, stream>>>(fT, N, bhi, blo);
      knnmf_kernel<20><<<dim3(N/64, NCm, B), 256, 0, stream>>>(bhi, blo, rr, N, NCm, cval, cidx);
      knn_merge_kernel<20><<<dim3((4*N+255)/256), 256, 0, stream>>>(cval, cidx, N, NCm*4, io);
    } else {
      dim3 gd(N/64, NC, B);
      if (K == 20) knn64_kernel<20><<<gd,64,0,stream>>>(fT, rr, N, NC, cval, cidx);
      else         knn64_kernel<10><<<gd,64,0,stream>>>(fT, rr, N, NC, cval, cidx);
      dim3 gm((4*N+255)/256);
      if (K == 20) knn_merge_kernel<20><<<gm,256,0,stream>>>(cval,cidx,N,NC,io);
      else         knn_merge_kernel<10><<<gm,256,0,stream>>>(cval,cidx,N,NC,io);
    }
  };
  auto edge2_b = [&](const float* fT, int N, int NC, float* wa, float* wq, float* w1, float* oT){
    knn_b(20, fT, N, NC, idx);
    pq_kernel<<<dim3((N+3)/4, B), 256, 0, stream>>>(fT, 64, 64, wa, P, N);
    edge2_kernel<<<dim3(N/4, B), 256, 0, stream>>>(P, fT, 64, 64, wq, idx, w1, oT, N, N-1);
  };
  auto edge1_b = [&](const float* fT, int N, int NC, int K, float* wa, float* wq, float* oT){
    knn_b(K, fT, N, NC, idx);
    pq_kernel<<<dim3((N+3)/4, B), 256, 0, stream>>>(fT, 64, 64, wa, P, N);
    edge1_kernel<<<dim3(N/4, B), 256, 0, stream>>>(P, fT, 64, 64, wq, idx, oT, N, K, N-1);
  };

  // level 0
  int nc9 = (NCbig < 8) ? NCbig : 8;                     // len 512
  knn_f(9, 20, 4096, 4096, nc9, idx);
  pq_kernel<<<dim3(1024, B), 256, 0, stream>>>(xfT, 9, 9, ec1a, P, 4096);
  edge2_kernel<<<dim3(1024, B), 256, 0, stream>>>(P, xfT, 9, 9, ec1q, idx, ec1w1, hA, 4096, 4095);
  edge2_b(hA, 4096, NCbig, ec2a, ec2q, ec2w1, x0T);
  pool_kernel<<<dim3(4,16,4), 256, 0, stream>>>(x0T, w_pn3, dtf, partial, 4096, 256, 0);
  // rand_pool 1
  knn_f(3, 20, 1024, 4096, 16, idx);                     // len 256
  gmax_kernel<<<dim3(1024, B), 64, 0, stream>>>(x0T, idx, n1f, 4096, 1024, 20, 4095);
  // level 1
  edge2_b(n1f, 1024, 16, ec4a, ec4q, ec4w1, hA);
  edge2_b(hA, 1024, 16, ec5a, ec5q, ec5w1, x1T);
  pool_kernel<<<dim3(4,4,4), 256, 0, stream>>>(x1T, w_pn6, dtf, partial, 1024, 256, 16);
  reluadd_kernel<<<dim3(1024), 256, 0, stream>>>(x1T, n1f, 4*1024*64);
  // rand_pool 2
  knn_f(3, 20, 256, 1024, 16, idx);                      // len 64
  gmax_kernel<<<dim3(256, B), 64, 0, stream>>>(x1T, idx, n2f, 1024, 256, 20, 1023);
  // level 2
  edge1_b(n2f, 256, 16, 20, ec7a, ec7q, hA);             // len 16
  edge1_b(hA, 256, 16, 20, ec8a, ec8q, x2T);
  pool_kernel<<<dim3(4,1,4), 256, 0, stream>>>(x2T, w_pn9, dtf, partial, 256, 256, 20);
  reluadd_kernel<<<dim3(256), 256, 0, stream>>>(x2T, n2f, 4*256*64);
  // rand_pool 3
  knn_f(3, 20, 64, 256, 4, idx);                         // len 64 (chunk TN bound)
  gmax_kernel<<<dim3(64, B), 64, 0, stream>>>(x2T, idx, n3f, 256, 64, 20, 255);
  // level 3
  edge1_b(n3f, 64, 8, 10, ec10a, ec10q, hA);             // len 8
  edge1_b(hA, 64, 8, 10, ec11a, ec11q, x3T);
  pool_kernel<<<dim3(4,1,4), 256, 0, stream>>>(x3T, w_pn12, dtf, partial, 64, 64, 21);
  reluadd_kernel<<<dim3(64), 256, 0, stream>>>(x3T, n3f, 4*64*64);
  // ---- idx, P, hA, n1f, n2f dead -> h3T/h2T/h1T aliases live ----
  gred_kernel<<<dim3(16), 256, 0, stream>>>(partial, g, 22);
  gw_kernel<<<dim3(256, 4), 64, 0, stream>>>(g, w_pn13, dtf, gW);
  mlp_kernel<<<dim3(16, B), 256, 0, stream>>>(gW, x3T, nullptr, 64, 64, wp13,
                                              nullptr, 0, nullptr, h3T, 64, 256);
  knn_f(3, 1, 256, 64, 1, idxU2);                        // len 64
  mlp_kernel<<<dim3(64, B), 256, 0, stream>>>(nullptr, h3T, idxU2, 64, 256, wt14,
                                              x2T, 64, wt14 + 256*256, h2T, 256, 256);
  knn_f(3, 1, 1024, 256, 4, idxU1);                      // len 64
  mlp_kernel<<<dim3(256, B), 256, 0, stream>>>(nullptr, h2T, idxU1, 256, 256, wt15,
                                               x1T, 64, wt15 + 256*256, h1T, 1024, 256);
  knn_f(3, 1, 4096, 1024, 4, idxU0);                     // len 256
  dec0_kernel<<<dim3(1024, B), 128, 0, stream>>>(h1T, idxU0, x0T, wt16, w_c17, dtf, out);
}

// Round 9
// 2998.141 us; speedup vs baseline: 1.1119x; 1.1119x over previous
//
#include <hip/hip_runtime.h>
#include <hip/hip_bf16.h>
#include <float.h>

typedef __hip_bfloat16 bf16;
typedef unsigned short u16;
typedef unsigned long long u64;
typedef __attribute__((ext_vector_type(8))) short bh8;   // 8 bf16 = 4 VGPRs (MFMA A/B frag)
typedef __attribute__((ext_vector_type(4))) float fx4;   // MFMA C/D frag

#define NEG_BIG (-1.0e30f)

__device__ __forceinline__ bf16 f2b(float v){ return __float2bfloat16(v); }
__device__ __forceinline__ float lrelu(float x){ return x >= 0.f ? x : 0.2f*x; }

// round-to-nearest-even fp32 -> bf16 bits
__device__ __forceinline__ u16 f2bf_rne(float x){
  unsigned u = __float_as_uint(x);
  unsigned r = (u + 0x7FFFu + ((u >> 16) & 1u)) >> 16;
  return (u16)r;
}

// dtype-flexible sanitized load from a raw INPUT buffer (element index)
__device__ __forceinline__ float ldx(const void* p, size_t i, int isbf){
  float v = isbf ? __bfloat162float(((const bf16*)p)[i]) : ((const float*)p)[i];
  return (v == v && fabsf(v) < 1e30f) ? v : 0.f;
}
// dtype-flexible store to the OUTPUT buffer (element index)
__device__ __forceinline__ void stout(void* p, size_t i, float v, int isbf){
  if (isbf) ((bf16*)p)[i] = f2b(v);
  else      ((float*)p)[i] = v;
}

// carry-chain sorted top-K insert (bv descending, bv[K-1] = min).
// TB=false: strict > (equal values keep earlier-scanned = lower index when scan is
// index-ordered). TB=true: explicit (value, lower-index) tie-break, order-independent.
// NOTE (r5-r8 lesson): packed-u64 key variants of this chain are NOT cheaper on CDNA
// (u64 cmp = 2 ops, u64 cndmask = 2x b32) — keep the float/int dual chain.
template<int K, bool TB>
__device__ __forceinline__ void topk_ins_t(float (&bv)[K], int (&bi)[K], float d, int j){
  bool gate = TB ? (d > bv[K-1] || (d == bv[K-1] && j < bi[K-1])) : (d > bv[K-1]);
  if (gate){
    bool gt[K];
    #pragma unroll
    for (int s = 0; s < K; s++)
      gt[s] = TB ? (d > bv[s] || (d == bv[s] && j < bi[s])) : (d > bv[s]);
    #pragma unroll
    for (int s = K-1; s > 0; s--){
      float nv = gt[s-1] ? bv[s-1] : d;
      int   ni = gt[s-1] ? bi[s-1] : j;
      bv[s] = gt[s] ? nv : bv[s];
      bi[s] = gt[s] ? ni : bi[s];
    }
    if (gt[0]){ bv[0] = d; bi[0] = j; }
  }
}
template<int K>
__device__ __forceinline__ void topk_ins(float (&bv)[K], int (&bi)[K], float d, int j){
  topk_ins_t<K,false>(bv, bi, d, j);
}

// ---------------- input dtype detector ----------------
__global__ void detect_kernel(const unsigned int* __restrict__ X, int* __restrict__ flag){
  __shared__ int cnt;
  if (threadIdx.x == 0) cnt = 0;
  __syncthreads();
  int hits = 0;
  for (int i = threadIdx.x; i < 8192; i += 256){
    unsigned w = X[i];
    unsigned lo = w & 0xFFFFu;
    unsigned e = (lo >> 7) & 0xFFu;
    if ((e >= 0x76u && e <= 0x84u) || lo == 0u) hits++;
  }
  atomicAdd(&cnt, hits);
  __syncthreads();
  if (threadIdx.x == 0) flag[0] = (cnt > 4096) ? 1 : 0;
}

// ---------------- weight prep ----------------
__global__ void wt_kernel(const void* __restrict__ W, const int* __restrict__ dtf,
                          int Cout, int pitch, int coff, int Cin, float* __restrict__ WT){
  int i = blockIdx.x*256 + threadIdx.x;
  if (i >= Cin*Cout) return;
  int isbf = *dtf;
  int c = i / Cout, o = i - c*Cout;
  WT[i] = ldx(W, (size_t)o*pitch + coff + c, isbf);
}

__global__ void w0_kernel(const void* __restrict__ W0, const int* __restrict__ dtf,
                          int C, float* __restrict__ WaT, float* __restrict__ WqT){
  int i = blockIdx.x*256 + threadIdx.x;
  if (i >= C*64) return;
  int isbf = *dtf;
  int c = i >> 6, o = i & 63;
  float a = ldx(W0, (size_t)o*2*C + c, isbf);
  float q = ldx(W0, (size_t)o*2*C + C + c, isbf);
  WaT[i] = a; WqT[i] = q - a;
}

__global__ void xconv_kernel(const void* __restrict__ x, const int* __restrict__ dtf,
                             float* __restrict__ xfT){
  int i = blockIdx.x*256 + threadIdx.x;
  if (i >= 4*4096) return;
  int isbf = *dtf;
  int b = i >> 12, n = i & 4095;
  for (int c = 0; c < 9; c++)
    xfT[((size_t)b*4096 + n)*9 + c] = ldx(x, ((size_t)b*9 + c)*4096 + n, isbf);
}

__global__ void nodecopy_kernel(const void* __restrict__ x, const int* __restrict__ dtf,
                                void* __restrict__ out){
  int i = blockIdx.x*256 + threadIdx.x;
  int isbf = *dtf;
  if (i < 12288){
    int b = i / 3072, r = i % 3072; int c = r / 1024, m = r % 1024;
    stout(out, 212992 + i, ldx(x, ((size_t)b*9 + c)*4096 + m, isbf), isbf);
  } else if (i < 15360){
    int j = i - 12288; int b = j / 768, r = j % 768; int c = r / 256, m = r % 256;
    stout(out, 212992 + i, ldx(x, ((size_t)b*9 + c)*4096 + m, isbf), isbf);
  } else if (i < 16128){
    int j = i - 15360; int b = j / 192, r = j % 192; int c = r / 64, m = r % 64;
    stout(out, 212992 + i, ldx(x, ((size_t)b*9 + c)*4096 + m, isbf), isbf);
  }
}

// ---------------- kNN ----------------
__global__ void rownorm_kernel(const float* __restrict__ T, int pitch, size_t bs,
                               int C, int N, float* __restrict__ rr){
  int n = blockIdx.x*256 + threadIdx.x;
  int b = blockIdx.y;
  if (n >= N) return;
  const float* row = T + (size_t)b*bs + (size_t)n*pitch;
  float s = 0.f;
  for (int c = 0; c < C; c++) s = fmaf(row[c], row[c], s);
  rr[b*N + n] = s;
}

// small-C chunked kNN (C=3/9; per-thread query in registers, refs staged in LDS).
// Refs staged TRANSPOSED [c][t]: wave-uniform ds_read_b128 broadcasts (4 cands/read).
// K>=8: tau-gated per-thread LDS FIFO (cap 16) + per-tile drains + overflow drain.
//   Exact: stale tau (== bv[K-1] at last drain) is only more permissive; FIFO drain
//   preserves ascending-j order so strict-> insert keeps lax.top_k tie semantics.
// REQUIREMENT: len = N/NC must be a multiple of TN.
template<int C, int K, int TN>
__global__ void knn_chunk_kernel(const float* __restrict__ qT, int qpitch, size_t qbs,
                                 const float* __restrict__ rT, int rpitch, size_t rbs,
                                 const float* __restrict__ rr, int M, int N, int NC,
                                 float* __restrict__ cval, int* __restrict__ cidx){
  constexpr bool FIFO = (K >= 8);
  constexpr int CAP = 16;
  __shared__ __align__(16) float sRT[C*TN];   // [c][t]
  __shared__ __align__(16) float sN[TN];
  __shared__ u64 sQ[FIFO ? 256*(CAP+1) : 1];  // per-thread FIFO, stride 17 u64
  int tid = threadIdx.x;
  int m = blockIdx.x*256 + tid;
  int cid = blockIdx.y, b = blockIdx.z;
  int len = N / NC;
  int n0 = cid * len;
  bool active = (m < M);
  float q[C]; float qq = 0.f;
  if (active){
    const float* qrow = qT + (size_t)b*qbs + (size_t)m*qpitch;
    #pragma unroll
    for (int c = 0; c < C; c++){ q[c] = qrow[c]; qq = fmaf(q[c], q[c], qq); }
  }
  float bv[K]; int bi[K];
  #pragma unroll
  for (int j = 0; j < K; j++){ bv[j] = NEG_BIG; bi[j] = n0; }
  float tau = NEG_BIG;
  u64* qb = FIFO ? &sQ[tid*(CAP+1)] : (u64*)nullptr;
  int qcnt = 0;
  const float* rbase = rT + (size_t)b*rbs;
  const float* rrb = rr + b*N;

  auto drain = [&](){
    int k = 0;
    while (__any(k < qcnt)){
      if (k < qcnt){
        u64 e = qb[k];
        float d = __uint_as_float((unsigned)(e >> 32));
        int j = (int)(unsigned)e;
        topk_ins_t<K,false>(bv, bi, d, j);
      }
      k++;
    }
    qcnt = 0;
    tau = bv[K-1];
  };

  for (int t0 = 0; t0 < len; t0 += TN){
    __syncthreads();
    for (int i = tid; i < TN*C; i += 256){
      int c = i / TN, t = i - c*TN;
      sRT[i] = rbase[(size_t)(n0 + t0 + t)*rpitch + c];
    }
    for (int i = tid; i < TN; i += 256) sN[i] = rrb[n0 + t0 + i];
    __syncthreads();
    if (active){
      for (int t = 0; t < TN; t += 4){
        float a0 = 0.f, a1 = 0.f, a2 = 0.f, a3 = 0.f;
        #pragma unroll
        for (int c = 0; c < C; c++){
          float4 rv = *(const float4*)&sRT[c*TN + t];
          float qc = q[c];
          a0 = fmaf(qc, rv.x, a0); a1 = fmaf(qc, rv.y, a1);
          a2 = fmaf(qc, rv.z, a2); a3 = fmaf(qc, rv.w, a3);
        }
        float4 nn = *(const float4*)&sN[t];
        int jb = n0 + t0 + t;
        float d0 = 2.f*a0 - qq - nn.x;
        float d1 = 2.f*a1 - qq - nn.y;
        float d2 = 2.f*a2 - qq - nn.z;
        float d3 = 2.f*a3 - qq - nn.w;
        if constexpr (FIFO){
          if (__any(qcnt >= CAP-4)) drain();    // guarantees room for 4
          if (d0 > tau){ qb[qcnt] = (((u64)__float_as_uint(d0))<<32) | (unsigned)(jb+0); qcnt++; }
          if (d1 > tau){ qb[qcnt] = (((u64)__float_as_uint(d1))<<32) | (unsigned)(jb+1); qcnt++; }
          if (d2 > tau){ qb[qcnt] = (((u64)__float_as_uint(d2))<<32) | (unsigned)(jb+2); qcnt++; }
          if (d3 > tau){ qb[qcnt] = (((u64)__float_as_uint(d3))<<32) | (unsigned)(jb+3); qcnt++; }
        } else {
          topk_ins<K>(bv, bi, d0, jb+0);
          topk_ins<K>(bv, bi, d1, jb+1);
          topk_ins<K>(bv, bi, d2, jb+2);
          topk_ins<K>(bv, bi, d3, jb+3);
        }
      }
    }
    if constexpr (FIFO){ drain(); }             // inactive lanes: qcnt==0, no-op
  }
  if (active){
    float* ov = cval + ((size_t)((size_t)b*M + m)*NC + cid)*K;
    int*   oi = cidx + ((size_t)((size_t)b*M + m)*NC + cid)*K;
    #pragma unroll
    for (int j = 0; j < K; j++){ ov[j] = bv[j]; oi[j] = bi[j]; }
  }
}

// C=64 self-kNN scan (legacy path, kept for N<=256): 1-wave blocks, queries in VGPRs.
template<int K>
__launch_bounds__(64, 2)
__global__ void knn64_kernel(const float* __restrict__ fT, const float* __restrict__ rr,
                             int N, int NC, float* __restrict__ cval, int* __restrict__ cidx){
  int lane = threadIdx.x;
  int q0 = blockIdx.x*64;
  int cid = blockIdx.y, b = blockIdx.z;
  int m = q0 + lane;
  int len = N / NC;
  int n0 = cid*len;
  float4 q4[16];
  {
    const float4* qp = (const float4*)(fT + ((size_t)b*N + m)*64);
    #pragma unroll
    for (int i = 0; i < 16; i++) q4[i] = qp[i];
  }
  float qq = rr[(size_t)b*N + m];   // self-kNN (M==N)
  float bv[K]; int bi[K];
  #pragma unroll
  for (int j = 0; j < K; j++){ bv[j] = NEG_BIG; bi[j] = n0; }
  const float4* rbase = (const float4*)(fT + ((size_t)b*N + n0)*64);
  const float* rrb = rr + (size_t)b*N + n0;
  for (int t0 = 0; t0 < len; t0 += 4){
    const float4* r4 = rbase + (size_t)t0*16;
    float a0=0.f, a1=0.f, a2=0.f, a3=0.f;
    #pragma unroll
    for (int ct = 0; ct < 16; ct++){
      float4 v0 = r4[ct], v1 = r4[16+ct], v2 = r4[32+ct], v3 = r4[48+ct];
      float4 qv = q4[ct];
      a0 = fmaf(qv.x,v0.x,a0); a0 = fmaf(qv.y,v0.y,a0); a0 = fmaf(qv.z,v0.z,a0); a0 = fmaf(qv.w,v0.w,a0);
      a1 = fmaf(qv.x,v1.x,a1); a1 = fmaf(qv.y,v1.y,a1); a1 = fmaf(qv.z,v1.z,a1); a1 = fmaf(qv.w,v1.w,a1);
      a2 = fmaf(qv.x,v2.x,a2); a2 = fmaf(qv.y,v2.y,a2); a2 = fmaf(qv.z,v2.z,a2); a2 = fmaf(qv.w,v2.w,a2);
      a3 = fmaf(qv.x,v3.x,a3); a3 = fmaf(qv.y,v3.y,a3); a3 = fmaf(qv.z,v3.z,a3); a3 = fmaf(qv.w,v3.w,a3);
    }
    topk_ins<K>(bv, bi, 2.f*a0 - qq - rrb[t0+0], n0+t0+0);
    topk_ins<K>(bv, bi, 2.f*a1 - qq - rrb[t0+1], n0+t0+1);
    topk_ins<K>(bv, bi, 2.f*a2 - qq - rrb[t0+2], n0+t0+2);
    topk_ins<K>(bv, bi, 2.f*a3 - qq - rrb[t0+3], n0+t0+3);
  }
  float* ov = cval + ((size_t)((size_t)b*N + m)*NC + cid)*K;
  int*   oi = cidx + ((size_t)((size_t)b*N + m)*NC + cid)*K;
  #pragma unroll
  for (int j = 0; j < K; j++){ ov[j] = bv[j]; oi[j] = bi[j]; }
}

// fp32 -> (hi, lo) bf16 split, stored PRE-SWIZZLED (c ^= (row&7)<<3) so that the
// kNN MFMA kernel can stage LDS tiles with linear copies and read ds_read_b128
// fragments bank-conflict-optimally (G4/T2 recipe).
__global__ void bfsplit_kernel(const float* __restrict__ fT, int N,
                               u16* __restrict__ hi, u16* __restrict__ lo){
  int i = blockIdx.x*256 + threadIdx.x;      // over 4*N*64
  if (i >= 4*N*64) return;
  int c = i & 63;
  int n = i >> 6;                            // combined row b*N + ln; N % 8 == 0 so n&7 == ln&7
  float x = fT[i];
  u16 h = f2bf_rne(x);
  float hf = __uint_as_float((unsigned)h << 16);
  u16 l = f2bf_rne(x - hf);
  size_t o = ((size_t)n << 6) + (c ^ ((n & 7) << 3));
  hi[o] = h; lo[o] = l;
}

// MFMA feature-space self-kNN (C=64).  exact-ish distances via bf16 hi/lo split:
// inner = hi·hi + hi·lo + lo·hi (3x mfma_f32_16x16x32_bf16, fp32 accum, rel err ~2^-17).
// D[ref][query] orientation: lane = (g=l>>4, lm=l&15) holds query (qblk+w*16+lm)'s
// distances for refs {tile + m*16 + 4g + i}.
// Selection:
//  * shared threshold tau = max over the 4 partition-lanes (lm, lm+16, lm+32, lm+48)
//    of their local bv[K-1], refreshed per tile via 2x shfl_xor.  Exact: any candidate
//    strictly below tau is below the query's final K-th value.
//  * candidates passing tau go to a per-thread 16-entry LDS FIFO (capacity proof:
//    drained every tile; a tile pushes at most 4m x 4i = 16).
//  * FIFO drain preserves ascending-j order -> strict-> insert (no tie-break chain);
//    cross-partition ties resolved exactly by the TB=true merge.
template<int K>
__launch_bounds__(256, 2)
__global__ void knnmf_kernel(const u16* __restrict__ hi, const u16* __restrict__ lo,
                             const float* __restrict__ rr, int N, int NC,
                             float* __restrict__ cval, int* __restrict__ cidx){
  __shared__ __align__(16) u16 sHi[64*64];     // 8 KB, swizzled rows
  __shared__ __align__(16) u16 sLo[64*64];     // 8 KB
  __shared__ float sRR[64];
  __shared__ u64 sQ[256*17];                   // per-thread 16-entry FIFO, stride 17 (34 KB)

  const int tid  = threadIdx.x;
  const int lane = tid & 63, w = tid >> 6;
  const int g    = lane >> 4;                  // 0..3
  const int lm   = lane & 15;
  const int qblk = blockIdx.x * 64;
  const int cid  = blockIdx.y, b = blockIdx.z;
  const int len  = N / NC, n0 = cid * len;

  const u16*  hib = hi + (size_t)b*N*64;
  const u16*  lob = lo + (size_t)b*N*64;
  const float* rrb = rr + (size_t)b*N;

  // ---- stage this block's 64 query rows, pull B-fragments into registers ----
  {
    const float4* sh = (const float4*)(hib + (size_t)qblk*64);
    const float4* sl = (const float4*)(lob + (size_t)qblk*64);
    float4* dh = (float4*)sHi; float4* dl = (float4*)sLo;
    for (int i = tid; i < 512; i += 256){ dh[i] = sh[i]; dl[i] = sl[i]; }
  }
  __syncthreads();
  const int qrow = w*16 + lm;                  // wave w owns queries qblk + w*16 .. +15
  const int kb0 = 8*g, kb1 = 32 + 8*g;         // frag k-offsets: k = koff + 8*(lane>>4) + i
  const int qsw = (qrow & 7) << 3;
  const bh8 qh0 = *(const bh8*)&sHi[qrow*64 + (kb0 ^ qsw)];
  const bh8 qh1 = *(const bh8*)&sHi[qrow*64 + (kb1 ^ qsw)];
  const bh8 ql0 = *(const bh8*)&sLo[qrow*64 + (kb0 ^ qsw)];
  const bh8 ql1 = *(const bh8*)&sLo[qrow*64 + (kb1 ^ qsw)];
  const float qq = rrb[qblk + qrow];

  float bv[K]; int bi[K];
  #pragma unroll
  for (int j = 0; j < K; j++){ bv[j] = NEG_BIG; bi[j] = n0; }
  float tau = NEG_BIG;                         // shared (4-partition) running K-th value
  u64* qbase = &sQ[tid*17];
  int qcnt = 0;

  for (int t0 = n0; t0 < n0 + len; t0 += 64){
    __syncthreads();                           // previous tile's frag reads done
    {
      const float4* sh = (const float4*)(hib + (size_t)t0*64);
      const float4* sl = (const float4*)(lob + (size_t)t0*64);
      float4* dh = (float4*)sHi; float4* dl = (float4*)sLo;
      for (int i = tid; i < 512; i += 256){ dh[i] = sh[i]; dl[i] = sl[i]; }
      if (tid < 64) sRR[tid] = rrb[t0 + tid];
    }
    __syncthreads();
    for (int m = 0; m < 4; m++){
      const int rrow = m*16 + lm;              // A-frag row owned by this lane
      const int sw = (rrow & 7) << 3;
      const bh8 ah0 = *(const bh8*)&sHi[rrow*64 + (kb0 ^ sw)];
      const bh8 ah1 = *(const bh8*)&sHi[rrow*64 + (kb1 ^ sw)];
      const bh8 al0 = *(const bh8*)&sLo[rrow*64 + (kb0 ^ sw)];
      const bh8 al1 = *(const bh8*)&sLo[rrow*64 + (kb1 ^ sw)];
      fx4 acc = {0.f, 0.f, 0.f, 0.f};
      acc = __builtin_amdgcn_mfma_f32_16x16x32_bf16(ah0, qh0, acc, 0, 0, 0);
      acc = __builtin_amdgcn_mfma_f32_16x16x32_bf16(ah1, qh1, acc, 0, 0, 0);
      acc = __builtin_amdgcn_mfma_f32_16x16x32_bf16(ah0, ql0, acc, 0, 0, 0);
      acc = __builtin_amdgcn_mfma_f32_16x16x32_bf16(ah1, ql1, acc, 0, 0, 0);
      acc = __builtin_amdgcn_mfma_f32_16x16x32_bf16(al0, qh0, acc, 0, 0, 0);
      acc = __builtin_amdgcn_mfma_f32_16x16x32_bf16(al1, qh1, acc, 0, 0, 0);
      const float4 rr4 = *(const float4*)&sRR[m*16 + 4*g];   // broadcast within 16-lane group
      const float rrv[4] = {rr4.x, rr4.y, rr4.z, rr4.w};
      const int jb = t0 + m*16 + 4*g;          // C/D rows: lane holds rows 4g+i
      #pragma unroll
      for (int i = 0; i < 4; i++){
        float d = fmaf(2.f, acc[i], -(qq + rrv[i]));
        if (d >= tau){                         // >= keeps boundary ties (exactness)
          qbase[qcnt] = (((u64)__float_as_uint(d)) << 32) | (unsigned)(jb + i);
          qcnt++;                              // <=16 pushes per tile, CAP=16 -> no overflow
        }
      }
    }
    // per-tile FIFO drain (ascending j -> strict-> insert keeps lowest index on ties)
    {
      int k = 0;
      while (__any(k < qcnt)){
        if (k < qcnt){
          u64 e = qbase[k];
          float d = __uint_as_float((unsigned)(e >> 32));
          int j = (int)(unsigned)e;
          topk_ins_t<K,false>(bv, bi, d, j);
        }
        k++;
      }
      qcnt = 0;
    }
    // refresh shared threshold: max of the 4 partition-lanes' local K-th values
    {
      float t = bv[K-1];
      t = fmaxf(t, __shfl_xor(t, 16));
      t = fmaxf(t, __shfl_xor(t, 32));
      tau = t;
    }
  }
  const int q = qblk + qrow;
  const size_t rowo = (((size_t)b*N + q)*(size_t)(NC*4) + (size_t)(cid*4 + g))*(size_t)K;
  float* ov = cval + rowo; int* oi = cidx + rowo;
  #pragma unroll
  for (int j = 0; j < K; j++){ ov[j] = bv[j]; oi[j] = bi[j]; }
}

template<int K, bool TB>
__global__ void knn_merge_kernel(const float* __restrict__ cval, const int* __restrict__ cidx,
                                 int M, int NC, int* __restrict__ idxo){
  int i = blockIdx.x*256 + threadIdx.x;   // b*M + m
  if (i >= 4*M) return;
  const float* cv = cval + (size_t)i*NC*K;
  const int*   ci = cidx + (size_t)i*NC*K;
  float bv[K]; int bi[K];
  #pragma unroll
  for (int j = 0; j < K; j++){ bv[j] = NEG_BIG; bi[j] = 0; }
  int T = NC*K;
  for (int t = 0; t < T; t++)
    topk_ins_t<K,TB>(bv, bi, cv[t], ci[t]);
  int* orow = idxo + (size_t)i*K;
  #pragma unroll
  for (int j = 0; j < K; j++) orow[j] = bi[j];
}

// ---------------- edge conv ----------------
__global__ void pq_kernel(const float* __restrict__ xT, int pitch, int C,
                          const float* __restrict__ WaT,
                          float* __restrict__ P, int N){
  int o = threadIdx.x & 63;
  int n = blockIdx.x*4 + (threadIdx.x >> 6);
  int b = blockIdx.y;
  if (n >= N) return;
  const float* row = xT + ((size_t)b*N + n)*pitch;
  float ap = 0.f;
  for (int c = 0; c < C; c++) ap = fmaf(WaT[c*64 + o], row[c], ap);
  P[((size_t)b*N + n)*64 + o] = ap;
}

// 4 points per 256-thread block: shared W1 tile, per-point sH. N % 4 == 0.
__global__ void edge2_kernel(const float* __restrict__ P, const float* __restrict__ featT,
                             int pitch, int C, const float* __restrict__ WqT,
                             const int* __restrict__ idx, const float* __restrict__ W1T,
                             float* __restrict__ outT, int N, int mask){
  __shared__ float sW[64*64];     // [c][o]
  __shared__ float sH[4*20*64];   // [t][kk][c]
  __shared__ float sx[4*64];
  int tid = threadIdx.x;
  int o = tid & 63, t = tid >> 6;
  int n = blockIdx.x*4 + t;
  int b = blockIdx.y;
  const float4* w4 = (const float4*)W1T;
  float4* s4 = (float4*)sW;
  for (int i = tid; i < 1024; i += 256) s4[i] = w4[i];
  if (o < C) sx[t*64 + o] = featT[((size_t)b*N + n)*pitch + o];
  __syncthreads();
  float qv = 0.f;
  for (int c = 0; c < C; c++) qv = fmaf(WqT[c*64 + o], sx[t*64 + c], qv);
  const float* Pb = P + (size_t)b*N*64;
  const int* irow = idx + ((size_t)b*N + n)*20;
  float* sHt = sH + t*1280;
  for (int kk = 0; kk < 20; kk++){
    int j = irow[kk] & mask;
    float h = Pb[(size_t)j*64 + o] + qv;
    sHt[kk*64 + o] = h >= 0.f ? h : 0.2f*h;
  }
  __syncthreads();
  float acc[20];
  #pragma unroll
  for (int kk = 0; kk < 20; kk++) acc[kk] = 0.f;
  for (int c = 0; c < 64; c += 4){
    float w0 = sW[c*64+o], w1 = sW[(c+1)*64+o], w2 = sW[(c+2)*64+o], w3 = sW[(c+3)*64+o];
    #pragma unroll
    for (int kk = 0; kk < 20; kk++){
      float4 h4 = *(const float4*)&sHt[kk*64 + c];
      float a = acc[kk];
      a = fmaf(w0, h4.x, a); a = fmaf(w1, h4.y, a);
      a = fmaf(w2, h4.z, a); a = fmaf(w3, h4.w, a);
      acc[kk] = a;
    }
  }
  float m = NEG_BIG;
  #pragma unroll
  for (int kk = 0; kk < 20; kk++) m = fmaxf(m, acc[kk]);
  outT[((size_t)b*N + n)*64 + o] = lrelu(m);
}

// 4 points per 256-thread block. N % 4 == 0.
__global__ void edge1_kernel(const float* __restrict__ P, const float* __restrict__ featT,
                             int pitch, int C, const float* __restrict__ WqT,
                             const int* __restrict__ idx, float* __restrict__ outT,
                             int N, int K, int mask){
  __shared__ float sx[4*64];
  int tid = threadIdx.x;
  int o = tid & 63, t = tid >> 6;
  int n = blockIdx.x*4 + t;
  int b = blockIdx.y;
  if (o < C) sx[t*64 + o] = featT[((size_t)b*N + n)*pitch + o];
  __syncthreads();
  float qv = 0.f;
  for (int c = 0; c < C; c++) qv = fmaf(WqT[c*64 + o], sx[t*64 + c], qv);
  const float* Pb = P + (size_t)b*N*64;
  const int* irow = idx + ((size_t)b*N + n)*K;
  float m = NEG_BIG;
  for (int kk = 0; kk < K; kk++){
    int j = irow[kk] & mask;
    m = fmaxf(m, Pb[(size_t)j*64 + o] + qv);
  }
  outT[((size_t)b*N + n)*64 + o] = lrelu(m);
}

__global__ void gmax_kernel(const float* __restrict__ inT, const int* __restrict__ idx,
                            float* __restrict__ outT, int Nin, int M, int K, int mask){
  int o = threadIdx.x; int m = blockIdx.x; int b = blockIdx.y;
  const float* ib = inT + (size_t)b*Nin*64;
  const int* irow = idx + ((size_t)b*M + m)*K;
  float v = NEG_BIG;
  for (int kk = 0; kk < K; kk++){
    int j = irow[kk] & mask;
    v = fmaxf(v, ib[(size_t)j*64 + o]);
  }
  outT[((size_t)b*M + m)*64 + o] = v;
}

__global__ void reluadd_kernel(float* __restrict__ x, const float* __restrict__ f, int total){
  int i = blockIdx.x*256 + threadIdx.x;
  if (i >= total) return;
  float v = x[i] + f[i];
  x[i] = v > 0.f ? v : 0.f;
}

// ---------------- global feature path ----------------
// W row (64 floats) held in REGISTERS per thread; x chunk staged in LDS and read via
// ds_read_b128 wave-broadcast (all lanes same address -> conflict-free, 4 vals/instr).
__launch_bounds__(256, 4)
__global__ void pool_kernel(const float* __restrict__ xT, const void* __restrict__ W,
                            const int* __restrict__ dtf, float* __restrict__ partial,
                            int N, int npts, int segbase){
  __shared__ __align__(16) float sX[32*64];   // 8 KB
  int tid = threadIdx.x;
  int ot = blockIdx.x, chunk = blockIdx.y, b = blockIdx.z;
  int isbf = *dtf;
  int o = ot*256 + tid;
  float wr[64];
  #pragma unroll
  for (int c = 0; c < 64; c++) wr[c] = ldx(W, (size_t)o*64 + c, isbf);
  int n0 = chunk * npts;
  float m = NEG_BIG;
  for (int s0 = 0; s0 < npts; s0 += 32){
    __syncthreads();
    const float4* src = (const float4*)(xT + ((size_t)b*N + n0 + s0)*64);
    float4* dst = (float4*)sX;
    for (int i = tid; i < 512; i += 256) dst[i] = src[i];
    __syncthreads();
    for (int t = 0; t < 32; t += 4){
      float a0 = 0.f, a1 = 0.f, a2 = 0.f, a3 = 0.f;
      #pragma unroll
      for (int c4 = 0; c4 < 16; c4++){
        float4 x0 = *(const float4*)&sX[(t+0)*64 + c4*4];
        float4 x1 = *(const float4*)&sX[(t+1)*64 + c4*4];
        float4 x2 = *(const float4*)&sX[(t+2)*64 + c4*4];
        float4 x3 = *(const float4*)&sX[(t+3)*64 + c4*4];
        float w0 = wr[c4*4+0], w1 = wr[c4*4+1], w2 = wr[c4*4+2], w3 = wr[c4*4+3];
        a0 = fmaf(w0, x0.x, a0); a0 = fmaf(w1, x0.y, a0); a0 = fmaf(w2, x0.z, a0); a0 = fmaf(w3, x0.w, a0);
        a1 = fmaf(w0, x1.x, a1); a1 = fmaf(w1, x1.y, a1); a1 = fmaf(w2, x1.z, a1); a1 = fmaf(w3, x1.w, a1);
        a2 = fmaf(w0, x2.x, a2); a2 = fmaf(w1, x2.y, a2); a2 = fmaf(w2, x2.z, a2); a2 = fmaf(w3, x2.w, a2);
        a3 = fmaf(w0, x3.x, a3); a3 = fmaf(w1, x3.y, a3); a3 = fmaf(w2, x3.z, a3); a3 = fmaf(w3, x3.w, a3);
      }
      m = fmaxf(m, fmaxf(fmaxf(a0,a1), fmaxf(a2,a3)));
    }
  }
  partial[((size_t)b*1024 + o)*22 + segbase + chunk] = m;
}

__global__ void gred_kernel(const float* __restrict__ partial, float* __restrict__ g, int S){
  int i = blockIdx.x*256 + threadIdx.x;
  if (i >= 4*1024) return;
  const float* p = partial + (size_t)i*22;
  float m = NEG_BIG;
  for (int s = 0; s < S; s++) m = fmaxf(m, p[s]);
  g[i] = lrelu(m);
}

__global__ void gw_kernel(const float* __restrict__ g, const void* __restrict__ W13,
                          const int* __restrict__ dtf, float* __restrict__ gW){
  int o = blockIdx.x, b = blockIdx.y;
  int lane = threadIdx.x;
  int isbf = *dtf;
  const float* gb = g + b*1024;
  float acc = 0.f;
  for (int c = lane; c < 1024; c += 64)
    acc = fmaf(ldx(W13, (size_t)o*1088 + c, isbf), gb[c], acc);
  for (int s = 32; s > 0; s >>= 1) acc += __shfl_down(acc, s, 64);
  if (lane == 0) gW[b*256 + o] = acc;
}

// ---------------- decoder MLPs (fused unpool gather) ----------------
__global__ void mlp_kernel(const float* __restrict__ base,
    const float* __restrict__ in1, const int* __restrict__ idx1, int N1, int C1,
    const float* __restrict__ W1T,
    const float* __restrict__ in2, int C2, const float* __restrict__ W2T,
    float* __restrict__ outT, int N, int Cout){
  __shared__ float sIn[4*320];
  int o = threadIdx.x, b = blockIdx.y;
  int n0 = blockIdx.x*4;
  int Cin = C1 + C2;
  int mask1 = N1 - 1;
  for (int t = 0; t < 4; t++){
    int n = n0 + t;
    int r1 = idx1 ? (idx1[(size_t)b*N + n] & mask1) : n;
    const float* p1 = in1 + ((size_t)b*N1 + r1)*C1;
    for (int c = o; c < C1; c += Cout) sIn[t*Cin + c] = p1[c];
    if (in2){
      const float* p2 = in2 + ((size_t)b*N + n)*C2;
      for (int c = o; c < C2; c += Cout) sIn[t*Cin + C1 + c] = p2[c];
    }
  }
  __syncthreads();
  float init = base ? base[b*Cout + o] : 0.f;
  float a0 = init, a1 = init, a2 = init, a3 = init;
  for (int c = 0; c < C1; c++){
    float wv = W1T[c*Cout + o];
    a0 = fmaf(wv, sIn[0*Cin + c], a0);
    a1 = fmaf(wv, sIn[1*Cin + c], a1);
    a2 = fmaf(wv, sIn[2*Cin + c], a2);
    a3 = fmaf(wv, sIn[3*Cin + c], a3);
  }
  for (int c = 0; c < C2; c++){
    float wv = W2T[c*Cout + o];
    a0 = fmaf(wv, sIn[0*Cin + C1 + c], a0);
    a1 = fmaf(wv, sIn[1*Cin + C1 + c], a1);
    a2 = fmaf(wv, sIn[2*Cin + C1 + c], a2);
    a3 = fmaf(wv, sIn[3*Cin + C1 + c], a3);
  }
  size_t ob = ((size_t)b*N + n0)*Cout + o;
  outT[ob]          = lrelu(a0);
  outT[ob + Cout]   = lrelu(a1);
  outT[ob + 2*Cout] = lrelu(a2);
  outT[ob + 3*Cout] = lrelu(a3);
}

__global__ void dec0_kernel(const float* __restrict__ h1T, const int* __restrict__ idxU0,
                            const float* __restrict__ x0T, const float* __restrict__ W16T,
                            const void* __restrict__ W17, const int* __restrict__ dtf,
                            void* __restrict__ out){
  __shared__ float sIn[4*320];
  __shared__ float sH0[4*128];
  int o = threadIdx.x;   // 128 threads
  int b = blockIdx.y; int n0 = blockIdx.x*4;
  for (int t = 0; t < 4; t++){
    int n = n0 + t;
    int r1 = idxU0[(size_t)b*4096 + n] & 1023;
    const float* p1 = h1T + ((size_t)b*1024 + r1)*256;
    for (int c = o; c < 256; c += 128) sIn[t*320 + c] = p1[c];
    const float* p2 = x0T + ((size_t)b*4096 + n)*64;
    if (o < 64) sIn[t*320 + 256 + o] = p2[o];
  }
  __syncthreads();
  float a0 = 0.f, a1 = 0.f, a2 = 0.f, a3 = 0.f;
  for (int c = 0; c < 256; c++){
    float wv = W16T[c*128 + o];
    a0 = fmaf(wv, sIn[0*320 + c], a0);
    a1 = fmaf(wv, sIn[1*320 + c], a1);
    a2 = fmaf(wv, sIn[2*320 + c], a2);
    a3 = fmaf(wv, sIn[3*320 + c], a3);
  }
  for (int c = 0; c < 64; c++){
    float wv = W16T[(256 + c)*128 + o];
    a0 = fmaf(wv, sIn[0*320 + 256 + c], a0);
    a1 = fmaf(wv, sIn[1*320 + 256 + c], a1);
    a2 = fmaf(wv, sIn[2*320 + 256 + c], a2);
    a3 = fmaf(wv, sIn[3*320 + 256 + c], a3);
  }
  sH0[0*128 + o] = lrelu(a0);
  sH0[1*128 + o] = lrelu(a1);
  sH0[2*128 + o] = lrelu(a2);
  sH0[3*128 + o] = lrelu(a3);
  __syncthreads();
  if (o < 52){
    int isbf = *dtf;
    int p = o / 13, cc = o % 13;
    float acc = 0.f;
    for (int c2 = 0; c2 < 128; c2++)
      acc = fmaf(ldx(W17, (size_t)cc*128 + c2, isbf), sH0[p*128 + c2], acc);
    if (!(acc == acc && fabsf(acc) < 1e30f)) acc = 0.f;
    stout(out, ((size_t)b*13 + cc)*4096 + (n0 + p), acc, isbf);
  }
}

// ---------------- host ----------------
extern "C" void kernel_launch(void* const* d_in, const int* in_sizes, int n_in,
                              void* d_out, int out_size, void* d_ws, size_t ws_size,
                              hipStream_t stream){
  (void)in_sizes; (void)n_in; (void)out_size;
  const int B = 4;
  const void* X       = d_in[0];
  const void* w_ec1_0 = d_in[1];
  const void* w_ec1_1 = d_in[2];
  const void* w_ec2_0 = d_in[3];
  const void* w_ec2_1 = d_in[4];
  const void* w_ec4_0 = d_in[5];
  const void* w_ec4_1 = d_in[6];
  const void* w_ec5_0 = d_in[7];
  const void* w_ec5_1 = d_in[8];
  const void* w_ec7   = d_in[9];
  const void* w_ec8   = d_in[10];
  const void* w_ec10  = d_in[11];
  const void* w_ec11  = d_in[12];
  const void* w_pn3   = d_in[13];
  const void* w_pn6   = d_in[14];
  const void* w_pn9   = d_in[15];
  const void* w_pn12  = d_in[16];
  const void* w_pn13  = d_in[17];
  const void* w_pn14  = d_in[18];
  const void* w_pn15  = d_in[19];
  const void* w_pn16  = d_in[20];
  const void* w_c17   = d_in[21];
  void* out = d_out;

  // ---- workspace layout (fp32 words; lifetime-aliased) ----
  float* wsf = (float*)d_ws;
  size_t off = 0;
  auto alloc = [&](size_t n)->float*{
    float* p = wsf + off; off += (n + 63) & ~(size_t)63; return p;
  };
  int*   dtf = (int*)alloc(64);
  float* xfT = alloc(4*4096*9);
  float* rr  = alloc(4*4096);
  float* partial = alloc(4*1024*22);
  float* g   = alloc(4*1024);
  float* gW  = alloc(4*256);
  int*   idx = (int*)alloc(4*4096*20);
  int*   idxU2 = (int*)alloc(4*256);
  int*   idxU1 = (int*)alloc(4*1024);
  int*   idxU0 = (int*)alloc(4*4096);
  float* ec1a = alloc(9*64);  float* ec1q = alloc(9*64);  float* ec1w1 = alloc(64*64);
  float* ec2a = alloc(64*64); float* ec2q = alloc(64*64); float* ec2w1 = alloc(64*64);
  float* ec4a = alloc(64*64); float* ec4q = alloc(64*64); float* ec4w1 = alloc(64*64);
  float* ec5a = alloc(64*64); float* ec5q = alloc(64*64); float* ec5w1 = alloc(64*64);
  float* ec7a = alloc(64*64); float* ec7q = alloc(64*64);
  float* ec8a = alloc(64*64); float* ec8q = alloc(64*64);
  float* ec10a = alloc(64*64); float* ec10q = alloc(64*64);
  float* ec11a = alloc(64*64); float* ec11q = alloc(64*64);
  float* wp13 = alloc(64*256);
  float* wt14 = alloc(320*256);
  float* wt15 = alloc(320*256);
  float* wt16 = alloc(320*128);
  float* P   = alloc(4*4096*64);
  float* hA  = alloc(4*4096*64);    // decoder: h1T alias (exact size)
  float* x0T = alloc(4*4096*64);
  float* x1T = alloc(4*1024*64);
  float* x2T = alloc(4*256*64);
  float* x3T = alloc(4*64*64);
  float* n1f = alloc(4*1024*64);    // decoder: h3T + head of h2T
  float* n2f = alloc(4*256*64);     // contiguous after n1f; h2T tail
  float* n3f = alloc(4*64*64);
  u16*   bhi = (u16*)alloc(4*4096*64/2);   // bf16 hi split (pre-swizzled), 2 MB
  u16*   blo = (u16*)alloc(4*4096*64/2);   // bf16 lo split (pre-swizzled), 2 MB
  float* h1T = hA;
  float* h3T = n1f;
  float* h2T = n1f + 65536;

  // ws-aware candidate sizing (ws_size constant across calls)
  size_t rem = (ws_size/4 > off + 256) ? (ws_size/4 - off - 256) : 0;
  size_t half = rem / 2;
  int NCbig = (half >= (size_t)4*4096*16*20) ? 16 :
              (half >= (size_t)4*4096*8*20)  ? 8  : 4;
  size_t E = (size_t)4*4096*20*NCbig;
  float* cval = alloc(E);
  int*   cidx = (int*)alloc(E);

  detect_kernel<<<dim3(1), 256, 0, stream>>>((const unsigned int*)X, dtf);

  // ---- weight prep ----
  w0_kernel<<<dim3(3), 256, 0, stream>>>(w_ec1_0, dtf, 9, ec1a, ec1q);
  w0_kernel<<<dim3(16), 256, 0, stream>>>(w_ec2_0, dtf, 64, ec2a, ec2q);
  w0_kernel<<<dim3(16), 256, 0, stream>>>(w_ec4_0, dtf, 64, ec4a, ec4q);
  w0_kernel<<<dim3(16), 256, 0, stream>>>(w_ec5_0, dtf, 64, ec5a, ec5q);
  w0_kernel<<<dim3(16), 256, 0, stream>>>(w_ec7, dtf, 64, ec7a, ec7q);
  w0_kernel<<<dim3(16), 256, 0, stream>>>(w_ec8, dtf, 64, ec8a, ec8q);
  w0_kernel<<<dim3(16), 256, 0, stream>>>(w_ec10, dtf, 64, ec10a, ec10q);
  w0_kernel<<<dim3(16), 256, 0, stream>>>(w_ec11, dtf, 64, ec11a, ec11q);
  wt_kernel<<<dim3(16), 256, 0, stream>>>(w_ec1_1, dtf, 64, 64, 0, 64, ec1w1);
  wt_kernel<<<dim3(16), 256, 0, stream>>>(w_ec2_1, dtf, 64, 64, 0, 64, ec2w1);
  wt_kernel<<<dim3(16), 256, 0, stream>>>(w_ec4_1, dtf, 64, 64, 0, 64, ec4w1);
  wt_kernel<<<dim3(16), 256, 0, stream>>>(w_ec5_1, dtf, 64, 64, 0, 64, ec5w1);
  wt_kernel<<<dim3(64), 256, 0, stream>>>(w_pn13, dtf, 256, 1088, 1024, 64, wp13);
  wt_kernel<<<dim3(320), 256, 0, stream>>>(w_pn14, dtf, 256, 320, 0, 320, wt14);
  wt_kernel<<<dim3(320), 256, 0, stream>>>(w_pn15, dtf, 256, 320, 0, 320, wt15);
  wt_kernel<<<dim3(160), 256, 0, stream>>>(w_pn16, dtf, 128, 320, 0, 320, wt16);

  xconv_kernel<<<dim3(64), 256, 0, stream>>>(X, dtf, xfT);
  nodecopy_kernel<<<dim3(64), 256, 0, stream>>>(X, dtf, out);

  const size_t xbs = (size_t)4096*9;
  // coord-space kNN on xfT (pitch 9). len=N/NC must be multiple of 64.
  auto knn_f = [&](int C, int K, int M, int N, int NC, int* io){
    rownorm_kernel<<<dim3((N+255)/256, B), 256, 0, stream>>>(xfT, 9, xbs, C, N, rr);
    dim3 gd((M+255)/256, NC, B);
    if (C == 9)      knn_chunk_kernel<9,20,64><<<gd,256,0,stream>>>(xfT,9,xbs,xfT,9,xbs,rr,M,N,NC,cval,cidx);
    else if (K==20)  knn_chunk_kernel<3,20,64><<<gd,256,0,stream>>>(xfT,9,xbs,xfT,9,xbs,rr,M,N,NC,cval,cidx);
    else             knn_chunk_kernel<3,1,64><<<gd,256,0,stream>>>(xfT,9,xbs,xfT,9,xbs,rr,M,N,NC,cval,cidx);
    dim3 gm((4*M+255)/256);
    if (K == 20)     knn_merge_kernel<20,false><<<gm,256,0,stream>>>(cval,cidx,M,NC,io);
    else             knn_merge_kernel<1,false><<<gm,256,0,stream>>>(cval,cidx,M,NC,io);
  };
  // feature-space self-kNN (C=64).
  // N>=1024: MFMA path (bf16 hi/lo split + tau-filtered LDS-FIFO selection), emits
  //          NC*4 virtual chunks, exact merge with index tie-break.
  // N<=256 : legacy scalar knn64 path (already cheap).
  auto knn_b = [&](int K, const float* fT, int N, int NC, int* io){
    rownorm_kernel<<<dim3((N+255)/256, B), 256, 0, stream>>>(fT, 64, (size_t)N*64, 64, N, rr);
    if (K == 20 && N >= 1024){
      int NCm = NCbig / 4; if (NCm < 1) NCm = 1;     // NC*4 virtual chunks must fit cval
      int cap = (N == 4096) ? 2 : 4;
      if (NCm > cap) NCm = cap;
      bfsplit_kernel<<<dim3((4*N*64)/256), 256, 0, stream>>>(fT, N, bhi, blo);
      knnmf_kernel<20><<<dim3(N/64, NCm, B), 256, 0, stream>>>(bhi, blo, rr, N, NCm, cval, cidx);
      knn_merge_kernel<20,true><<<dim3((4*N+255)/256), 256, 0, stream>>>(cval, cidx, N, NCm*4, io);
    } else {
      dim3 gd(N/64, NC, B);
      if (K == 20) knn64_kernel<20><<<gd,64,0,stream>>>(fT, rr, N, NC, cval, cidx);
      else         knn64_kernel<10><<<gd,64,0,stream>>>(fT, rr, N, NC, cval, cidx);
      dim3 gm((4*N+255)/256);
      if (K == 20) knn_merge_kernel<20,false><<<gm,256,0,stream>>>(cval,cidx,N,NC,io);
      else         knn_merge_kernel<10,false><<<gm,256,0,stream>>>(cval,cidx,N,NC,io);
    }
  };
  auto edge2_b = [&](const float* fT, int N, int NC, float* wa, float* wq, float* w1, float* oT){
    knn_b(20, fT, N, NC, idx);
    pq_kernel<<<dim3((N+3)/4, B), 256, 0, stream>>>(fT, 64, 64, wa, P, N);
    edge2_kernel<<<dim3(N/4, B), 256, 0, stream>>>(P, fT, 64, 64, wq, idx, w1, oT, N, N-1);
  };
  auto edge1_b = [&](const float* fT, int N, int NC, int K, float* wa, float* wq, float* oT){
    knn_b(K, fT, N, NC, idx);
    pq_kernel<<<dim3((N+3)/4, B), 256, 0, stream>>>(fT, 64, 64, wa, P, N);
    edge1_kernel<<<dim3(N/4, B), 256, 0, stream>>>(P, fT, 64, 64, wq, idx, oT, N, K, N-1);
  };

  // level 0
  int nc9 = (NCbig < 8) ? NCbig : 8;                     // len 512: halves redundant fill work
  knn_f(9, 20, 4096, 4096, nc9, idx);
  pq_kernel<<<dim3(1024, B), 256, 0, stream>>>(xfT, 9, 9, ec1a, P, 4096);
  edge2_kernel<<<dim3(1024, B), 256, 0, stream>>>(P, xfT, 9, 9, ec1q, idx, ec1w1, hA, 4096, 4095);
  edge2_b(hA, 4096, NCbig, ec2a, ec2q, ec2w1, x0T);
  pool_kernel<<<dim3(4,16,4), 256, 0, stream>>>(x0T, w_pn3, dtf, partial, 4096, 256, 0);
  // rand_pool 1
  knn_f(3, 20, 1024, 4096, 16, idx);                     // len 256
  gmax_kernel<<<dim3(1024, B), 64, 0, stream>>>(x0T, idx, n1f, 4096, 1024, 20, 4095);
  // level 1
  edge2_b(n1f, 1024, 16, ec4a, ec4q, ec4w1, hA);
  edge2_b(hA, 1024, 16, ec5a, ec5q, ec5w1, x1T);
  pool_kernel<<<dim3(4,4,4), 256, 0, stream>>>(x1T, w_pn6, dtf, partial, 1024, 256, 16);
  reluadd_kernel<<<dim3(1024), 256, 0, stream>>>(x1T, n1f, 4*1024*64);
  // rand_pool 2
  knn_f(3, 20, 256, 1024, 16, idx);                      // len 64
  gmax_kernel<<<dim3(256, B), 64, 0, stream>>>(x1T, idx, n2f, 1024, 256, 20, 1023);
  // level 2
  edge1_b(n2f, 256, 16, 20, ec7a, ec7q, hA);             // len 16
  edge1_b(hA, 256, 16, 20, ec8a, ec8q, x2T);
  pool_kernel<<<dim3(4,1,4), 256, 0, stream>>>(x2T, w_pn9, dtf, partial, 256, 256, 20);
  reluadd_kernel<<<dim3(256), 256, 0, stream>>>(x2T, n2f, 4*256*64);
  // rand_pool 3
  knn_f(3, 20, 64, 256, 4, idx);                         // len 64 (chunk TN bound)
  gmax_kernel<<<dim3(64, B), 64, 0, stream>>>(x2T, idx, n3f, 256, 64, 20, 255);
  // level 3
  edge1_b(n3f, 64, 8, 10, ec10a, ec10q, hA);             // len 8
  edge1_b(hA, 64, 8, 10, ec11a, ec11q, x3T);
  pool_kernel<<<dim3(4,1,4), 256, 0, stream>>>(x3T, w_pn12, dtf, partial, 64, 64, 21);
  reluadd_kernel<<<dim3(64), 256, 0, stream>>>(x3T, n3f, 4*64*64);
  // ---- idx, P, hA, n1f, n2f dead -> h3T/h2T/h1T aliases live ----
  gred_kernel<<<dim3(16), 256, 0, stream>>>(partial, g, 22);
  gw_kernel<<<dim3(256, 4), 64, 0, stream>>>(g, w_pn13, dtf, gW);
  mlp_kernel<<<dim3(16, B), 256, 0, stream>>>(gW, x3T, nullptr, 64, 64, wp13,
                                              nullptr, 0, nullptr, h3T, 64, 256);
  knn_f(3, 1, 256, 64, 1, idxU2);                        // len 64
  mlp_kernel<<<dim3(64, B), 256, 0, stream>>>(nullptr, h3T, idxU2, 64, 256, wt14,
                                              x2T, 64, wt14 + 256*256, h2T, 256, 256);
  knn_f(3, 1, 1024, 256, 4, idxU1);                      // len 64
  mlp_kernel<<<dim3(256, B), 256, 0, stream>>>(nullptr, h2T, idxU1, 256, 256, wt15,
                                               x1T, 64, wt15 + 256*256, h1T, 1024, 256);
  knn_f(3, 1, 4096, 1024, 4, idxU0);                     // len 256
  dec0_kernel<<<dim3(1024, B), 128, 0, stream>>>(h1T, idxU0, x0T, wt16, w_c17, dtf, out);
}

// Round 10
// 2990.088 us; speedup vs baseline: 1.1149x; 1.0027x over previous
//
#include <hip/hip_runtime.h>
#include <hip/hip_bf16.h>
#include <float.h>

typedef __hip_bfloat16 bf16;
typedef unsigned short u16;
typedef unsigned long long u64;
typedef __attribute__((ext_vector_type(8))) short bh8;   // 8 bf16 = 4 VGPRs (MFMA A/B frag)
typedef __attribute__((ext_vector_type(4))) float fx4;   // MFMA C/D frag

#define NEG_BIG (-1.0e30f)

__device__ __forceinline__ bf16 f2b(float v){ return __float2bfloat16(v); }
__device__ __forceinline__ float lrelu(float x){ return x >= 0.f ? x : 0.2f*x; }

// round-to-nearest-even fp32 -> bf16 bits
__device__ __forceinline__ u16 f2bf_rne(float x){
  unsigned u = __float_as_uint(x);
  unsigned r = (u + 0x7FFFu + ((u >> 16) & 1u)) >> 16;
  return (u16)r;
}

// dtype-flexible sanitized load from a raw INPUT buffer (element index)
__device__ __forceinline__ float ldx(const void* p, size_t i, int isbf){
  float v = isbf ? __bfloat162float(((const bf16*)p)[i]) : ((const float*)p)[i];
  return (v == v && fabsf(v) < 1e30f) ? v : 0.f;
}
// dtype-flexible store to the OUTPUT buffer (element index)
__device__ __forceinline__ void stout(void* p, size_t i, float v, int isbf){
  if (isbf) ((bf16*)p)[i] = f2b(v);
  else      ((float*)p)[i] = v;
}

// carry-chain sorted top-K insert (bv descending, bv[K-1] = min).
// TB=false: strict > (equal values keep earlier-scanned = lower index when scan is
// index-ordered). TB=true: explicit (value, lower-index) tie-break, order-independent.
// NOTE (r5-r8 lesson): packed-u64 key variants of this chain are NOT cheaper on CDNA
// (u64 cmp = 2 ops, u64 cndmask = 2x b32) — keep the float/int dual chain.
template<int K, bool TB>
__device__ __forceinline__ void topk_ins_t(float (&bv)[K], int (&bi)[K], float d, int j){
  bool gate = TB ? (d > bv[K-1] || (d == bv[K-1] && j < bi[K-1])) : (d > bv[K-1]);
  if (gate){
    bool gt[K];
    #pragma unroll
    for (int s = 0; s < K; s++)
      gt[s] = TB ? (d > bv[s] || (d == bv[s] && j < bi[s])) : (d > bv[s]);
    #pragma unroll
    for (int s = K-1; s > 0; s--){
      float nv = gt[s-1] ? bv[s-1] : d;
      int   ni = gt[s-1] ? bi[s-1] : j;
      bv[s] = gt[s] ? nv : bv[s];
      bi[s] = gt[s] ? ni : bi[s];
    }
    if (gt[0]){ bv[0] = d; bi[0] = j; }
  }
}
template<int K>
__device__ __forceinline__ void topk_ins(float (&bv)[K], int (&bi)[K], float d, int j){
  topk_ins_t<K,false>(bv, bi, d, j);
}

// ---------------- input dtype detector ----------------
__global__ void detect_kernel(const unsigned int* __restrict__ X, int* __restrict__ flag){
  __shared__ int cnt;
  if (threadIdx.x == 0) cnt = 0;
  __syncthreads();
  int hits = 0;
  for (int i = threadIdx.x; i < 8192; i += 256){
    unsigned w = X[i];
    unsigned lo = w & 0xFFFFu;
    unsigned e = (lo >> 7) & 0xFFu;
    if ((e >= 0x76u && e <= 0x84u) || lo == 0u) hits++;
  }
  atomicAdd(&cnt, hits);
  __syncthreads();
  if (threadIdx.x == 0) flag[0] = (cnt > 4096) ? 1 : 0;
}

// ---------------- weight prep ----------------
__global__ void wt_kernel(const void* __restrict__ W, const int* __restrict__ dtf,
                          int Cout, int pitch, int coff, int Cin, float* __restrict__ WT){
  int i = blockIdx.x*256 + threadIdx.x;
  if (i >= Cin*Cout) return;
  int isbf = *dtf;
  int c = i / Cout, o = i - c*Cout;
  WT[i] = ldx(W, (size_t)o*pitch + coff + c, isbf);
}

__global__ void w0_kernel(const void* __restrict__ W0, const int* __restrict__ dtf,
                          int C, float* __restrict__ WaT, float* __restrict__ WqT){
  int i = blockIdx.x*256 + threadIdx.x;
  if (i >= C*64) return;
  int isbf = *dtf;
  int c = i >> 6, o = i & 63;
  float a = ldx(W0, (size_t)o*2*C + c, isbf);
  float q = ldx(W0, (size_t)o*2*C + C + c, isbf);
  WaT[i] = a; WqT[i] = q - a;
}

__global__ void xconv_kernel(const void* __restrict__ x, const int* __restrict__ dtf,
                             float* __restrict__ xfT){
  int i = blockIdx.x*256 + threadIdx.x;
  if (i >= 4*4096) return;
  int isbf = *dtf;
  int b = i >> 12, n = i & 4095;
  for (int c = 0; c < 9; c++)
    xfT[((size_t)b*4096 + n)*9 + c] = ldx(x, ((size_t)b*9 + c)*4096 + n, isbf);
}

__global__ void nodecopy_kernel(const void* __restrict__ x, const int* __restrict__ dtf,
                                void* __restrict__ out){
  int i = blockIdx.x*256 + threadIdx.x;
  int isbf = *dtf;
  if (i < 12288){
    int b = i / 3072, r = i % 3072; int c = r / 1024, m = r % 1024;
    stout(out, 212992 + i, ldx(x, ((size_t)b*9 + c)*4096 + m, isbf), isbf);
  } else if (i < 15360){
    int j = i - 12288; int b = j / 768, r = j % 768; int c = r / 256, m = r % 256;
    stout(out, 212992 + i, ldx(x, ((size_t)b*9 + c)*4096 + m, isbf), isbf);
  } else if (i < 16128){
    int j = i - 15360; int b = j / 192, r = j % 192; int c = r / 64, m = r % 64;
    stout(out, 212992 + i, ldx(x, ((size_t)b*9 + c)*4096 + m, isbf), isbf);
  }
}

// ---------------- kNN ----------------
__global__ void rownorm_kernel(const float* __restrict__ T, int pitch, size_t bs,
                               int C, int N, float* __restrict__ rr){
  int n = blockIdx.x*256 + threadIdx.x;
  int b = blockIdx.y;
  if (n >= N) return;
  const float* row = T + (size_t)b*bs + (size_t)n*pitch;
  float s = 0.f;
  for (int c = 0; c < C; c++) s = fmaf(row[c], row[c], s);
  rr[b*N + n] = s;
}

// small-C chunked kNN (C=3/9; per-thread query in registers, refs staged in LDS).
// Refs staged TRANSPOSED [c][t]: wave-uniform ds_read_b128 broadcasts (4 cands/read).
// K>=8: tau-gated per-thread LDS FIFO (CAP=8; occupancy — r9 lesson: the 16-entry
//   FIFO's 34KB LDS capped blocks/CU) + per-tile drains + overflow drain guard
//   (per 4-candidate group, max 4 pushes -> capacity provably sufficient).
//   Exact: stale tau (== bv[K-1] at last drain) is only more permissive; FIFO drain
//   preserves ascending-j order so strict-> insert keeps lax.top_k tie semantics.
// REQUIREMENT: len = N/NC must be a multiple of TN.
template<int C, int K, int TN>
__global__ void knn_chunk_kernel(const float* __restrict__ qT, int qpitch, size_t qbs,
                                 const float* __restrict__ rT, int rpitch, size_t rbs,
                                 const float* __restrict__ rr, int M, int N, int NC,
                                 float* __restrict__ cval, int* __restrict__ cidx){
  constexpr bool FIFO = (K >= 8);
  constexpr int CAP = 8;
  __shared__ __align__(16) float sRT[C*TN];   // [c][t]
  __shared__ __align__(16) float sN[TN];
  __shared__ u64 sQ[FIFO ? 256*(CAP+1) : 1];  // per-thread FIFO, stride 9 u64 (18 KB)
  int tid = threadIdx.x;
  int m = blockIdx.x*256 + tid;
  int cid = blockIdx.y, b = blockIdx.z;
  int len = N / NC;
  int n0 = cid * len;
  bool active = (m < M);
  float q[C]; float qq = 0.f;
  if (active){
    const float* qrow = qT + (size_t)b*qbs + (size_t)m*qpitch;
    #pragma unroll
    for (int c = 0; c < C; c++){ q[c] = qrow[c]; qq = fmaf(q[c], q[c], qq); }
  }
  float bv[K]; int bi[K];
  #pragma unroll
  for (int j = 0; j < K; j++){ bv[j] = NEG_BIG; bi[j] = n0; }
  float tau = NEG_BIG;
  u64* qb = FIFO ? &sQ[tid*(CAP+1)] : (u64*)nullptr;
  int qcnt = 0;
  const float* rbase = rT + (size_t)b*rbs;
  const float* rrb = rr + b*N;

  auto drain = [&](){
    int k = 0;
    while (__any(k < qcnt)){
      if (k < qcnt){
        u64 e = qb[k];
        float d = __uint_as_float((unsigned)(e >> 32));
        int j = (int)(unsigned)e;
        topk_ins_t<K,false>(bv, bi, d, j);
      }
      k++;
    }
    qcnt = 0;
    tau = bv[K-1];
  };

  for (int t0 = 0; t0 < len; t0 += TN){
    __syncthreads();
    for (int i = tid; i < TN*C; i += 256){
      int c = i / TN, t = i - c*TN;
      sRT[i] = rbase[(size_t)(n0 + t0 + t)*rpitch + c];
    }
    for (int i = tid; i < TN; i += 256) sN[i] = rrb[n0 + t0 + i];
    __syncthreads();
    if (active){
      for (int t = 0; t < TN; t += 4){
        float a0 = 0.f, a1 = 0.f, a2 = 0.f, a3 = 0.f;
        #pragma unroll
        for (int c = 0; c < C; c++){
          float4 rv = *(const float4*)&sRT[c*TN + t];
          float qc = q[c];
          a0 = fmaf(qc, rv.x, a0); a1 = fmaf(qc, rv.y, a1);
          a2 = fmaf(qc, rv.z, a2); a3 = fmaf(qc, rv.w, a3);
        }
        float4 nn = *(const float4*)&sN[t];
        int jb = n0 + t0 + t;
        float d0 = 2.f*a0 - qq - nn.x;
        float d1 = 2.f*a1 - qq - nn.y;
        float d2 = 2.f*a2 - qq - nn.z;
        float d3 = 2.f*a3 - qq - nn.w;
        if constexpr (FIFO){
          if (__any(qcnt >= CAP-4)) drain();    // guarantees room for 4
          if (d0 > tau){ qb[qcnt] = (((u64)__float_as_uint(d0))<<32) | (unsigned)(jb+0); qcnt++; }
          if (d1 > tau){ qb[qcnt] = (((u64)__float_as_uint(d1))<<32) | (unsigned)(jb+1); qcnt++; }
          if (d2 > tau){ qb[qcnt] = (((u64)__float_as_uint(d2))<<32) | (unsigned)(jb+2); qcnt++; }
          if (d3 > tau){ qb[qcnt] = (((u64)__float_as_uint(d3))<<32) | (unsigned)(jb+3); qcnt++; }
        } else {
          topk_ins<K>(bv, bi, d0, jb+0);
          topk_ins<K>(bv, bi, d1, jb+1);
          topk_ins<K>(bv, bi, d2, jb+2);
          topk_ins<K>(bv, bi, d3, jb+3);
        }
      }
    }
    if constexpr (FIFO){ drain(); }             // inactive lanes: qcnt==0, no-op
  }
  if (active){
    float* ov = cval + ((size_t)((size_t)b*M + m)*NC + cid)*K;
    int*   oi = cidx + ((size_t)((size_t)b*M + m)*NC + cid)*K;
    #pragma unroll
    for (int j = 0; j < K; j++){ ov[j] = bv[j]; oi[j] = bi[j]; }
  }
}

// C=64 self-kNN scan (legacy path, kept for N<=256): 1-wave blocks, queries in VGPRs.
template<int K>
__launch_bounds__(64, 2)
__global__ void knn64_kernel(const float* __restrict__ fT, const float* __restrict__ rr,
                             int N, int NC, float* __restrict__ cval, int* __restrict__ cidx){
  int lane = threadIdx.x;
  int q0 = blockIdx.x*64;
  int cid = blockIdx.y, b = blockIdx.z;
  int m = q0 + lane;
  int len = N / NC;
  int n0 = cid*len;
  float4 q4[16];
  {
    const float4* qp = (const float4*)(fT + ((size_t)b*N + m)*64);
    #pragma unroll
    for (int i = 0; i < 16; i++) q4[i] = qp[i];
  }
  float qq = rr[(size_t)b*N + m];   // self-kNN (M==N)
  float bv[K]; int bi[K];
  #pragma unroll
  for (int j = 0; j < K; j++){ bv[j] = NEG_BIG; bi[j] = n0; }
  const float4* rbase = (const float4*)(fT + ((size_t)b*N + n0)*64);
  const float* rrb = rr + (size_t)b*N + n0;
  for (int t0 = 0; t0 < len; t0 += 4){
    const float4* r4 = rbase + (size_t)t0*16;
    float a0=0.f, a1=0.f, a2=0.f, a3=0.f;
    #pragma unroll
    for (int ct = 0; ct < 16; ct++){
      float4 v0 = r4[ct], v1 = r4[16+ct], v2 = r4[32+ct], v3 = r4[48+ct];
      float4 qv = q4[ct];
      a0 = fmaf(qv.x,v0.x,a0); a0 = fmaf(qv.y,v0.y,a0); a0 = fmaf(qv.z,v0.z,a0); a0 = fmaf(qv.w,v0.w,a0);
      a1 = fmaf(qv.x,v1.x,a1); a1 = fmaf(qv.y,v1.y,a1); a1 = fmaf(qv.z,v1.z,a1); a1 = fmaf(qv.w,v1.w,a1);
      a2 = fmaf(qv.x,v2.x,a2); a2 = fmaf(qv.y,v2.y,a2); a2 = fmaf(qv.z,v2.z,a2); a2 = fmaf(qv.w,v2.w,a2);
      a3 = fmaf(qv.x,v3.x,a3); a3 = fmaf(qv.y,v3.y,a3); a3 = fmaf(qv.z,v3.z,a3); a3 = fmaf(qv.w,v3.w,a3);
    }
    topk_ins<K>(bv, bi, 2.f*a0 - qq - rrb[t0+0], n0+t0+0);
    topk_ins<K>(bv, bi, 2.f*a1 - qq - rrb[t0+1], n0+t0+1);
    topk_ins<K>(bv, bi, 2.f*a2 - qq - rrb[t0+2], n0+t0+2);
    topk_ins<K>(bv, bi, 2.f*a3 - qq - rrb[t0+3], n0+t0+3);
  }
  float* ov = cval + ((size_t)((size_t)b*N + m)*NC + cid)*K;
  int*   oi = cidx + ((size_t)((size_t)b*N + m)*NC + cid)*K;
  #pragma unroll
  for (int j = 0; j < K; j++){ ov[j] = bv[j]; oi[j] = bi[j]; }
}

// fp32 -> (hi, lo) bf16 split, stored PRE-SWIZZLED (c ^= (row&7)<<3) so that the
// kNN MFMA kernel can stage LDS tiles with linear copies and read ds_read_b128
// fragments bank-conflict-optimally (G4/T2 recipe).
__global__ void bfsplit_kernel(const float* __restrict__ fT, int N,
                               u16* __restrict__ hi, u16* __restrict__ lo){
  int i = blockIdx.x*256 + threadIdx.x;      // over 4*N*64
  if (i >= 4*N*64) return;
  int c = i & 63;
  int n = i >> 6;                            // combined row b*N + ln; N % 8 == 0 so n&7 == ln&7
  float x = fT[i];
  u16 h = f2bf_rne(x);
  float hf = __uint_as_float((unsigned)h << 16);
  u16 l = f2bf_rne(x - hf);
  size_t o = ((size_t)n << 6) + (c ^ ((n & 7) << 3));
  hi[o] = h; lo[o] = l;
}

// MFMA feature-space self-kNN (C=64).  exact-ish distances via bf16 hi/lo split:
// inner = hi·hi + hi·lo + lo·hi (3x mfma_f32_16x16x32_bf16, fp32 accum, rel err ~2^-17).
// D[ref][query] orientation: lane = (g=l>>4, lm=l&15) holds query (qblk+w*16+lm)'s
// distances for refs {tile + m*16 + 4g + i}.
// Selection:
//  * shared threshold tau = max over the 4 partition-lanes (lm, lm+16, lm+32, lm+48)
//    of their local bv[K-1], refreshed per tile via 2x shfl_xor.  Exact: any candidate
//    strictly below tau is below the query's final K-th value.
//  * candidates passing tau go to a per-thread CAP=8 LDS FIFO (r9 occupancy lesson:
//    CAP=16's 34KB LDS capped residency at ~2 blocks/CU with VALUBusy 62%).  Guard
//    before each m-step (max 4 pushes) drains when any lane is near-full -> capacity
//    provably sufficient; mid-tile drains leave tau unchanged (still valid).
//  * FIFO drain preserves ascending-j order -> strict-> insert (no tie-break chain);
//    cross-partition ties resolved exactly by the TB=true merge.
template<int K>
__launch_bounds__(256, 4)
__global__ void knnmf_kernel(const u16* __restrict__ hi, const u16* __restrict__ lo,
                             const float* __restrict__ rr, int N, int NC,
                             float* __restrict__ cval, int* __restrict__ cidx){
  constexpr int CAP = 8;
  __shared__ __align__(16) u16 sHi[64*64];     // 8 KB, swizzled rows
  __shared__ __align__(16) u16 sLo[64*64];     // 8 KB
  __shared__ float sRR[64];
  __shared__ u64 sQ[256*(CAP+1)];              // per-thread 8-entry FIFO, stride 9 (18 KB)

  const int tid  = threadIdx.x;
  const int lane = tid & 63, w = tid >> 6;
  const int g    = lane >> 4;                  // 0..3
  const int lm   = lane & 15;
  const int qblk = blockIdx.x * 64;
  const int cid  = blockIdx.y, b = blockIdx.z;
  const int len  = N / NC, n0 = cid * len;

  const u16*  hib = hi + (size_t)b*N*64;
  const u16*  lob = lo + (size_t)b*N*64;
  const float* rrb = rr + (size_t)b*N;

  // ---- stage this block's 64 query rows, pull B-fragments into registers ----
  {
    const float4* sh = (const float4*)(hib + (size_t)qblk*64);
    const float4* sl = (const float4*)(lob + (size_t)qblk*64);
    float4* dh = (float4*)sHi; float4* dl = (float4*)sLo;
    for (int i = tid; i < 512; i += 256){ dh[i] = sh[i]; dl[i] = sl[i]; }
  }
  __syncthreads();
  const int qrow = w*16 + lm;                  // wave w owns queries qblk + w*16 .. +15
  const int kb0 = 8*g, kb1 = 32 + 8*g;         // frag k-offsets: k = koff + 8*(lane>>4) + i
  const int qsw = (qrow & 7) << 3;
  const bh8 qh0 = *(const bh8*)&sHi[qrow*64 + (kb0 ^ qsw)];
  const bh8 qh1 = *(const bh8*)&sHi[qrow*64 + (kb1 ^ qsw)];
  const bh8 ql0 = *(const bh8*)&sLo[qrow*64 + (kb0 ^ qsw)];
  const bh8 ql1 = *(const bh8*)&sLo[qrow*64 + (kb1 ^ qsw)];
  const float qq = rrb[qblk + qrow];

  float bv[K]; int bi[K];
  #pragma unroll
  for (int j = 0; j < K; j++){ bv[j] = NEG_BIG; bi[j] = n0; }
  float tau = NEG_BIG;                         // shared (4-partition) running K-th value
  u64* qbase = &sQ[tid*(CAP+1)];
  int qcnt = 0;

  // drain FIFOs into the sorted chain; tau NOT touched here (mid-tile safe)
  auto drainq = [&](){
    int k = 0;
    while (__any(k < qcnt)){
      if (k < qcnt){
        u64 e = qbase[k];
        float d = __uint_as_float((unsigned)(e >> 32));
        int j = (int)(unsigned)e;
        topk_ins_t<K,false>(bv, bi, d, j);
      }
      k++;
    }
    qcnt = 0;
  };

  for (int t0 = n0; t0 < n0 + len; t0 += 64){
    __syncthreads();                           // previous tile's frag reads done
    {
      const float4* sh = (const float4*)(hib + (size_t)t0*64);
      const float4* sl = (const float4*)(lob + (size_t)t0*64);
      float4* dh = (float4*)sHi; float4* dl = (float4*)sLo;
      for (int i = tid; i < 512; i += 256){ dh[i] = sh[i]; dl[i] = sl[i]; }
      if (tid < 64) sRR[tid] = rrb[t0 + tid];
    }
    __syncthreads();
    for (int m = 0; m < 4; m++){
      const int rrow = m*16 + lm;              // A-frag row owned by this lane
      const int sw = (rrow & 7) << 3;
      const bh8 ah0 = *(const bh8*)&sHi[rrow*64 + (kb0 ^ sw)];
      const bh8 ah1 = *(const bh8*)&sHi[rrow*64 + (kb1 ^ sw)];
      const bh8 al0 = *(const bh8*)&sLo[rrow*64 + (kb0 ^ sw)];
      const bh8 al1 = *(const bh8*)&sLo[rrow*64 + (kb1 ^ sw)];
      fx4 acc = {0.f, 0.f, 0.f, 0.f};
      acc = __builtin_amdgcn_mfma_f32_16x16x32_bf16(ah0, qh0, acc, 0, 0, 0);
      acc = __builtin_amdgcn_mfma_f32_16x16x32_bf16(ah1, qh1, acc, 0, 0, 0);
      acc = __builtin_amdgcn_mfma_f32_16x16x32_bf16(ah0, ql0, acc, 0, 0, 0);
      acc = __builtin_amdgcn_mfma_f32_16x16x32_bf16(ah1, ql1, acc, 0, 0, 0);
      acc = __builtin_amdgcn_mfma_f32_16x16x32_bf16(al0, qh0, acc, 0, 0, 0);
      acc = __builtin_amdgcn_mfma_f32_16x16x32_bf16(al1, qh1, acc, 0, 0, 0);
      const float4 rr4 = *(const float4*)&sRR[m*16 + 4*g];   // broadcast within 16-lane group
      const float rrv[4] = {rr4.x, rr4.y, rr4.z, rr4.w};
      const int jb = t0 + m*16 + 4*g;          // C/D rows: lane holds rows 4g+i
      if (__any(qcnt >= CAP-4)) drainq();      // guarantees room for 4 pushes
      #pragma unroll
      for (int i = 0; i < 4; i++){
        float d = fmaf(2.f, acc[i], -(qq + rrv[i]));
        if (d >= tau){                         // >= keeps boundary ties (exactness)
          qbase[qcnt] = (((u64)__float_as_uint(d)) << 32) | (unsigned)(jb + i);
          qcnt++;
        }
      }
    }
    // per-tile drain + shared-threshold refresh
    drainq();
    {
      float t = bv[K-1];
      t = fmaxf(t, __shfl_xor(t, 16));
      t = fmaxf(t, __shfl_xor(t, 32));
      tau = t;
    }
  }
  const int q = qblk + qrow;
  const size_t rowo = (((size_t)b*N + q)*(size_t)(NC*4) + (size_t)(cid*4 + g))*(size_t)K;
  float* ov = cval + rowo; int* oi = cidx + rowo;
  #pragma unroll
  for (int j = 0; j < K; j++){ ov[j] = bv[j]; oi[j] = bi[j]; }
}

template<int K, bool TB>
__global__ void knn_merge_kernel(const float* __restrict__ cval, const int* __restrict__ cidx,
                                 int M, int NC, int* __restrict__ idxo){
  int i = blockIdx.x*256 + threadIdx.x;   // b*M + m
  if (i >= 4*M) return;
  const float* cv = cval + (size_t)i*NC*K;
  const int*   ci = cidx + (size_t)i*NC*K;
  float bv[K]; int bi[K];
  #pragma unroll
  for (int j = 0; j < K; j++){ bv[j] = NEG_BIG; bi[j] = 0; }
  int T = NC*K;
  for (int t = 0; t < T; t++)
    topk_ins_t<K,TB>(bv, bi, cv[t], ci[t]);
  int* orow = idxo + (size_t)i*K;
  #pragma unroll
  for (int j = 0; j < K; j++) orow[j] = bi[j];
}

// ---------------- edge conv ----------------
__global__ void pq_kernel(const float* __restrict__ xT, int pitch, int C,
                          const float* __restrict__ WaT,
                          float* __restrict__ P, int N){
  int o = threadIdx.x & 63;
  int n = blockIdx.x*4 + (threadIdx.x >> 6);
  int b = blockIdx.y;
  if (n >= N) return;
  const float* row = xT + ((size_t)b*N + n)*pitch;
  float ap = 0.f;
  for (int c = 0; c < C; c++) ap = fmaf(WaT[c*64 + o], row[c], ap);
  P[((size_t)b*N + n)*64 + o] = ap;
}

// 4 points per 256-thread block: shared W1 tile, per-point sH. N % 4 == 0.
__global__ void edge2_kernel(const float* __restrict__ P, const float* __restrict__ featT,
                             int pitch, int C, const float* __restrict__ WqT,
                             const int* __restrict__ idx, const float* __restrict__ W1T,
                             float* __restrict__ outT, int N, int mask){
  __shared__ float sW[64*64];     // [c][o]
  __shared__ float sH[4*20*64];   // [t][kk][c]
  __shared__ float sx[4*64];
  int tid = threadIdx.x;
  int o = tid & 63, t = tid >> 6;
  int n = blockIdx.x*4 + t;
  int b = blockIdx.y;
  const float4* w4 = (const float4*)W1T;
  float4* s4 = (float4*)sW;
  for (int i = tid; i < 1024; i += 256) s4[i] = w4[i];
  if (o < C) sx[t*64 + o] = featT[((size_t)b*N + n)*pitch + o];
  __syncthreads();
  float qv = 0.f;
  for (int c = 0; c < C; c++) qv = fmaf(WqT[c*64 + o], sx[t*64 + c], qv);
  const float* Pb = P + (size_t)b*N*64;
  const int* irow = idx + ((size_t)b*N + n)*20;
  float* sHt = sH + t*1280;
  for (int kk = 0; kk < 20; kk++){
    int j = irow[kk] & mask;
    float h = Pb[(size_t)j*64 + o] + qv;
    sHt[kk*64 + o] = h >= 0.f ? h : 0.2f*h;
  }
  __syncthreads();
  float acc[20];
  #pragma unroll
  for (int kk = 0; kk < 20; kk++) acc[kk] = 0.f;
  for (int c = 0; c < 64; c += 4){
    float w0 = sW[c*64+o], w1 = sW[(c+1)*64+o], w2 = sW[(c+2)*64+o], w3 = sW[(c+3)*64+o];
    #pragma unroll
    for (int kk = 0; kk < 20; kk++){
      float4 h4 = *(const float4*)&sHt[kk*64 + c];
      float a = acc[kk];
      a = fmaf(w0, h4.x, a); a = fmaf(w1, h4.y, a);
      a = fmaf(w2, h4.z, a); a = fmaf(w3, h4.w, a);
      acc[kk] = a;
    }
  }
  float m = NEG_BIG;
  #pragma unroll
  for (int kk = 0; kk < 20; kk++) m = fmaxf(m, acc[kk]);
  outT[((size_t)b*N + n)*64 + o] = lrelu(m);
}

// 4 points per 256-thread block. N % 4 == 0.
__global__ void edge1_kernel(const float* __restrict__ P, const float* __restrict__ featT,
                             int pitch, int C, const float* __restrict__ WqT,
                             const int* __restrict__ idx, float* __restrict__ outT,
                             int N, int K, int mask){
  __shared__ float sx[4*64];
  int tid = threadIdx.x;
  int o = tid & 63, t = tid >> 6;
  int n = blockIdx.x*4 + t;
  int b = blockIdx.y;
  if (o < C) sx[t*64 + o] = featT[((size_t)b*N + n)*pitch + o];
  __syncthreads();
  float qv = 0.f;
  for (int c = 0; c < C; c++) qv = fmaf(WqT[c*64 + o], sx[t*64 + c], qv);
  const float* Pb = P + (size_t)b*N*64;
  const int* irow = idx + ((size_t)b*N + n)*K;
  float m = NEG_BIG;
  for (int kk = 0; kk < K; kk++){
    int j = irow[kk] & mask;
    m = fmaxf(m, Pb[(size_t)j*64 + o] + qv);
  }
  outT[((size_t)b*N + n)*64 + o] = lrelu(m);
}

__global__ void gmax_kernel(const float* __restrict__ inT, const int* __restrict__ idx,
                            float* __restrict__ outT, int Nin, int M, int K, int mask){
  int o = threadIdx.x; int m = blockIdx.x; int b = blockIdx.y;
  const float* ib = inT + (size_t)b*Nin*64;
  const int* irow = idx + ((size_t)b*M + m)*K;
  float v = NEG_BIG;
  for (int kk = 0; kk < K; kk++){
    int j = irow[kk] & mask;
    v = fmaxf(v, ib[(size_t)j*64 + o]);
  }
  outT[((size_t)b*M + m)*64 + o] = v;
}

__global__ void reluadd_kernel(float* __restrict__ x, const float* __restrict__ f, int total){
  int i = blockIdx.x*256 + threadIdx.x;
  if (i >= total) return;
  float v = x[i] + f[i];
  x[i] = v > 0.f ? v : 0.f;
}

// ---------------- global feature path ----------------
// W row (64 floats) held in REGISTERS per thread; x chunk staged in LDS and read via
// ds_read_b128 wave-broadcast (all lanes same address -> conflict-free, 4 vals/instr).
__launch_bounds__(256, 4)
__global__ void pool_kernel(const float* __restrict__ xT, const void* __restrict__ W,
                            const int* __restrict__ dtf, float* __restrict__ partial,
                            int N, int npts, int segbase){
  __shared__ __align__(16) float sX[32*64];   // 8 KB
  int tid = threadIdx.x;
  int ot = blockIdx.x, chunk = blockIdx.y, b = blockIdx.z;
  int isbf = *dtf;
  int o = ot*256 + tid;
  float wr[64];
  #pragma unroll
  for (int c = 0; c < 64; c++) wr[c] = ldx(W, (size_t)o*64 + c, isbf);
  int n0 = chunk * npts;
  float m = NEG_BIG;
  for (int s0 = 0; s0 < npts; s0 += 32){
    __syncthreads();
    const float4* src = (const float4*)(xT + ((size_t)b*N + n0 + s0)*64);
    float4* dst = (float4*)sX;
    for (int i = tid; i < 512; i += 256) dst[i] = src[i];
    __syncthreads();
    for (int t = 0; t < 32; t += 4){
      float a0 = 0.f, a1 = 0.f, a2 = 0.f, a3 = 0.f;
      #pragma unroll
      for (int c4 = 0; c4 < 16; c4++){
        float4 x0 = *(const float4*)&sX[(t+0)*64 + c4*4];
        float4 x1 = *(const float4*)&sX[(t+1)*64 + c4*4];
        float4 x2 = *(const float4*)&sX[(t+2)*64 + c4*4];
        float4 x3 = *(const float4*)&sX[(t+3)*64 + c4*4];
        float w0 = wr[c4*4+0], w1 = wr[c4*4+1], w2 = wr[c4*4+2], w3 = wr[c4*4+3];
        a0 = fmaf(w0, x0.x, a0); a0 = fmaf(w1, x0.y, a0); a0 = fmaf(w2, x0.z, a0); a0 = fmaf(w3, x0.w, a0);
        a1 = fmaf(w0, x1.x, a1); a1 = fmaf(w1, x1.y, a1); a1 = fmaf(w2, x1.z, a1); a1 = fmaf(w3, x1.w, a1);
        a2 = fmaf(w0, x2.x, a2); a2 = fmaf(w1, x2.y, a2); a2 = fmaf(w2, x2.z, a2); a2 = fmaf(w3, x2.w, a2);
        a3 = fmaf(w0, x3.x, a3); a3 = fmaf(w1, x3.y, a3); a3 = fmaf(w2, x3.z, a3); a3 = fmaf(w3, x3.w, a3);
      }
      m = fmaxf(m, fmaxf(fmaxf(a0,a1), fmaxf(a2,a3)));
    }
  }
  partial[((size_t)b*1024 + o)*22 + segbase + chunk] = m;
}

__global__ void gred_kernel(const float* __restrict__ partial, float* __restrict__ g, int S){
  int i = blockIdx.x*256 + threadIdx.x;
  if (i >= 4*1024) return;
  const float* p = partial + (size_t)i*22;
  float m = NEG_BIG;
  for (int s = 0; s < S; s++) m = fmaxf(m, p[s]);
  g[i] = lrelu(m);
}

__global__ void gw_kernel(const float* __restrict__ g, const void* __restrict__ W13,
                          const int* __restrict__ dtf, float* __restrict__ gW){
  int o = blockIdx.x, b = blockIdx.y;
  int lane = threadIdx.x;
  int isbf = *dtf;
  const float* gb = g + b*1024;
  float acc = 0.f;
  for (int c = lane; c < 1024; c += 64)
    acc = fmaf(ldx(W13, (size_t)o*1088 + c, isbf), gb[c], acc);
  for (int s = 32; s > 0; s >>= 1) acc += __shfl_down(acc, s, 64);
  if (lane == 0) gW[b*256 + o] = acc;
}

// ---------------- decoder MLPs (fused unpool gather) ----------------
__global__ void mlp_kernel(const float* __restrict__ base,
    const float* __restrict__ in1, const int* __restrict__ idx1, int N1, int C1,
    const float* __restrict__ W1T,
    const float* __restrict__ in2, int C2, const float* __restrict__ W2T,
    float* __restrict__ outT, int N, int Cout){
  __shared__ float sIn[4*320];
  int o = threadIdx.x, b = blockIdx.y;
  int n0 = blockIdx.x*4;
  int Cin = C1 + C2;
  int mask1 = N1 - 1;
  for (int t = 0; t < 4; t++){
    int n = n0 + t;
    int r1 = idx1 ? (idx1[(size_t)b*N + n] & mask1) : n;
    const float* p1 = in1 + ((size_t)b*N1 + r1)*C1;
    for (int c = o; c < C1; c += Cout) sIn[t*Cin + c] = p1[c];
    if (in2){
      const float* p2 = in2 + ((size_t)b*N + n)*C2;
      for (int c = o; c < C2; c += Cout) sIn[t*Cin + C1 + c] = p2[c];
    }
  }
  __syncthreads();
  float init = base ? base[b*Cout + o] : 0.f;
  float a0 = init, a1 = init, a2 = init, a3 = init;
  for (int c = 0; c < C1; c++){
    float wv = W1T[c*Cout + o];
    a0 = fmaf(wv, sIn[0*Cin + c], a0);
    a1 = fmaf(wv, sIn[1*Cin + c], a1);
    a2 = fmaf(wv, sIn[2*Cin + c], a2);
    a3 = fmaf(wv, sIn[3*Cin + c], a3);
  }
  for (int c = 0; c < C2; c++){
    float wv = W2T[c*Cout + o];
    a0 = fmaf(wv, sIn[0*Cin + C1 + c], a0);
    a1 = fmaf(wv, sIn[1*Cin + C1 + c], a1);
    a2 = fmaf(wv, sIn[2*Cin + C1 + c], a2);
    a3 = fmaf(wv, sIn[3*Cin + C1 + c], a3);
  }
  size_t ob = ((size_t)b*N + n0)*Cout + o;
  outT[ob]          = lrelu(a0);
  outT[ob + Cout]   = lrelu(a1);
  outT[ob + 2*Cout] = lrelu(a2);
  outT[ob + 3*Cout] = lrelu(a3);
}

__global__ void dec0_kernel(const float* __restrict__ h1T, const int* __restrict__ idxU0,
                            const float* __restrict__ x0T, const float* __restrict__ W16T,
                            const void* __restrict__ W17, const int* __restrict__ dtf,
                            void* __restrict__ out){
  __shared__ float sIn[4*320];
  __shared__ float sH0[4*128];
  int o = threadIdx.x;   // 128 threads
  int b = blockIdx.y; int n0 = blockIdx.x*4;
  for (int t = 0; t < 4; t++){
    int n = n0 + t;
    int r1 = idxU0[(size_t)b*4096 + n] & 1023;
    const float* p1 = h1T + ((size_t)b*1024 + r1)*256;
    for (int c = o; c < 256; c += 128) sIn[t*320 + c] = p1[c];
    const float* p2 = x0T + ((size_t)b*4096 + n)*64;
    if (o < 64) sIn[t*320 + 256 + o] = p2[o];
  }
  __syncthreads();
  float a0 = 0.f, a1 = 0.f, a2 = 0.f, a3 = 0.f;
  for (int c = 0; c < 256; c++){
    float wv = W16T[c*128 + o];
    a0 = fmaf(wv, sIn[0*320 + c], a0);
    a1 = fmaf(wv, sIn[1*320 + c], a1);
    a2 = fmaf(wv, sIn[2*320 + c], a2);
    a3 = fmaf(wv, sIn[3*320 + c], a3);
  }
  for (int c = 0; c < 64; c++){
    float wv = W16T[(256 + c)*128 + o];
    a0 = fmaf(wv, sIn[0*320 + 256 + c], a0);
    a1 = fmaf(wv, sIn[1*320 + 256 + c], a1);
    a2 = fmaf(wv, sIn[2*320 + 256 + c], a2);
    a3 = fmaf(wv, sIn[3*320 + 256 + c], a3);
  }
  sH0[0*128 + o] = lrelu(a0);
  sH0[1*128 + o] = lrelu(a1);
  sH0[2*128 + o] = lrelu(a2);
  sH0[3*128 + o] = lrelu(a3);
  __syncthreads();
  if (o < 52){
    int isbf = *dtf;
    int p = o / 13, cc = o % 13;
    float acc = 0.f;
    for (int c2 = 0; c2 < 128; c2++)
      acc = fmaf(ldx(W17, (size_t)cc*128 + c2, isbf), sH0[p*128 + c2], acc);
    if (!(acc == acc && fabsf(acc) < 1e30f)) acc = 0.f;
    stout(out, ((size_t)b*13 + cc)*4096 + (n0 + p), acc, isbf);
  }
}

// ---------------- host ----------------
extern "C" void kernel_launch(void* const* d_in, const int* in_sizes, int n_in,
                              void* d_out, int out_size, void* d_ws, size_t ws_size,
                              hipStream_t stream){
  (void)in_sizes; (void)n_in; (void)out_size;
  const int B = 4;
  const void* X       = d_in[0];
  const void* w_ec1_0 = d_in[1];
  const void* w_ec1_1 = d_in[2];
  const void* w_ec2_0 = d_in[3];
  const void* w_ec2_1 = d_in[4];
  const void* w_ec4_0 = d_in[5];
  const void* w_ec4_1 = d_in[6];
  const void* w_ec5_0 = d_in[7];
  const void* w_ec5_1 = d_in[8];
  const void* w_ec7   = d_in[9];
  const void* w_ec8   = d_in[10];
  const void* w_ec10  = d_in[11];
  const void* w_ec11  = d_in[12];
  const void* w_pn3   = d_in[13];
  const void* w_pn6   = d_in[14];
  const void* w_pn9   = d_in[15];
  const void* w_pn12  = d_in[16];
  const void* w_pn13  = d_in[17];
  const void* w_pn14  = d_in[18];
  const void* w_pn15  = d_in[19];
  const void* w_pn16  = d_in[20];
  const void* w_c17   = d_in[21];
  void* out = d_out;

  // ---- workspace layout (fp32 words; lifetime-aliased) ----
  float* wsf = (float*)d_ws;
  size_t off = 0;
  auto alloc = [&](size_t n)->float*{
    float* p = wsf + off; off += (n + 63) & ~(size_t)63; return p;
  };
  int*   dtf = (int*)alloc(64);
  float* xfT = alloc(4*4096*9);
  float* rr  = alloc(4*4096);
  float* partial = alloc(4*1024*22);
  float* g   = alloc(4*1024);
  float* gW  = alloc(4*256);
  int*   idx = (int*)alloc(4*4096*20);
  int*   idxU2 = (int*)alloc(4*256);
  int*   idxU1 = (int*)alloc(4*1024);
  int*   idxU0 = (int*)alloc(4*4096);
  float* ec1a = alloc(9*64);  float* ec1q = alloc(9*64);  float* ec1w1 = alloc(64*64);
  float* ec2a = alloc(64*64); float* ec2q = alloc(64*64); float* ec2w1 = alloc(64*64);
  float* ec4a = alloc(64*64); float* ec4q = alloc(64*64); float* ec4w1 = alloc(64*64);
  float* ec5a = alloc(64*64); float* ec5q = alloc(64*64); float* ec5w1 = alloc(64*64);
  float* ec7a = alloc(64*64); float* ec7q = alloc(64*64);
  float* ec8a = alloc(64*64); float* ec8q = alloc(64*64);
  float* ec10a = alloc(64*64); float* ec10q = alloc(64*64);
  float* ec11a = alloc(64*64); float* ec11q = alloc(64*64);
  float* wp13 = alloc(64*256);
  float* wt14 = alloc(320*256);
  float* wt15 = alloc(320*256);
  float* wt16 = alloc(320*128);
  float* P   = alloc(4*4096*64);
  float* hA  = alloc(4*4096*64);    // decoder: h1T alias (exact size)
  float* x0T = alloc(4*4096*64);
  float* x1T = alloc(4*1024*64);
  float* x2T = alloc(4*256*64);
  float* x3T = alloc(4*64*64);
  float* n1f = alloc(4*1024*64);    // decoder: h3T + head of h2T
  float* n2f = alloc(4*256*64);     // contiguous after n1f; h2T tail
  float* n3f = alloc(4*64*64);
  u16*   bhi = (u16*)alloc(4*4096*64/2);   // bf16 hi split (pre-swizzled), 2 MB
  u16*   blo = (u16*)alloc(4*4096*64/2);   // bf16 lo split (pre-swizzled), 2 MB
  float* h1T = hA;
  float* h3T = n1f;
  float* h2T = n1f + 65536;

  // ws-aware candidate sizing (ws_size constant across calls)
  size_t rem = (ws_size/4 > off + 256) ? (ws_size/4 - off - 256) : 0;
  size_t half = rem / 2;
  int NCbig = (half >= (size_t)4*4096*16*20) ? 16 :
              (half >= (size_t)4*4096*8*20)  ? 8  : 4;
  size_t E = (size_t)4*4096*20*NCbig;
  float* cval = alloc(E);
  int*   cidx = (int*)alloc(E);

  detect_kernel<<<dim3(1), 256, 0, stream>>>((const unsigned int*)X, dtf);

  // ---- weight prep ----
  w0_kernel<<<dim3(3), 256, 0, stream>>>(w_ec1_0, dtf, 9, ec1a, ec1q);
  w0_kernel<<<dim3(16), 256, 0, stream>>>(w_ec2_0, dtf, 64, ec2a, ec2q);
  w0_kernel<<<dim3(16), 256, 0, stream>>>(w_ec4_0, dtf, 64, ec4a, ec4q);
  w0_kernel<<<dim3(16), 256, 0, stream>>>(w_ec5_0, dtf, 64, ec5a, ec5q);
  w0_kernel<<<dim3(16), 256, 0, stream>>>(w_ec7, dtf, 64, ec7a, ec7q);
  w0_kernel<<<dim3(16), 256, 0, stream>>>(w_ec8, dtf, 64, ec8a, ec8q);
  w0_kernel<<<dim3(16), 256, 0, stream>>>(w_ec10, dtf, 64, ec10a, ec10q);
  w0_kernel<<<dim3(16), 256, 0, stream>>>(w_ec11, dtf, 64, ec11a, ec11q);
  wt_kernel<<<dim3(16), 256, 0, stream>>>(w_ec1_1, dtf, 64, 64, 0, 64, ec1w1);
  wt_kernel<<<dim3(16), 256, 0, stream>>>(w_ec2_1, dtf, 64, 64, 0, 64, ec2w1);
  wt_kernel<<<dim3(16), 256, 0, stream>>>(w_ec4_1, dtf, 64, 64, 0, 64, ec4w1);
  wt_kernel<<<dim3(16), 256, 0, stream>>>(w_ec5_1, dtf, 64, 64, 0, 64, ec5w1);
  wt_kernel<<<dim3(64), 256, 0, stream>>>(w_pn13, dtf, 256, 1088, 1024, 64, wp13);
  wt_kernel<<<dim3(320), 256, 0, stream>>>(w_pn14, dtf, 256, 320, 0, 320, wt14);
  wt_kernel<<<dim3(320), 256, 0, stream>>>(w_pn15, dtf, 256, 320, 0, 320, wt15);
  wt_kernel<<<dim3(160), 256, 0, stream>>>(w_pn16, dtf, 128, 320, 0, 320, wt16);

  xconv_kernel<<<dim3(64), 256, 0, stream>>>(X, dtf, xfT);
  nodecopy_kernel<<<dim3(64), 256, 0, stream>>>(X, dtf, out);

  const size_t xbs = (size_t)4096*9;
  // coord-space kNN on xfT (pitch 9). len=N/NC must be multiple of 64.
  auto knn_f = [&](int C, int K, int M, int N, int NC, int* io){
    rownorm_kernel<<<dim3((N+255)/256, B), 256, 0, stream>>>(xfT, 9, xbs, C, N, rr);
    dim3 gd((M+255)/256, NC, B);
    if (C == 9)      knn_chunk_kernel<9,20,64><<<gd,256,0,stream>>>(xfT,9,xbs,xfT,9,xbs,rr,M,N,NC,cval,cidx);
    else if (K==20)  knn_chunk_kernel<3,20,64><<<gd,256,0,stream>>>(xfT,9,xbs,xfT,9,xbs,rr,M,N,NC,cval,cidx);
    else             knn_chunk_kernel<3,1,64><<<gd,256,0,stream>>>(xfT,9,xbs,xfT,9,xbs,rr,M,N,NC,cval,cidx);
    dim3 gm((4*M+255)/256);
    if (K == 20)     knn_merge_kernel<20,false><<<gm,256,0,stream>>>(cval,cidx,M,NC,io);
    else             knn_merge_kernel<1,false><<<gm,256,0,stream>>>(cval,cidx,M,NC,io);
  };
  // feature-space self-kNN (C=64).
  // N>=1024: MFMA path (bf16 hi/lo split + tau-filtered LDS-FIFO selection), emits
  //          NC*4 virtual chunks, exact merge with index tie-break.
  // N<=256 : legacy scalar knn64 path (already cheap).
  auto knn_b = [&](int K, const float* fT, int N, int NC, int* io){
    rownorm_kernel<<<dim3((N+255)/256, B), 256, 0, stream>>>(fT, 64, (size_t)N*64, 64, N, rr);
    if (K == 20 && N >= 1024){
      int NCm = NCbig / 4; if (NCm < 1) NCm = 1;     // NC*4 virtual chunks must fit cval
      int cap = (N == 4096) ? 2 : 4;
      if (NCm > cap) NCm = cap;
      bfsplit_kernel<<<dim3((4*N*64)/256), 256, 0, stream>>>(fT, N, bhi, blo);
      knnmf_kernel<20><<<dim3(N/64, NCm, B), 256, 0, stream>>>(bhi, blo, rr, N, NCm, cval, cidx);
      knn_merge_kernel<20,true><<<dim3((4*N+255)/256), 256, 0, stream>>>(cval, cidx, N, NCm*4, io);
    } else {
      dim3 gd(N/64, NC, B);
      if (K == 20) knn64_kernel<20><<<gd,64,0,stream>>>(fT, rr, N, NC, cval, cidx);
      else         knn64_kernel<10><<<gd,64,0,stream>>>(fT, rr, N, NC, cval, cidx);
      dim3 gm((4*N+255)/256);
      if (K == 20) knn_merge_kernel<20,false><<<gm,256,0,stream>>>(cval,cidx,N,NC,io);
      else         knn_merge_kernel<10,false><<<gm,256,0,stream>>>(cval,cidx,N,NC,io);
    }
  };
  auto edge2_b = [&](const float* fT, int N, int NC, float* wa, float* wq, float* w1, float* oT){
    knn_b(20, fT, N, NC, idx);
    pq_kernel<<<dim3((N+3)/4, B), 256, 0, stream>>>(fT, 64, 64, wa, P, N);
    edge2_kernel<<<dim3(N/4, B), 256, 0, stream>>>(P, fT, 64, 64, wq, idx, w1, oT, N, N-1);
  };
  auto edge1_b = [&](const float* fT, int N, int NC, int K, float* wa, float* wq, float* oT){
    knn_b(K, fT, N, NC, idx);
    pq_kernel<<<dim3((N+3)/4, B), 256, 0, stream>>>(fT, 64, 64, wa, P, N);
    edge1_kernel<<<dim3(N/4, B), 256, 0, stream>>>(P, fT, 64, 64, wq, idx, oT, N, K, N-1);
  };

  // level 0
  int nc9 = (NCbig < 8) ? NCbig : 8;                     // len 512: halves redundant fill work
  knn_f(9, 20, 4096, 4096, nc9, idx);
  pq_kernel<<<dim3(1024, B), 256, 0, stream>>>(xfT, 9, 9, ec1a, P, 4096);
  edge2_kernel<<<dim3(1024, B), 256, 0, stream>>>(P, xfT, 9, 9, ec1q, idx, ec1w1, hA, 4096, 4095);
  edge2_b(hA, 4096, NCbig, ec2a, ec2q, ec2w1, x0T);
  pool_kernel<<<dim3(4,16,4), 256, 0, stream>>>(x0T, w_pn3, dtf, partial, 4096, 256, 0);
  // rand_pool 1
  knn_f(3, 20, 1024, 4096, 16, idx);                     // len 256
  gmax_kernel<<<dim3(1024, B), 64, 0, stream>>>(x0T, idx, n1f, 4096, 1024, 20, 4095);
  // level 1
  edge2_b(n1f, 1024, 16, ec4a, ec4q, ec4w1, hA);
  edge2_b(hA, 1024, 16, ec5a, ec5q, ec5w1, x1T);
  pool_kernel<<<dim3(4,4,4), 256, 0, stream>>>(x1T, w_pn6, dtf, partial, 1024, 256, 16);
  reluadd_kernel<<<dim3(1024), 256, 0, stream>>>(x1T, n1f, 4*1024*64);
  // rand_pool 2
  knn_f(3, 20, 256, 1024, 16, idx);                      // len 64
  gmax_kernel<<<dim3(256, B), 64, 0, stream>>>(x1T, idx, n2f, 1024, 256, 20, 1023);
  // level 2
  edge1_b(n2f, 256, 16, 20, ec7a, ec7q, hA);             // len 16
  edge1_b(hA, 256, 16, 20, ec8a, ec8q, x2T);
  pool_kernel<<<dim3(4,1,4), 256, 0, stream>>>(x2T, w_pn9, dtf, partial, 256, 256, 20);
  reluadd_kernel<<<dim3(256), 256, 0, stream>>>(x2T, n2f, 4*256*64);
  // rand_pool 3
  knn_f(3, 20, 64, 256, 4, idx);                         // len 64 (chunk TN bound)
  gmax_kernel<<<dim3(64, B), 64, 0, stream>>>(x2T, idx, n3f, 256, 64, 20, 255);
  // level 3
  edge1_b(n3f, 64, 8, 10, ec10a, ec10q, hA);             // len 8
  edge1_b(hA, 64, 8, 10, ec11a, ec11q, x3T);
  pool_kernel<<<dim3(4,1,4), 256, 0, stream>>>(x3T, w_pn12, dtf, partial, 64, 64, 21);
  reluadd_kernel<<<dim3(64), 256, 0, stream>>>(x3T, n3f, 4*64*64);
  // ---- idx, P, hA, n1f, n2f dead -> h3T/h2T/h1T aliases live ----
  gred_kernel<<<dim3(16), 256, 0, stream>>>(partial, g, 22);
  gw_kernel<<<dim3(256, 4), 64, 0, stream>>>(g, w_pn13, dtf, gW);
  mlp_kernel<<<dim3(16, B), 256, 0, stream>>>(gW, x3T, nullptr, 64, 64, wp13,
                                              nullptr, 0, nullptr, h3T, 64, 256);
  knn_f(3, 1, 256, 64, 1, idxU2);                        // len 64
  mlp_kernel<<<dim3(64, B), 256, 0, stream>>>(nullptr, h3T, idxU2, 64, 256, wt14,
                                              x2T, 64, wt14 + 256*256, h2T, 256, 256);
  knn_f(3, 1, 1024, 256, 4, idxU1);                      // len 64
  mlp_kernel<<<dim3(256, B), 256, 0, stream>>>(nullptr, h2T, idxU1, 256, 256, wt15,
                                               x1T, 64, wt15 + 256*256, h1T, 1024, 256);
  knn_f(3, 1, 4096, 1024, 4, idxU0);                     // len 256
  dec0_kernel<<<dim3(1024, B), 128, 0, stream>>>(h1T, idxU0, x0T, wt16, w_c17, dtf, out);
}

// Round 11
// 2684.740 us; speedup vs baseline: 1.2417x; 1.1137x over previous
//
#include <hip/hip_runtime.h>
#include <hip/hip_bf16.h>
#include <float.h>

typedef __hip_bfloat16 bf16;
typedef unsigned short u16;
typedef unsigned long long u64;
typedef __attribute__((ext_vector_type(8))) short bh8;   // 8 bf16 = 4 VGPRs (MFMA A/B frag)
typedef __attribute__((ext_vector_type(4))) float fx4;   // MFMA C/D frag

#define NEG_BIG (-1.0e30f)

__device__ __forceinline__ bf16 f2b(float v){ return __float2bfloat16(v); }
__device__ __forceinline__ float lrelu(float x){ return x >= 0.f ? x : 0.2f*x; }

// round-to-nearest-even fp32 -> bf16 bits
__device__ __forceinline__ u16 f2bf_rne(float x){
  unsigned u = __float_as_uint(x);
  unsigned r = (u + 0x7FFFu + ((u >> 16) & 1u)) >> 16;
  return (u16)r;
}

// dtype-flexible sanitized load from a raw INPUT buffer (element index)
__device__ __forceinline__ float ldx(const void* p, size_t i, int isbf){
  float v = isbf ? __bfloat162float(((const bf16*)p)[i]) : ((const float*)p)[i];
  return (v == v && fabsf(v) < 1e30f) ? v : 0.f;
}
// dtype-flexible store to the OUTPUT buffer (element index)
__device__ __forceinline__ void stout(void* p, size_t i, float v, int isbf){
  if (isbf) ((bf16*)p)[i] = f2b(v);
  else      ((float*)p)[i] = v;
}

// carry-chain sorted top-K insert (bv descending, bv[K-1] = min).
// TB=false: strict > (equal values keep earlier-scanned = lower index when scan is
// index-ordered). TB=true: explicit (value, lower-index) tie-break, order-independent.
// NOTE (r5-r8 lesson): packed-u64 key variants of this chain are NOT cheaper on CDNA
// (u64 cmp = 2 ops, u64 cndmask = 2x b32) — keep the float/int dual chain.
template<int K, bool TB>
__device__ __forceinline__ void topk_ins_t(float (&bv)[K], int (&bi)[K], float d, int j){
  bool gate = TB ? (d > bv[K-1] || (d == bv[K-1] && j < bi[K-1])) : (d > bv[K-1]);
  if (gate){
    bool gt[K];
    #pragma unroll
    for (int s = 0; s < K; s++)
      gt[s] = TB ? (d > bv[s] || (d == bv[s] && j < bi[s])) : (d > bv[s]);
    #pragma unroll
    for (int s = K-1; s > 0; s--){
      float nv = gt[s-1] ? bv[s-1] : d;
      int   ni = gt[s-1] ? bi[s-1] : j;
      bv[s] = gt[s] ? nv : bv[s];
      bi[s] = gt[s] ? ni : bi[s];
    }
    if (gt[0]){ bv[0] = d; bi[0] = j; }
  }
}
template<int K>
__device__ __forceinline__ void topk_ins(float (&bv)[K], int (&bi)[K], float d, int j){
  topk_ins_t<K,false>(bv, bi, d, j);
}

// ---------------- input dtype detector ----------------
__global__ void detect_kernel(const unsigned int* __restrict__ X, int* __restrict__ flag){
  __shared__ int cnt;
  if (threadIdx.x == 0) cnt = 0;
  __syncthreads();
  int hits = 0;
  for (int i = threadIdx.x; i < 8192; i += 256){
    unsigned w = X[i];
    unsigned lo = w & 0xFFFFu;
    unsigned e = (lo >> 7) & 0xFFu;
    if ((e >= 0x76u && e <= 0x84u) || lo == 0u) hits++;
  }
  atomicAdd(&cnt, hits);
  __syncthreads();
  if (threadIdx.x == 0) flag[0] = (cnt > 4096) ? 1 : 0;
}

// ---------------- weight prep ----------------
__global__ void wt_kernel(const void* __restrict__ W, const int* __restrict__ dtf,
                          int Cout, int pitch, int coff, int Cin, float* __restrict__ WT){
  int i = blockIdx.x*256 + threadIdx.x;
  if (i >= Cin*Cout) return;
  int isbf = *dtf;
  int c = i / Cout, o = i - c*Cout;
  WT[i] = ldx(W, (size_t)o*pitch + coff + c, isbf);
}

__global__ void w0_kernel(const void* __restrict__ W0, const int* __restrict__ dtf,
                          int C, float* __restrict__ WaT, float* __restrict__ WqT){
  int i = blockIdx.x*256 + threadIdx.x;
  if (i >= C*64) return;
  int isbf = *dtf;
  int c = i >> 6, o = i & 63;
  float a = ldx(W0, (size_t)o*2*C + c, isbf);
  float q = ldx(W0, (size_t)o*2*C + C + c, isbf);
  WaT[i] = a; WqT[i] = q - a;
}

__global__ void xconv_kernel(const void* __restrict__ x, const int* __restrict__ dtf,
                             float* __restrict__ xfT){
  int i = blockIdx.x*256 + threadIdx.x;
  if (i >= 4*4096) return;
  int isbf = *dtf;
  int b = i >> 12, n = i & 4095;
  for (int c = 0; c < 9; c++)
    xfT[((size_t)b*4096 + n)*9 + c] = ldx(x, ((size_t)b*9 + c)*4096 + n, isbf);
}

__global__ void nodecopy_kernel(const void* __restrict__ x, const int* __restrict__ dtf,
                                void* __restrict__ out){
  int i = blockIdx.x*256 + threadIdx.x;
  int isbf = *dtf;
  if (i < 12288){
    int b = i / 3072, r = i % 3072; int c = r / 1024, m = r % 1024;
    stout(out, 212992 + i, ldx(x, ((size_t)b*9 + c)*4096 + m, isbf), isbf);
  } else if (i < 15360){
    int j = i - 12288; int b = j / 768, r = j % 768; int c = r / 256, m = r % 256;
    stout(out, 212992 + i, ldx(x, ((size_t)b*9 + c)*4096 + m, isbf), isbf);
  } else if (i < 16128){
    int j = i - 15360; int b = j / 192, r = j % 192; int c = r / 64, m = r % 64;
    stout(out, 212992 + i, ldx(x, ((size_t)b*9 + c)*4096 + m, isbf), isbf);
  }
}

// ---------------- kNN ----------------
__global__ void rownorm_kernel(const float* __restrict__ T, int pitch, size_t bs,
                               int C, int N, float* __restrict__ rr){
  int n = blockIdx.x*256 + threadIdx.x;
  int b = blockIdx.y;
  if (n >= N) return;
  const float* row = T + (size_t)b*bs + (size_t)n*pitch;
  float s = 0.f;
  for (int c = 0; c < C; c++) s = fmaf(row[c], row[c], s);
  rr[b*N + n] = s;
}

// small-C chunked kNN (C=3/9; per-thread query in registers, refs staged in LDS).
// Refs staged TRANSPOSED [c][t]: wave-uniform ds_read_b128 broadcasts (4 cands/read).
// K>=8: tau-gated per-thread LDS FIFO (CAP=8; occupancy — r9 lesson) + per-tile
//   drains + overflow drain guard (per 4-candidate group, max 4 pushes).
//   Exact: stale tau (== bv[K-1] at last drain) is only more permissive; FIFO drain
//   preserves ascending-j order so strict-> insert keeps lax.top_k tie semantics.
// REQUIREMENT: len = N/NC must be a multiple of TN.
template<int C, int K, int TN>
__global__ void knn_chunk_kernel(const float* __restrict__ qT, int qpitch, size_t qbs,
                                 const float* __restrict__ rT, int rpitch, size_t rbs,
                                 const float* __restrict__ rr, int M, int N, int NC,
                                 float* __restrict__ cval, int* __restrict__ cidx){
  constexpr bool FIFO = (K >= 8);
  constexpr int CAP = 8;
  __shared__ __align__(16) float sRT[C*TN];   // [c][t]
  __shared__ __align__(16) float sN[TN];
  __shared__ u64 sQ[FIFO ? 256*(CAP+1) : 1];  // per-thread FIFO, stride 9 u64 (18 KB)
  int tid = threadIdx.x;
  int m = blockIdx.x*256 + tid;
  int cid = blockIdx.y, b = blockIdx.z;
  int len = N / NC;
  int n0 = cid * len;
  bool active = (m < M);
  float q[C]; float qq = 0.f;
  if (active){
    const float* qrow = qT + (size_t)b*qbs + (size_t)m*qpitch;
    #pragma unroll
    for (int c = 0; c < C; c++){ q[c] = qrow[c]; qq = fmaf(q[c], q[c], qq); }
  }
  float bv[K]; int bi[K];
  #pragma unroll
  for (int j = 0; j < K; j++){ bv[j] = NEG_BIG; bi[j] = n0; }
  float tau = NEG_BIG;
  u64* qb = FIFO ? &sQ[tid*(CAP+1)] : (u64*)nullptr;
  int qcnt = 0;
  const float* rbase = rT + (size_t)b*rbs;
  const float* rrb = rr + b*N;

  auto drain = [&](){
    int k = 0;
    while (__any(k < qcnt)){
      if (k < qcnt){
        u64 e = qb[k];
        float d = __uint_as_float((unsigned)(e >> 32));
        int j = (int)(unsigned)e;
        topk_ins_t<K,false>(bv, bi, d, j);
      }
      k++;
    }
    qcnt = 0;
    tau = bv[K-1];
  };

  for (int t0 = 0; t0 < len; t0 += TN){
    __syncthreads();
    for (int i = tid; i < TN*C; i += 256){
      int c = i / TN, t = i - c*TN;
      sRT[i] = rbase[(size_t)(n0 + t0 + t)*rpitch + c];
    }
    for (int i = tid; i < TN; i += 256) sN[i] = rrb[n0 + t0 + i];
    __syncthreads();
    if (active){
      for (int t = 0; t < TN; t += 4){
        float a0 = 0.f, a1 = 0.f, a2 = 0.f, a3 = 0.f;
        #pragma unroll
        for (int c = 0; c < C; c++){
          float4 rv = *(const float4*)&sRT[c*TN + t];
          float qc = q[c];
          a0 = fmaf(qc, rv.x, a0); a1 = fmaf(qc, rv.y, a1);
          a2 = fmaf(qc, rv.z, a2); a3 = fmaf(qc, rv.w, a3);
        }
        float4 nn = *(const float4*)&sN[t];
        int jb = n0 + t0 + t;
        float d0 = 2.f*a0 - qq - nn.x;
        float d1 = 2.f*a1 - qq - nn.y;
        float d2 = 2.f*a2 - qq - nn.z;
        float d3 = 2.f*a3 - qq - nn.w;
        if constexpr (FIFO){
          if (__any(qcnt >= CAP-4)) drain();    // guarantees room for 4
          if (d0 > tau){ qb[qcnt] = (((u64)__float_as_uint(d0))<<32) | (unsigned)(jb+0); qcnt++; }
          if (d1 > tau){ qb[qcnt] = (((u64)__float_as_uint(d1))<<32) | (unsigned)(jb+1); qcnt++; }
          if (d2 > tau){ qb[qcnt] = (((u64)__float_as_uint(d2))<<32) | (unsigned)(jb+2); qcnt++; }
          if (d3 > tau){ qb[qcnt] = (((u64)__float_as_uint(d3))<<32) | (unsigned)(jb+3); qcnt++; }
        } else {
          topk_ins<K>(bv, bi, d0, jb+0);
          topk_ins<K>(bv, bi, d1, jb+1);
          topk_ins<K>(bv, bi, d2, jb+2);
          topk_ins<K>(bv, bi, d3, jb+3);
        }
      }
    }
    if constexpr (FIFO){ drain(); }             // inactive lanes: qcnt==0, no-op
  }
  if (active){
    float* ov = cval + ((size_t)((size_t)b*M + m)*NC + cid)*K;
    int*   oi = cidx + ((size_t)((size_t)b*M + m)*NC + cid)*K;
    #pragma unroll
    for (int j = 0; j < K; j++){ ov[j] = bv[j]; oi[j] = bi[j]; }
  }
}

// C=64 self-kNN scan (legacy path, kept for N<=256): 1-wave blocks, queries in VGPRs.
template<int K>
__launch_bounds__(64, 2)
__global__ void knn64_kernel(const float* __restrict__ fT, const float* __restrict__ rr,
                             int N, int NC, float* __restrict__ cval, int* __restrict__ cidx){
  int lane = threadIdx.x;
  int q0 = blockIdx.x*64;
  int cid = blockIdx.y, b = blockIdx.z;
  int m = q0 + lane;
  int len = N / NC;
  int n0 = cid*len;
  float4 q4[16];
  {
    const float4* qp = (const float4*)(fT + ((size_t)b*N + m)*64);
    #pragma unroll
    for (int i = 0; i < 16; i++) q4[i] = qp[i];
  }
  float qq = rr[(size_t)b*N + m];   // self-kNN (M==N)
  float bv[K]; int bi[K];
  #pragma unroll
  for (int j = 0; j < K; j++){ bv[j] = NEG_BIG; bi[j] = n0; }
  const float4* rbase = (const float4*)(fT + ((size_t)b*N + n0)*64);
  const float* rrb = rr + (size_t)b*N + n0;
  for (int t0 = 0; t0 < len; t0 += 4){
    const float4* r4 = rbase + (size_t)t0*16;
    float a0=0.f, a1=0.f, a2=0.f, a3=0.f;
    #pragma unroll
    for (int ct = 0; ct < 16; ct++){
      float4 v0 = r4[ct], v1 = r4[16+ct], v2 = r4[32+ct], v3 = r4[48+ct];
      float4 qv = q4[ct];
      a0 = fmaf(qv.x,v0.x,a0); a0 = fmaf(qv.y,v0.y,a0); a0 = fmaf(qv.z,v0.z,a0); a0 = fmaf(qv.w,v0.w,a0);
      a1 = fmaf(qv.x,v1.x,a1); a1 = fmaf(qv.y,v1.y,a1); a1 = fmaf(qv.z,v1.z,a1); a1 = fmaf(qv.w,v1.w,a1);
      a2 = fmaf(qv.x,v2.x,a2); a2 = fmaf(qv.y,v2.y,a2); a2 = fmaf(qv.z,v2.z,a2); a2 = fmaf(qv.w,v2.w,a2);
      a3 = fmaf(qv.x,v3.x,a3); a3 = fmaf(qv.y,v3.y,a3); a3 = fmaf(qv.z,v3.z,a3); a3 = fmaf(qv.w,v3.w,a3);
    }
    topk_ins<K>(bv, bi, 2.f*a0 - qq - rrb[t0+0], n0+t0+0);
    topk_ins<K>(bv, bi, 2.f*a1 - qq - rrb[t0+1], n0+t0+1);
    topk_ins<K>(bv, bi, 2.f*a2 - qq - rrb[t0+2], n0+t0+2);
    topk_ins<K>(bv, bi, 2.f*a3 - qq - rrb[t0+3], n0+t0+3);
  }
  float* ov = cval + ((size_t)((size_t)b*N + m)*NC + cid)*K;
  int*   oi = cidx + ((size_t)((size_t)b*N + m)*NC + cid)*K;
  #pragma unroll
  for (int j = 0; j < K; j++){ ov[j] = bv[j]; oi[j] = bi[j]; }
}

// fp32 -> (hi, lo) bf16 split, stored PRE-SWIZZLED (c ^= (row&7)<<3) so that the
// kNN MFMA kernel can stage LDS tiles with linear copies and read ds_read_b128
// fragments bank-conflict-optimally (G4/T2 recipe).
__global__ void bfsplit_kernel(const float* __restrict__ fT, int N,
                               u16* __restrict__ hi, u16* __restrict__ lo){
  int i = blockIdx.x*256 + threadIdx.x;      // over 4*N*64
  if (i >= 4*N*64) return;
  int c = i & 63;
  int n = i >> 6;                            // combined row b*N + ln; N % 8 == 0 so n&7 == ln&7
  float x = fT[i];
  u16 h = f2bf_rne(x);
  float hf = __uint_as_float((unsigned)h << 16);
  u16 l = f2bf_rne(x - hf);
  size_t o = ((size_t)n << 6) + (c ^ ((n & 7) << 3));
  hi[o] = h; lo[o] = l;
}

// MFMA feature-space self-kNN (C=64).  exact-ish distances via bf16 hi/lo split:
// inner = hi·hi + hi·lo + lo·hi (3x mfma_f32_16x16x32_bf16, fp32 accum, rel err ~2^-17).
// D[ref][query] orientation: lane = (g=l>>4, lm=l&15) holds query (qblk+w*16+lm)'s
// distances for refs {tile + m*16 + 4g + i}.
// Selection: shared float tau (max over 4 partition-lanes of bv[K-1], per-tile
// shfl_xor refresh) gates candidates into a per-thread CAP=8 LDS FIFO (occupancy;
// guard before each m-step drains when near-full -> capacity provably sufficient;
// mid-tile drains leave tau unchanged, still valid).  FIFO drain preserves
// ascending-j order -> strict-> insert; cross-partition ties via TB=true merge.
template<int K>
__launch_bounds__(256, 4)
__global__ void knnmf_kernel(const u16* __restrict__ hi, const u16* __restrict__ lo,
                             const float* __restrict__ rr, int N, int NC,
                             float* __restrict__ cval, int* __restrict__ cidx){
  constexpr int CAP = 8;
  __shared__ __align__(16) u16 sHi[64*64];     // 8 KB, swizzled rows
  __shared__ __align__(16) u16 sLo[64*64];     // 8 KB
  __shared__ float sRR[64];
  __shared__ u64 sQ[256*(CAP+1)];              // per-thread 8-entry FIFO, stride 9 (18 KB)

  const int tid  = threadIdx.x;
  const int lane = tid & 63, w = tid >> 6;
  const int g    = lane >> 4;                  // 0..3
  const int lm   = lane & 15;
  const int qblk = blockIdx.x * 64;
  const int cid  = blockIdx.y, b = blockIdx.z;
  const int len  = N / NC, n0 = cid * len;

  const u16*  hib = hi + (size_t)b*N*64;
  const u16*  lob = lo + (size_t)b*N*64;
  const float* rrb = rr + (size_t)b*N;

  // ---- stage this block's 64 query rows, pull B-fragments into registers ----
  {
    const float4* sh = (const float4*)(hib + (size_t)qblk*64);
    const float4* sl = (const float4*)(lob + (size_t)qblk*64);
    float4* dh = (float4*)sHi; float4* dl = (float4*)sLo;
    for (int i = tid; i < 512; i += 256){ dh[i] = sh[i]; dl[i] = sl[i]; }
  }
  __syncthreads();
  const int qrow = w*16 + lm;                  // wave w owns queries qblk + w*16 .. +15
  const int kb0 = 8*g, kb1 = 32 + 8*g;         // frag k-offsets: k = koff + 8*(lane>>4) + i
  const int qsw = (qrow & 7) << 3;
  const bh8 qh0 = *(const bh8*)&sHi[qrow*64 + (kb0 ^ qsw)];
  const bh8 qh1 = *(const bh8*)&sHi[qrow*64 + (kb1 ^ qsw)];
  const bh8 ql0 = *(const bh8*)&sLo[qrow*64 + (kb0 ^ qsw)];
  const bh8 ql1 = *(const bh8*)&sLo[qrow*64 + (kb1 ^ qsw)];
  const float qq = rrb[qblk + qrow];

  float bv[K]; int bi[K];
  #pragma unroll
  for (int j = 0; j < K; j++){ bv[j] = NEG_BIG; bi[j] = n0; }
  float tau = NEG_BIG;                         // shared (4-partition) running K-th value
  u64* qbase = &sQ[tid*(CAP+1)];
  int qcnt = 0;

  // drain FIFOs into the sorted chain; tau NOT touched here (mid-tile safe)
  auto drainq = [&](){
    int k = 0;
    while (__any(k < qcnt)){
      if (k < qcnt){
        u64 e = qbase[k];
        float d = __uint_as_float((unsigned)(e >> 32));
        int j = (int)(unsigned)e;
        topk_ins_t<K,false>(bv, bi, d, j);
      }
      k++;
    }
    qcnt = 0;
  };

  for (int t0 = n0; t0 < n0 + len; t0 += 64){
    __syncthreads();                           // previous tile's frag reads done
    {
      const float4* sh = (const float4*)(hib + (size_t)t0*64);
      const float4* sl = (const float4*)(lob + (size_t)t0*64);
      float4* dh = (float4*)sHi; float4* dl = (float4*)sLo;
      for (int i = tid; i < 512; i += 256){ dh[i] = sh[i]; dl[i] = sl[i]; }
      if (tid < 64) sRR[tid] = rrb[t0 + tid];
    }
    __syncthreads();
    for (int m = 0; m < 4; m++){
      const int rrow = m*16 + lm;              // A-frag row owned by this lane
      const int sw = (rrow & 7) << 3;
      const bh8 ah0 = *(const bh8*)&sHi[rrow*64 + (kb0 ^ sw)];
      const bh8 ah1 = *(const bh8*)&sHi[rrow*64 + (kb1 ^ sw)];
      const bh8 al0 = *(const bh8*)&sLo[rrow*64 + (kb0 ^ sw)];
      const bh8 al1 = *(const bh8*)&sLo[rrow*64 + (kb1 ^ sw)];
      fx4 acc = {0.f, 0.f, 0.f, 0.f};
      acc = __builtin_amdgcn_mfma_f32_16x16x32_bf16(ah0, qh0, acc, 0, 0, 0);
      acc = __builtin_amdgcn_mfma_f32_16x16x32_bf16(ah1, qh1, acc, 0, 0, 0);
      acc = __builtin_amdgcn_mfma_f32_16x16x32_bf16(ah0, ql0, acc, 0, 0, 0);
      acc = __builtin_amdgcn_mfma_f32_16x16x32_bf16(ah1, ql1, acc, 0, 0, 0);
      acc = __builtin_amdgcn_mfma_f32_16x16x32_bf16(al0, qh0, acc, 0, 0, 0);
      acc = __builtin_amdgcn_mfma_f32_16x16x32_bf16(al1, qh1, acc, 0, 0, 0);
      const float4 rr4 = *(const float4*)&sRR[m*16 + 4*g];   // broadcast within 16-lane group
      const float rrv[4] = {rr4.x, rr4.y, rr4.z, rr4.w};
      const int jb = t0 + m*16 + 4*g;          // C/D rows: lane holds rows 4g+i
      if (__any(qcnt >= CAP-4)) drainq();      // guarantees room for 4 pushes
      #pragma unroll
      for (int i = 0; i < 4; i++){
        float d = fmaf(2.f, acc[i], -(qq + rrv[i]));
        if (d >= tau){                         // >= keeps boundary ties (exactness)
          qbase[qcnt] = (((u64)__float_as_uint(d)) << 32) | (unsigned)(jb + i);
          qcnt++;
        }
      }
    }
    // per-tile drain + shared-threshold refresh
    drainq();
    {
      float t = bv[K-1];
      t = fmaxf(t, __shfl_xor(t, 16));
      t = fmaxf(t, __shfl_xor(t, 32));
      tau = t;
    }
  }
  const int q = qblk + qrow;
  const size_t rowo = (((size_t)b*N + q)*(size_t)(NC*4) + (size_t)(cid*4 + g))*(size_t)K;
  float* ov = cval + rowo; int* oi = cidx + rowo;
  #pragma unroll
  for (int j = 0; j < K; j++){ ov[j] = bv[j]; oi[j] = bi[j]; }
}

template<int K, bool TB>
__global__ void knn_merge_kernel(const float* __restrict__ cval, const int* __restrict__ cidx,
                                 int M, int NC, int* __restrict__ idxo){
  int i = blockIdx.x*256 + threadIdx.x;   // b*M + m
  if (i >= 4*M) return;
  const float* cv = cval + (size_t)i*NC*K;
  const int*   ci = cidx + (size_t)i*NC*K;
  float bv[K]; int bi[K];
  #pragma unroll
  for (int j = 0; j < K; j++){ bv[j] = NEG_BIG; bi[j] = 0; }
  int T = NC*K;
  for (int t = 0; t < T; t++)
    topk_ins_t<K,TB>(bv, bi, cv[t], ci[t]);
  int* orow = idxo + (size_t)i*K;
  #pragma unroll
  for (int j = 0; j < K; j++) orow[j] = bi[j];
}

// ---------------- edge conv ----------------
__global__ void pq_kernel(const float* __restrict__ xT, int pitch, int C,
                          const float* __restrict__ WaT,
                          float* __restrict__ P, int N){
  int o = threadIdx.x & 63;
  int n = blockIdx.x*4 + (threadIdx.x >> 6);
  int b = blockIdx.y;
  if (n >= N) return;
  const float* row = xT + ((size_t)b*N + n)*pitch;
  float ap = 0.f;
  for (int c = 0; c < C; c++) ap = fmaf(WaT[c*64 + o], row[c], ap);
  P[((size_t)b*N + n)*64 + o] = ap;
}

// 4 points per 256-thread block: shared W1 tile, per-point sH. N % 4 == 0.
__global__ void edge2_kernel(const float* __restrict__ P, const float* __restrict__ featT,
                             int pitch, int C, const float* __restrict__ WqT,
                             const int* __restrict__ idx, const float* __restrict__ W1T,
                             float* __restrict__ outT, int N, int mask){
  __shared__ float sW[64*64];     // [c][o]
  __shared__ float sH[4*20*64];   // [t][kk][c]
  __shared__ float sx[4*64];
  int tid = threadIdx.x;
  int o = tid & 63, t = tid >> 6;
  int n = blockIdx.x*4 + t;
  int b = blockIdx.y;
  const float4* w4 = (const float4*)W1T;
  float4* s4 = (float4*)sW;
  for (int i = tid; i < 1024; i += 256) s4[i] = w4[i];
  if (o < C) sx[t*64 + o] = featT[((size_t)b*N + n)*pitch + o];
  __syncthreads();
  float qv = 0.f;
  for (int c = 0; c < C; c++) qv = fmaf(WqT[c*64 + o], sx[t*64 + c], qv);
  const float* Pb = P + (size_t)b*N*64;
  const int* irow = idx + ((size_t)b*N + n)*20;
  float* sHt = sH + t*1280;
  for (int kk = 0; kk < 20; kk++){
    int j = irow[kk] & mask;
    float h = Pb[(size_t)j*64 + o] + qv;
    sHt[kk*64 + o] = h >= 0.f ? h : 0.2f*h;
  }
  __syncthreads();
  float acc[20];
  #pragma unroll
  for (int kk = 0; kk < 20; kk++) acc[kk] = 0.f;
  for (int c = 0; c < 64; c += 4){
    float w0 = sW[c*64+o], w1 = sW[(c+1)*64+o], w2 = sW[(c+2)*64+o], w3 = sW[(c+3)*64+o];
    #pragma unroll
    for (int kk = 0; kk < 20; kk++){
      float4 h4 = *(const float4*)&sHt[kk*64 + c];
      float a = acc[kk];
      a = fmaf(w0, h4.x, a); a = fmaf(w1, h4.y, a);
      a = fmaf(w2, h4.z, a); a = fmaf(w3, h4.w, a);
      acc[kk] = a;
    }
  }
  float m = NEG_BIG;
  #pragma unroll
  for (int kk = 0; kk < 20; kk++) m = fmaxf(m, acc[kk]);
  outT[((size_t)b*N + n)*64 + o] = lrelu(m);
}

// 4 points per 256-thread block. N % 4 == 0.
__global__ void edge1_kernel(const float* __restrict__ P, const float* __restrict__ featT,
                             int pitch, int C, const float* __restrict__ WqT,
                             const int* __restrict__ idx, float* __restrict__ outT,
                             int N, int K, int mask){
  __shared__ float sx[4*64];
  int tid = threadIdx.x;
  int o = tid & 63, t = tid >> 6;
  int n = blockIdx.x*4 + t;
  int b = blockIdx.y;
  if (o < C) sx[t*64 + o] = featT[((size_t)b*N + n)*pitch + o];
  __syncthreads();
  float qv = 0.f;
  for (int c = 0; c < C; c++) qv = fmaf(WqT[c*64 + o], sx[t*64 + c], qv);
  const float* Pb = P + (size_t)b*N*64;
  const int* irow = idx + ((size_t)b*N + n)*K;
  float m = NEG_BIG;
  for (int kk = 0; kk < K; kk++){
    int j = irow[kk] & mask;
    m = fmaxf(m, Pb[(size_t)j*64 + o] + qv);
  }
  outT[((size_t)b*N + n)*64 + o] = lrelu(m);
}

__global__ void gmax_kernel(const float* __restrict__ inT, const int* __restrict__ idx,
                            float* __restrict__ outT, int Nin, int M, int K, int mask){
  int o = threadIdx.x; int m = blockIdx.x; int b = blockIdx.y;
  const float* ib = inT + (size_t)b*Nin*64;
  const int* irow = idx + ((size_t)b*M + m)*K;
  float v = NEG_BIG;
  for (int kk = 0; kk < K; kk++){
    int j = irow[kk] & mask;
    v = fmaxf(v, ib[(size_t)j*64 + o]);
  }
  outT[((size_t)b*M + m)*64 + o] = v;
}

__global__ void reluadd_kernel(float* __restrict__ x, const float* __restrict__ f, int total){
  int i = blockIdx.x*256 + threadIdx.x;
  if (i >= total) return;
  float v = x[i] + f[i];
  x[i] = v > 0.f ? v : 0.f;
}

// ---------------- global feature path ----------------
// W row (64 floats) held in REGISTERS per thread; x chunk staged in LDS and read via
// ds_read_b128 wave-broadcast (all lanes same address -> conflict-free, 4 vals/instr).
// r10 lesson: level-0 grid of 256 blocks = 1 block/CU was latency-bound (VALUBusy 18%,
// Occ 11%); npts=64 quadruples block count.  fmax regroup is exact -> outputs
// bit-identical.  PSTRIDE = total partial slots per (b,o) row.
#define PSTRIDE 85
__launch_bounds__(256, 4)
__global__ void pool_kernel(const float* __restrict__ xT, const void* __restrict__ W,
                            const int* __restrict__ dtf, float* __restrict__ partial,
                            int N, int npts, int segbase){
  __shared__ __align__(16) float sX[32*64];   // 8 KB
  int tid = threadIdx.x;
  int ot = blockIdx.x, chunk = blockIdx.y, b = blockIdx.z;
  int isbf = *dtf;
  int o = ot*256 + tid;
  float wr[64];
  #pragma unroll
  for (int c = 0; c < 64; c++) wr[c] = ldx(W, (size_t)o*64 + c, isbf);
  int n0 = chunk * npts;
  float m = NEG_BIG;
  for (int s0 = 0; s0 < npts; s0 += 32){
    __syncthreads();
    const float4* src = (const float4*)(xT + ((size_t)b*N + n0 + s0)*64);
    float4* dst = (float4*)sX;
    for (int i = tid; i < 512; i += 256) dst[i] = src[i];
    __syncthreads();
    for (int t = 0; t < 32; t += 4){
      float a0 = 0.f, a1 = 0.f, a2 = 0.f, a3 = 0.f;
      #pragma unroll
      for (int c4 = 0; c4 < 16; c4++){
        float4 x0 = *(const float4*)&sX[(t+0)*64 + c4*4];
        float4 x1 = *(const float4*)&sX[(t+1)*64 + c4*4];
        float4 x2 = *(const float4*)&sX[(t+2)*64 + c4*4];
        float4 x3 = *(const float4*)&sX[(t+3)*64 + c4*4];
        float w0 = wr[c4*4+0], w1 = wr[c4*4+1], w2 = wr[c4*4+2], w3 = wr[c4*4+3];
        a0 = fmaf(w0, x0.x, a0); a0 = fmaf(w1, x0.y, a0); a0 = fmaf(w2, x0.z, a0); a0 = fmaf(w3, x0.w, a0);
        a1 = fmaf(w0, x1.x, a1); a1 = fmaf(w1, x1.y, a1); a1 = fmaf(w2, x1.z, a1); a1 = fmaf(w3, x1.w, a1);
        a2 = fmaf(w0, x2.x, a2); a2 = fmaf(w1, x2.y, a2); a2 = fmaf(w2, x2.z, a2); a2 = fmaf(w3, x2.w, a2);
        a3 = fmaf(w0, x3.x, a3); a3 = fmaf(w1, x3.y, a3); a3 = fmaf(w2, x3.z, a3); a3 = fmaf(w3, x3.w, a3);
      }
      m = fmaxf(m, fmaxf(fmaxf(a0,a1), fmaxf(a2,a3)));
    }
  }
  partial[((size_t)b*1024 + o)*PSTRIDE + segbase + chunk] = m;
}

__global__ void gred_kernel(const float* __restrict__ partial, float* __restrict__ g, int S){
  int i = blockIdx.x*256 + threadIdx.x;
  if (i >= 4*1024) return;
  const float* p = partial + (size_t)i*PSTRIDE;
  float m = NEG_BIG;
  for (int s = 0; s < S; s++) m = fmaxf(m, p[s]);
  g[i] = lrelu(m);
}

__global__ void gw_kernel(const float* __restrict__ g, const void* __restrict__ W13,
                          const int* __restrict__ dtf, float* __restrict__ gW){
  int o = blockIdx.x, b = blockIdx.y;
  int lane = threadIdx.x;
  int isbf = *dtf;
  const float* gb = g + b*1024;
  float acc = 0.f;
  for (int c = lane; c < 1024; c += 64)
    acc = fmaf(ldx(W13, (size_t)o*1088 + c, isbf), gb[c], acc);
  for (int s = 32; s > 0; s >>= 1) acc += __shfl_down(acc, s, 64);
  if (lane == 0) gW[b*256 + o] = acc;
}

// ---------------- decoder MLPs (fused unpool gather) ----------------
__global__ void mlp_kernel(const float* __restrict__ base,
    const float* __restrict__ in1, const int* __restrict__ idx1, int N1, int C1,
    const float* __restrict__ W1T,
    const float* __restrict__ in2, int C2, const float* __restrict__ W2T,
    float* __restrict__ outT, int N, int Cout){
  __shared__ float sIn[4*320];
  int o = threadIdx.x, b = blockIdx.y;
  int n0 = blockIdx.x*4;
  int Cin = C1 + C2;
  int mask1 = N1 - 1;
  for (int t = 0; t < 4; t++){
    int n = n0 + t;
    int r1 = idx1 ? (idx1[(size_t)b*N + n] & mask1) : n;
    const float* p1 = in1 + ((size_t)b*N1 + r1)*C1;
    for (int c = o; c < C1; c += Cout) sIn[t*Cin + c] = p1[c];
    if (in2){
      const float* p2 = in2 + ((size_t)b*N + n)*C2;
      for (int c = o; c < C2; c += Cout) sIn[t*Cin + C1 + c] = p2[c];
    }
  }
  __syncthreads();
  float init = base ? base[b*Cout + o] : 0.f;
  float a0 = init, a1 = init, a2 = init, a3 = init;
  for (int c = 0; c < C1; c++){
    float wv = W1T[c*Cout + o];
    a0 = fmaf(wv, sIn[0*Cin + c], a0);
    a1 = fmaf(wv, sIn[1*Cin + c], a1);
    a2 = fmaf(wv, sIn[2*Cin + c], a2);
    a3 = fmaf(wv, sIn[3*Cin + c], a3);
  }
  for (int c = 0; c < C2; c++){
    float wv = W2T[c*Cout + o];
    a0 = fmaf(wv, sIn[0*Cin + C1 + c], a0);
    a1 = fmaf(wv, sIn[1*Cin + C1 + c], a1);
    a2 = fmaf(wv, sIn[2*Cin + C1 + c], a2);
    a3 = fmaf(wv, sIn[3*Cin + C1 + c], a3);
  }
  size_t ob = ((size_t)b*N + n0)*Cout + o;
  outT[ob]          = lrelu(a0);
  outT[ob + Cout]   = lrelu(a1);
  outT[ob + 2*Cout] = lrelu(a2);
  outT[ob + 3*Cout] = lrelu(a3);
}

__global__ void dec0_kernel(const float* __restrict__ h1T, const int* __restrict__ idxU0,
                            const float* __restrict__ x0T, const float* __restrict__ W16T,
                            const void* __restrict__ W17, const int* __restrict__ dtf,
                            void* __restrict__ out){
  __shared__ float sIn[4*320];
  __shared__ float sH0[4*128];
  int o = threadIdx.x;   // 128 threads
  int b = blockIdx.y; int n0 = blockIdx.x*4;
  for (int t = 0; t < 4; t++){
    int n = n0 + t;
    int r1 = idxU0[(size_t)b*4096 + n] & 1023;
    const float* p1 = h1T + ((size_t)b*1024 + r1)*256;
    for (int c = o; c < 256; c += 128) sIn[t*320 + c] = p1[c];
    const float* p2 = x0T + ((size_t)b*4096 + n)*64;
    if (o < 64) sIn[t*320 + 256 + o] = p2[o];
  }
  __syncthreads();
  float a0 = 0.f, a1 = 0.f, a2 = 0.f, a3 = 0.f;
  for (int c = 0; c < 256; c++){
    float wv = W16T[c*128 + o];
    a0 = fmaf(wv, sIn[0*320 + c], a0);
    a1 = fmaf(wv, sIn[1*320 + c], a1);
    a2 = fmaf(wv, sIn[2*320 + c], a2);
    a3 = fmaf(wv, sIn[3*320 + c], a3);
  }
  for (int c = 0; c < 64; c++){
    float wv = W16T[(256 + c)*128 + o];
    a0 = fmaf(wv, sIn[0*320 + 256 + c], a0);
    a1 = fmaf(wv, sIn[1*320 + 256 + c], a1);
    a2 = fmaf(wv, sIn[2*320 + 256 + c], a2);
    a3 = fmaf(wv, sIn[3*320 + 256 + c], a3);
  }
  sH0[0*128 + o] = lrelu(a0);
  sH0[1*128 + o] = lrelu(a1);
  sH0[2*128 + o] = lrelu(a2);
  sH0[3*128 + o] = lrelu(a3);
  __syncthreads();
  if (o < 52){
    int isbf = *dtf;
    int p = o / 13, cc = o % 13;
    float acc = 0.f;
    for (int c2 = 0; c2 < 128; c2++)
      acc = fmaf(ldx(W17, (size_t)cc*128 + c2, isbf), sH0[p*128 + c2], acc);
    if (!(acc == acc && fabsf(acc) < 1e30f)) acc = 0.f;
    stout(out, ((size_t)b*13 + cc)*4096 + (n0 + p), acc, isbf);
  }
}

// ---------------- host ----------------
extern "C" void kernel_launch(void* const* d_in, const int* in_sizes, int n_in,
                              void* d_out, int out_size, void* d_ws, size_t ws_size,
                              hipStream_t stream){
  (void)in_sizes; (void)n_in; (void)out_size;
  const int B = 4;
  const void* X       = d_in[0];
  const void* w_ec1_0 = d_in[1];
  const void* w_ec1_1 = d_in[2];
  const void* w_ec2_0 = d_in[3];
  const void* w_ec2_1 = d_in[4];
  const void* w_ec4_0 = d_in[5];
  const void* w_ec4_1 = d_in[6];
  const void* w_ec5_0 = d_in[7];
  const void* w_ec5_1 = d_in[8];
  const void* w_ec7   = d_in[9];
  const void* w_ec8   = d_in[10];
  const void* w_ec10  = d_in[11];
  const void* w_ec11  = d_in[12];
  const void* w_pn3   = d_in[13];
  const void* w_pn6   = d_in[14];
  const void* w_pn9   = d_in[15];
  const void* w_pn12  = d_in[16];
  const void* w_pn13  = d_in[17];
  const void* w_pn14  = d_in[18];
  const void* w_pn15  = d_in[19];
  const void* w_pn16  = d_in[20];
  const void* w_c17   = d_in[21];
  void* out = d_out;

  // ---- workspace layout (fp32 words; lifetime-aliased) ----
  float* wsf = (float*)d_ws;
  size_t off = 0;
  auto alloc = [&](size_t n)->float*{
    float* p = wsf + off; off += (n + 63) & ~(size_t)63; return p;
  };
  int*   dtf = (int*)alloc(64);
  float* xfT = alloc(4*4096*9);
  float* rr  = alloc(4*4096);
  float* partial = alloc(4*1024*85);
  float* g   = alloc(4*1024);
  float* gW  = alloc(4*256);
  int*   idx = (int*)alloc(4*4096*20);
  int*   idxU2 = (int*)alloc(4*256);
  int*   idxU1 = (int*)alloc(4*1024);
  int*   idxU0 = (int*)alloc(4*4096);
  float* ec1a = alloc(9*64);  float* ec1q = alloc(9*64);  float* ec1w1 = alloc(64*64);
  float* ec2a = alloc(64*64); float* ec2q = alloc(64*64); float* ec2w1 = alloc(64*64);
  float* ec4a = alloc(64*64); float* ec4q = alloc(64*64); float* ec4w1 = alloc(64*64);
  float* ec5a = alloc(64*64); float* ec5q = alloc(64*64); float* ec5w1 = alloc(64*64);
  float* ec7a = alloc(64*64); float* ec7q = alloc(64*64);
  float* ec8a = alloc(64*64); float* ec8q = alloc(64*64);
  float* ec10a = alloc(64*64); float* ec10q = alloc(64*64);
  float* ec11a = alloc(64*64); float* ec11q = alloc(64*64);
  float* wp13 = alloc(64*256);
  float* wt14 = alloc(320*256);
  float* wt15 = alloc(320*256);
  float* wt16 = alloc(320*128);
  float* P   = alloc(4*4096*64);
  float* hA  = alloc(4*4096*64);    // decoder: h1T alias (exact size)
  float* x0T = alloc(4*4096*64);
  float* x1T = alloc(4*1024*64);
  float* x2T = alloc(4*256*64);
  float* x3T = alloc(4*64*64);
  float* n1f = alloc(4*1024*64);    // decoder: h3T + head of h2T
  float* n2f = alloc(4*256*64);     // contiguous after n1f; h2T tail
  float* n3f = alloc(4*64*64);
  u16*   bhi = (u16*)alloc(4*4096*64/2);   // bf16 hi split (pre-swizzled), 2 MB
  u16*   blo = (u16*)alloc(4*4096*64/2);   // bf16 lo split (pre-swizzled), 2 MB
  float* h1T = hA;
  float* h3T = n1f;
  float* h2T = n1f + 65536;

  // ws-aware candidate sizing (ws_size constant across calls)
  size_t rem = (ws_size/4 > off + 256) ? (ws_size/4 - off - 256) : 0;
  size_t half = rem / 2;
  int NCbig = (half >= (size_t)4*4096*16*20) ? 16 :
              (half >= (size_t)4*4096*8*20)  ? 8  : 4;
  size_t E = (size_t)4*4096*20*NCbig;
  float* cval = alloc(E);
  int*   cidx = (int*)alloc(E);

  detect_kernel<<<dim3(1), 256, 0, stream>>>((const unsigned int*)X, dtf);

  // ---- weight prep ----
  w0_kernel<<<dim3(3), 256, 0, stream>>>(w_ec1_0, dtf, 9, ec1a, ec1q);
  w0_kernel<<<dim3(16), 256, 0, stream>>>(w_ec2_0, dtf, 64, ec2a, ec2q);
  w0_kernel<<<dim3(16), 256, 0, stream>>>(w_ec4_0, dtf, 64, ec4a, ec4q);
  w0_kernel<<<dim3(16), 256, 0, stream>>>(w_ec5_0, dtf, 64, ec5a, ec5q);
  w0_kernel<<<dim3(16), 256, 0, stream>>>(w_ec7, dtf, 64, ec7a, ec7q);
  w0_kernel<<<dim3(16), 256, 0, stream>>>(w_ec8, dtf, 64, ec8a, ec8q);
  w0_kernel<<<dim3(16), 256, 0, stream>>>(w_ec10, dtf, 64, ec10a, ec10q);
  w0_kernel<<<dim3(16), 256, 0, stream>>>(w_ec11, dtf, 64, ec11a, ec11q);
  wt_kernel<<<dim3(16), 256, 0, stream>>>(w_ec1_1, dtf, 64, 64, 0, 64, ec1w1);
  wt_kernel<<<dim3(16), 256, 0, stream>>>(w_ec2_1, dtf, 64, 64, 0, 64, ec2w1);
  wt_kernel<<<dim3(16), 256, 0, stream>>>(w_ec4_1, dtf, 64, 64, 0, 64, ec4w1);
  wt_kernel<<<dim3(16), 256, 0, stream>>>(w_ec5_1, dtf, 64, 64, 0, 64, ec5w1);
  wt_kernel<<<dim3(64), 256, 0, stream>>>(w_pn13, dtf, 256, 1088, 1024, 64, wp13);
  wt_kernel<<<dim3(320), 256, 0, stream>>>(w_pn14, dtf, 256, 320, 0, 320, wt14);
  wt_kernel<<<dim3(320), 256, 0, stream>>>(w_pn15, dtf, 256, 320, 0, 320, wt15);
  wt_kernel<<<dim3(160), 256, 0, stream>>>(w_pn16, dtf, 128, 320, 0, 320, wt16);

  xconv_kernel<<<dim3(64), 256, 0, stream>>>(X, dtf, xfT);
  nodecopy_kernel<<<dim3(64), 256, 0, stream>>>(X, dtf, out);

  const size_t xbs = (size_t)4096*9;
  // coord-space kNN on xfT (pitch 9). len=N/NC must be multiple of 64.
  auto knn_f = [&](int C, int K, int M, int N, int NC, int* io){
    rownorm_kernel<<<dim3((N+255)/256, B), 256, 0, stream>>>(xfT, 9, xbs, C, N, rr);
    dim3 gd((M+255)/256, NC, B);
    if (C == 9)      knn_chunk_kernel<9,20,64><<<gd,256,0,stream>>>(xfT,9,xbs,xfT,9,xbs,rr,M,N,NC,cval,cidx);
    else if (K==20)  knn_chunk_kernel<3,20,64><<<gd,256,0,stream>>>(xfT,9,xbs,xfT,9,xbs,rr,M,N,NC,cval,cidx);
    else             knn_chunk_kernel<3,1,64><<<gd,256,0,stream>>>(xfT,9,xbs,xfT,9,xbs,rr,M,N,NC,cval,cidx);
    dim3 gm((4*M+255)/256);
    if (K == 20)     knn_merge_kernel<20,false><<<gm,256,0,stream>>>(cval,cidx,M,NC,io);
    else             knn_merge_kernel<1,false><<<gm,256,0,stream>>>(cval,cidx,M,NC,io);
  };
  // feature-space self-kNN (C=64).
  // N>=1024: MFMA path (bf16 hi/lo split + tau-filtered LDS-FIFO selection), emits
  //          NC*4 virtual chunks, exact merge with index tie-break.
  // N<=256 : legacy scalar knn64 path (already cheap).
  auto knn_b = [&](int K, const float* fT, int N, int NC, int* io){
    rownorm_kernel<<<dim3((N+255)/256, B), 256, 0, stream>>>(fT, 64, (size_t)N*64, 64, N, rr);
    if (K == 20 && N >= 1024){
      int NCm = NCbig / 4; if (NCm < 1) NCm = 1;     // NC*4 virtual chunks must fit cval
      int cap = (N == 4096) ? 2 : 4;
      if (NCm > cap) NCm = cap;
      bfsplit_kernel<<<dim3((4*N*64)/256), 256, 0, stream>>>(fT, N, bhi, blo);
      knnmf_kernel<20><<<dim3(N/64, NCm, B), 256, 0, stream>>>(bhi, blo, rr, N, NCm, cval, cidx);
      knn_merge_kernel<20,true><<<dim3((4*N+255)/256), 256, 0, stream>>>(cval, cidx, N, NCm*4, io);
    } else {
      dim3 gd(N/64, NC, B);
      if (K == 20) knn64_kernel<20><<<gd,64,0,stream>>>(fT, rr, N, NC, cval, cidx);
      else         knn64_kernel<10><<<gd,64,0,stream>>>(fT, rr, N, NC, cval, cidx);
      dim3 gm((4*N+255)/256);
      if (K == 20) knn_merge_kernel<20,false><<<gm,256,0,stream>>>(cval,cidx,N,NC,io);
      else         knn_merge_kernel<10,false><<<gm,256,0,stream>>>(cval,cidx,N,NC,io);
    }
  };
  auto edge2_b = [&](const float* fT, int N, int NC, float* wa, float* wq, float* w1, float* oT){
    knn_b(20, fT, N, NC, idx);
    pq_kernel<<<dim3((N+3)/4, B), 256, 0, stream>>>(fT, 64, 64, wa, P, N);
    edge2_kernel<<<dim3(N/4, B), 256, 0, stream>>>(P, fT, 64, 64, wq, idx, w1, oT, N, N-1);
  };
  auto edge1_b = [&](const float* fT, int N, int NC, int K, float* wa, float* wq, float* oT){
    knn_b(K, fT, N, NC, idx);
    pq_kernel<<<dim3((N+3)/4, B), 256, 0, stream>>>(fT, 64, 64, wa, P, N);
    edge1_kernel<<<dim3(N/4, B), 256, 0, stream>>>(P, fT, 64, 64, wq, idx, oT, N, K, N-1);
  };

  // level 0
  int nc9 = (NCbig < 8) ? NCbig : 8;                     // len 512: halves redundant fill work
  knn_f(9, 20, 4096, 4096, nc9, idx);
  pq_kernel<<<dim3(1024, B), 256, 0, stream>>>(xfT, 9, 9, ec1a, P, 4096);
  edge2_kernel<<<dim3(1024, B), 256, 0, stream>>>(P, xfT, 9, 9, ec1q, idx, ec1w1, hA, 4096, 4095);
  edge2_b(hA, 4096, NCbig, ec2a, ec2q, ec2w1, x0T);
  pool_kernel<<<dim3(4,64,4), 256, 0, stream>>>(x0T, w_pn3, dtf, partial, 4096, 64, 0);
  // rand_pool 1
  knn_f(3, 20, 1024, 4096, 16, idx);                     // len 256
  gmax_kernel<<<dim3(1024, B), 64, 0, stream>>>(x0T, idx, n1f, 4096, 1024, 20, 4095);
  // level 1
  edge2_b(n1f, 1024, 16, ec4a, ec4q, ec4w1, hA);
  edge2_b(hA, 1024, 16, ec5a, ec5q, ec5w1, x1T);
  pool_kernel<<<dim3(4,16,4), 256, 0, stream>>>(x1T, w_pn6, dtf, partial, 1024, 64, 64);
  reluadd_kernel<<<dim3(1024), 256, 0, stream>>>(x1T, n1f, 4*1024*64);
  // rand_pool 2
  knn_f(3, 20, 256, 1024, 16, idx);                      // len 64
  gmax_kernel<<<dim3(256, B), 64, 0, stream>>>(x1T, idx, n2f, 1024, 256, 20, 1023);
  // level 2
  edge1_b(n2f, 256, 16, 20, ec7a, ec7q, hA);             // len 16
  edge1_b(hA, 256, 16, 20, ec8a, ec8q, x2T);
  pool_kernel<<<dim3(4,4,4), 256, 0, stream>>>(x2T, w_pn9, dtf, partial, 256, 64, 80);
  reluadd_kernel<<<dim3(256), 256, 0, stream>>>(x2T, n2f, 4*256*64);
  // rand_pool 3
  knn_f(3, 20, 64, 256, 4, idx);                         // len 64 (chunk TN bound)
  gmax_kernel<<<dim3(64, B), 64, 0, stream>>>(x2T, idx, n3f, 256, 64, 20, 255);
  // level 3
  edge1_b(n3f, 64, 8, 10, ec10a, ec10q, hA);             // len 8
  edge1_b(hA, 64, 8, 10, ec11a, ec11q, x3T);
  pool_kernel<<<dim3(4,1,4), 256, 0, stream>>>(x3T, w_pn12, dtf, partial, 64, 64, 84);
  reluadd_kernel<<<dim3(64), 256, 0, stream>>>(x3T, n3f, 4*64*64);
  // ---- idx, P, hA, n1f, n2f dead -> h3T/h2T/h1T aliases live ----
  gred_kernel<<<dim3(16), 256, 0, stream>>>(partial, g, 85);
  gw_kernel<<<dim3(256, 4), 64, 0, stream>>>(g, w_pn13, dtf, gW);
  mlp_kernel<<<dim3(16, B), 256, 0, stream>>>(gW, x3T, nullptr, 64, 64, wp13,
                                              nullptr, 0, nullptr, h3T, 64, 256);
  knn_f(3, 1, 256, 64, 1, idxU2);                        // len 64
  mlp_kernel<<<dim3(64, B), 256, 0, stream>>>(nullptr, h3T, idxU2, 64, 256, wt14,
                                              x2T, 64, wt14 + 256*256, h2T, 256, 256);
  knn_f(3, 1, 1024, 256, 4, idxU1);                      // len 64
  mlp_kernel<<<dim3(256, B), 256, 0, stream>>>(nullptr, h2T, idxU1, 256, 256, wt15,
                                               x1T, 64, wt15 + 256*256, h1T, 1024, 256);
  knn_f(3, 1, 4096, 1024, 4, idxU0);                     // len 256
  dec0_kernel<<<dim3(1024, B), 128, 0, stream>>>(h1T, idxU0, x0T, wt16, w_c17, dtf, out);
}

// Round 12
// 1779.120 us; speedup vs baseline: 1.8737x; 1.5090x over previous
//
#include <hip/hip_runtime.h>
#include <hip/hip_bf16.h>
#include <float.h>

typedef __hip_bfloat16 bf16;
typedef unsigned short u16;
typedef unsigned long long u64;
typedef __attribute__((ext_vector_type(8))) short bh8;   // 8 bf16 = 4 VGPRs (MFMA A/B frag)
typedef __attribute__((ext_vector_type(4))) float fx4;   // MFMA C/D frag

#define NEG_BIG (-1.0e30f)

__device__ __forceinline__ bf16 f2b(float v){ return __float2bfloat16(v); }
__device__ __forceinline__ float lrelu(float x){ return x >= 0.f ? x : 0.2f*x; }

// round-to-nearest-even fp32 -> bf16 bits
__device__ __forceinline__ u16 f2bf_rne(float x){
  unsigned u = __float_as_uint(x);
  unsigned r = (u + 0x7FFFu + ((u >> 16) & 1u)) >> 16;
  return (u16)r;
}

// dtype-flexible sanitized load from a raw INPUT buffer (element index)
__device__ __forceinline__ float ldx(const void* p, size_t i, int isbf){
  float v = isbf ? __bfloat162float(((const bf16*)p)[i]) : ((const float*)p)[i];
  return (v == v && fabsf(v) < 1e30f) ? v : 0.f;
}
// dtype-flexible store to the OUTPUT buffer (element index)
__device__ __forceinline__ void stout(void* p, size_t i, float v, int isbf){
  if (isbf) ((bf16*)p)[i] = f2b(v);
  else      ((float*)p)[i] = v;
}

// ---- packed sort key for the wave-merge ONLY (r7/r8 lesson: never pack in the
// per-candidate filter path; here it's ~36 packs per output row — negligible).
// key = ord(d)<<32 | ~j : (value desc, index asc) lexicographic == u64 '>'.
__device__ __forceinline__ u64 dkey(float d, int j){
  unsigned u = __float_as_uint(d);
  u ^= (unsigned)(((int)u) >> 31) | 0x80000000u;
  return ((u64)u << 32) | (u64)(~(unsigned)j);
}
__device__ __forceinline__ int key_j(u64 k){ return (int)~(unsigned)k; }
__device__ __forceinline__ u64 shfl_xor_u64(u64 v, int m){
  unsigned lo = (unsigned)v, hi = (unsigned)(v >> 32);
  lo = __shfl_xor(lo, m); hi = __shfl_xor(hi, m);
  return ((u64)hi << 32) | (u64)lo;
}
__device__ __forceinline__ u64 maxu64(u64 a, u64 b){ return a > b ? a : b; }

// carry-chain sorted top-K insert (bv descending, bv[K-1] = min).
// TB=false: strict > (equal values keep earlier-scanned = lower index when scan is
// index-ordered). TB=true: explicit (value, lower-index) tie-break, order-independent.
template<int K, bool TB>
__device__ __forceinline__ void topk_ins_t(float (&bv)[K], int (&bi)[K], float d, int j){
  bool gate = TB ? (d > bv[K-1] || (d == bv[K-1] && j < bi[K-1])) : (d > bv[K-1]);
  if (gate){
    bool gt[K];
    #pragma unroll
    for (int s = 0; s < K; s++)
      gt[s] = TB ? (d > bv[s] || (d == bv[s] && j < bi[s])) : (d > bv[s]);
    #pragma unroll
    for (int s = K-1; s > 0; s--){
      float nv = gt[s-1] ? bv[s-1] : d;
      int   ni = gt[s-1] ? bi[s-1] : j;
      bv[s] = gt[s] ? nv : bv[s];
      bi[s] = gt[s] ? ni : bi[s];
    }
    if (gt[0]){ bv[0] = d; bi[0] = j; }
  }
}
template<int K>
__device__ __forceinline__ void topk_ins(float (&bv)[K], int (&bi)[K], float d, int j){
  topk_ins_t<K,false>(bv, bi, d, j);
}

// ---------------- input dtype detector ----------------
__global__ void detect_kernel(const unsigned int* __restrict__ X, int* __restrict__ flag){
  __shared__ int cnt;
  if (threadIdx.x == 0) cnt = 0;
  __syncthreads();
  int hits = 0;
  for (int i = threadIdx.x; i < 8192; i += 256){
    unsigned w = X[i];
    unsigned lo = w & 0xFFFFu;
    unsigned e = (lo >> 7) & 0xFFu;
    if ((e >= 0x76u && e <= 0x84u) || lo == 0u) hits++;
  }
  atomicAdd(&cnt, hits);
  __syncthreads();
  if (threadIdx.x == 0) flag[0] = (cnt > 4096) ? 1 : 0;
}

// ---------------- weight prep ----------------
__global__ void wt_kernel(const void* __restrict__ W, const int* __restrict__ dtf,
                          int Cout, int pitch, int coff, int Cin, float* __restrict__ WT){
  int i = blockIdx.x*256 + threadIdx.x;
  if (i >= Cin*Cout) return;
  int isbf = *dtf;
  int c = i / Cout, o = i - c*Cout;
  WT[i] = ldx(W, (size_t)o*pitch + coff + c, isbf);
}

__global__ void w0_kernel(const void* __restrict__ W0, const int* __restrict__ dtf,
                          int C, float* __restrict__ WaT, float* __restrict__ WqT){
  int i = blockIdx.x*256 + threadIdx.x;
  if (i >= C*64) return;
  int isbf = *dtf;
  int c = i >> 6, o = i & 63;
  float a = ldx(W0, (size_t)o*2*C + c, isbf);
  float q = ldx(W0, (size_t)o*2*C + C + c, isbf);
  WaT[i] = a; WqT[i] = q - a;
}

__global__ void xconv_kernel(const void* __restrict__ x, const int* __restrict__ dtf,
                             float* __restrict__ xfT){
  int i = blockIdx.x*256 + threadIdx.x;
  if (i >= 4*4096) return;
  int isbf = *dtf;
  int b = i >> 12, n = i & 4095;
  for (int c = 0; c < 9; c++)
    xfT[((size_t)b*4096 + n)*9 + c] = ldx(x, ((size_t)b*9 + c)*4096 + n, isbf);
}

__global__ void nodecopy_kernel(const void* __restrict__ x, const int* __restrict__ dtf,
                                void* __restrict__ out){
  int i = blockIdx.x*256 + threadIdx.x;
  int isbf = *dtf;
  if (i < 12288){
    int b = i / 3072, r = i % 3072; int c = r / 1024, m = r % 1024;
    stout(out, 212992 + i, ldx(x, ((size_t)b*9 + c)*4096 + m, isbf), isbf);
  } else if (i < 15360){
    int j = i - 12288; int b = j / 768, r = j % 768; int c = r / 256, m = r % 256;
    stout(out, 212992 + i, ldx(x, ((size_t)b*9 + c)*4096 + m, isbf), isbf);
  } else if (i < 16128){
    int j = i - 15360; int b = j / 192, r = j % 192; int c = r / 64, m = r % 64;
    stout(out, 212992 + i, ldx(x, ((size_t)b*9 + c)*4096 + m, isbf), isbf);
  }
}

// ---------------- kNN ----------------
__global__ void rownorm_kernel(const float* __restrict__ T, int pitch, size_t bs,
                               int C, int N, float* __restrict__ rr){
  int n = blockIdx.x*256 + threadIdx.x;
  int b = blockIdx.y;
  if (n >= N) return;
  const float* row = T + (size_t)b*bs + (size_t)n*pitch;
  float s = 0.f;
  for (int c = 0; c < C; c++) s = fmaf(row[c], row[c], s);
  rr[b*N + n] = s;
}

// small-C chunked kNN (C=3/9; per-thread query in registers, refs staged in LDS).
// Refs staged TRANSPOSED [c][t]: wave-uniform ds_read_b128 broadcasts (4 cands/read).
// K>=8: tau-gated per-thread LDS FIFO (CAP=8) + per-tile drains + overflow guard.
// REQUIREMENT: len = N/NC must be a multiple of TN.
template<int C, int K, int TN>
__global__ void knn_chunk_kernel(const float* __restrict__ qT, int qpitch, size_t qbs,
                                 const float* __restrict__ rT, int rpitch, size_t rbs,
                                 const float* __restrict__ rr, int M, int N, int NC,
                                 float* __restrict__ cval, int* __restrict__ cidx){
  constexpr bool FIFO = (K >= 8);
  constexpr int CAP = 8;
  __shared__ __align__(16) float sRT[C*TN];   // [c][t]
  __shared__ __align__(16) float sN[TN];
  __shared__ u64 sQ[FIFO ? 256*(CAP+1) : 1];  // per-thread FIFO, stride 9 u64 (18 KB)
  int tid = threadIdx.x;
  int m = blockIdx.x*256 + tid;
  int cid = blockIdx.y, b = blockIdx.z;
  int len = N / NC;
  int n0 = cid * len;
  bool active = (m < M);
  float q[C]; float qq = 0.f;
  if (active){
    const float* qrow = qT + (size_t)b*qbs + (size_t)m*qpitch;
    #pragma unroll
    for (int c = 0; c < C; c++){ q[c] = qrow[c]; qq = fmaf(q[c], q[c], qq); }
  }
  float bv[K]; int bi[K];
  #pragma unroll
  for (int j = 0; j < K; j++){ bv[j] = NEG_BIG; bi[j] = n0; }
  float tau = NEG_BIG;
  u64* qb = FIFO ? &sQ[tid*(CAP+1)] : (u64*)nullptr;
  int qcnt = 0;
  const float* rbase = rT + (size_t)b*rbs;
  const float* rrb = rr + b*N;

  auto drain = [&](){
    int k = 0;
    while (__any(k < qcnt)){
      if (k < qcnt){
        u64 e = qb[k];
        float d = __uint_as_float((unsigned)(e >> 32));
        int j = (int)(unsigned)e;
        topk_ins_t<K,false>(bv, bi, d, j);
      }
      k++;
    }
    qcnt = 0;
    tau = bv[K-1];
  };

  for (int t0 = 0; t0 < len; t0 += TN){
    __syncthreads();
    for (int i = tid; i < TN*C; i += 256){
      int c = i / TN, t = i - c*TN;
      sRT[i] = rbase[(size_t)(n0 + t0 + t)*rpitch + c];
    }
    for (int i = tid; i < TN; i += 256) sN[i] = rrb[n0 + t0 + i];
    __syncthreads();
    if (active){
      for (int t = 0; t < TN; t += 4){
        float a0 = 0.f, a1 = 0.f, a2 = 0.f, a3 = 0.f;
        #pragma unroll
        for (int c = 0; c < C; c++){
          float4 rv = *(const float4*)&sRT[c*TN + t];
          float qc = q[c];
          a0 = fmaf(qc, rv.x, a0); a1 = fmaf(qc, rv.y, a1);
          a2 = fmaf(qc, rv.z, a2); a3 = fmaf(qc, rv.w, a3);
        }
        float4 nn = *(const float4*)&sN[t];
        int jb = n0 + t0 + t;
        float d0 = 2.f*a0 - qq - nn.x;
        float d1 = 2.f*a1 - qq - nn.y;
        float d2 = 2.f*a2 - qq - nn.z;
        float d3 = 2.f*a3 - qq - nn.w;
        if constexpr (FIFO){
          if (__any(qcnt >= CAP-4)) drain();    // guarantees room for 4
          if (d0 > tau){ qb[qcnt] = (((u64)__float_as_uint(d0))<<32) | (unsigned)(jb+0); qcnt++; }
          if (d1 > tau){ qb[qcnt] = (((u64)__float_as_uint(d1))<<32) | (unsigned)(jb+1); qcnt++; }
          if (d2 > tau){ qb[qcnt] = (((u64)__float_as_uint(d2))<<32) | (unsigned)(jb+2); qcnt++; }
          if (d3 > tau){ qb[qcnt] = (((u64)__float_as_uint(d3))<<32) | (unsigned)(jb+3); qcnt++; }
        } else {
          topk_ins<K>(bv, bi, d0, jb+0);
          topk_ins<K>(bv, bi, d1, jb+1);
          topk_ins<K>(bv, bi, d2, jb+2);
          topk_ins<K>(bv, bi, d3, jb+3);
        }
      }
    }
    if constexpr (FIFO){ drain(); }             // inactive lanes: qcnt==0, no-op
  }
  if (active){
    float* ov = cval + ((size_t)((size_t)b*M + m)*NC + cid)*K;
    int*   oi = cidx + ((size_t)((size_t)b*M + m)*NC + cid)*K;
    #pragma unroll
    for (int j = 0; j < K; j++){ ov[j] = bv[j]; oi[j] = bi[j]; }
  }
}

// C=64 self-kNN scan (legacy path, kept for N<=256): 1-wave blocks, queries in VGPRs.
template<int K>
__launch_bounds__(64, 2)
__global__ void knn64_kernel(const float* __restrict__ fT, const float* __restrict__ rr,
                             int N, int NC, float* __restrict__ cval, int* __restrict__ cidx){
  int lane = threadIdx.x;
  int q0 = blockIdx.x*64;
  int cid = blockIdx.y, b = blockIdx.z;
  int m = q0 + lane;
  int len = N / NC;
  int n0 = cid*len;
  float4 q4[16];
  {
    const float4* qp = (const float4*)(fT + ((size_t)b*N + m)*64);
    #pragma unroll
    for (int i = 0; i < 16; i++) q4[i] = qp[i];
  }
  float qq = rr[(size_t)b*N + m];   // self-kNN (M==N)
  float bv[K]; int bi[K];
  #pragma unroll
  for (int j = 0; j < K; j++){ bv[j] = NEG_BIG; bi[j] = n0; }
  const float4* rbase = (const float4*)(fT + ((size_t)b*N + n0)*64);
  const float* rrb = rr + (size_t)b*N + n0;
  for (int t0 = 0; t0 < len; t0 += 4){
    const float4* r4 = rbase + (size_t)t0*16;
    float a0=0.f, a1=0.f, a2=0.f, a3=0.f;
    #pragma unroll
    for (int ct = 0; ct < 16; ct++){
      float4 v0 = r4[ct], v1 = r4[16+ct], v2 = r4[32+ct], v3 = r4[48+ct];
      float4 qv = q4[ct];
      a0 = fmaf(qv.x,v0.x,a0); a0 = fmaf(qv.y,v0.y,a0); a0 = fmaf(qv.z,v0.z,a0); a0 = fmaf(qv.w,v0.w,a0);
      a1 = fmaf(qv.x,v1.x,a1); a1 = fmaf(qv.y,v1.y,a1); a1 = fmaf(qv.z,v1.z,a1); a1 = fmaf(qv.w,v1.w,a1);
      a2 = fmaf(qv.x,v2.x,a2); a2 = fmaf(qv.y,v2.y,a2); a2 = fmaf(qv.z,v2.z,a2); a2 = fmaf(qv.w,v2.w,a2);
      a3 = fmaf(qv.x,v3.x,a3); a3 = fmaf(qv.y,v3.y,a3); a3 = fmaf(qv.z,v3.z,a3); a3 = fmaf(qv.w,v3.w,a3);
    }
    topk_ins<K>(bv, bi, 2.f*a0 - qq - rrb[t0+0], n0+t0+0);
    topk_ins<K>(bv, bi, 2.f*a1 - qq - rrb[t0+1], n0+t0+1);
    topk_ins<K>(bv, bi, 2.f*a2 - qq - rrb[t0+2], n0+t0+2);
    topk_ins<K>(bv, bi, 2.f*a3 - qq - rrb[t0+3], n0+t0+3);
  }
  float* ov = cval + ((size_t)((size_t)b*N + m)*NC + cid)*K;
  int*   oi = cidx + ((size_t)((size_t)b*N + m)*NC + cid)*K;
  #pragma unroll
  for (int j = 0; j < K; j++){ ov[j] = bv[j]; oi[j] = bi[j]; }
}

// fp32 -> (hi, lo) bf16 split, stored PRE-SWIZZLED (c ^= (row&7)<<3) so that the
// kNN MFMA kernel can stage LDS tiles with linear copies and read ds_read_b128
// fragments bank-conflict-optimally (G4/T2 recipe).
__global__ void bfsplit_kernel(const float* __restrict__ fT, int N,
                               u16* __restrict__ hi, u16* __restrict__ lo){
  int i = blockIdx.x*256 + threadIdx.x;      // over 4*N*64
  if (i >= 4*N*64) return;
  int c = i & 63;
  int n = i >> 6;                            // combined row b*N + ln; N % 8 == 0 so n&7 == ln&7
  float x = fT[i];
  u16 h = f2bf_rne(x);
  float hf = __uint_as_float((unsigned)h << 16);
  u16 l = f2bf_rne(x - hf);
  size_t o = ((size_t)n << 6) + (c ^ ((n & 7) << 3));
  hi[o] = h; lo[o] = l;
}

// MFMA feature-space self-kNN (C=64).  exact-ish distances via bf16 hi/lo split:
// inner = hi·hi + hi·lo + lo·hi (3x mfma_f32_16x16x32_bf16, fp32 accum, rel err ~2^-17).
// D[ref][query] orientation: lane = (g=l>>4, lm=l&15) holds query (qblk+w*16+lm)'s
// distances for refs {tile + m*16 + 4g + i}.
// Selection: shared float tau (max over 4 partition-lanes of bv[K-1], per-tile
// shfl_xor refresh) gates candidates into a per-thread CAP=8 LDS FIFO (occupancy;
// guard before each m-step drains when near-full; mid-tile drains leave tau valid).
template<int K>
__launch_bounds__(256, 4)
__global__ void knnmf_kernel(const u16* __restrict__ hi, const u16* __restrict__ lo,
                             const float* __restrict__ rr, int N, int NC,
                             float* __restrict__ cval, int* __restrict__ cidx){
  constexpr int CAP = 8;
  __shared__ __align__(16) u16 sHi[64*64];     // 8 KB, swizzled rows
  __shared__ __align__(16) u16 sLo[64*64];     // 8 KB
  __shared__ float sRR[64];
  __shared__ u64 sQ[256*(CAP+1)];              // per-thread 8-entry FIFO, stride 9 (18 KB)

  const int tid  = threadIdx.x;
  const int lane = tid & 63, w = tid >> 6;
  const int g    = lane >> 4;                  // 0..3
  const int lm   = lane & 15;
  const int qblk = blockIdx.x * 64;
  const int cid  = blockIdx.y, b = blockIdx.z;
  const int len  = N / NC, n0 = cid * len;

  const u16*  hib = hi + (size_t)b*N*64;
  const u16*  lob = lo + (size_t)b*N*64;
  const float* rrb = rr + (size_t)b*N;

  // ---- stage this block's 64 query rows, pull B-fragments into registers ----
  {
    const float4* sh = (const float4*)(hib + (size_t)qblk*64);
    const float4* sl = (const float4*)(lob + (size_t)qblk*64);
    float4* dh = (float4*)sHi; float4* dl = (float4*)sLo;
    for (int i = tid; i < 512; i += 256){ dh[i] = sh[i]; dl[i] = sl[i]; }
  }
  __syncthreads();
  const int qrow = w*16 + lm;                  // wave w owns queries qblk + w*16 .. +15
  const int kb0 = 8*g, kb1 = 32 + 8*g;         // frag k-offsets: k = koff + 8*(lane>>4) + i
  const int qsw = (qrow & 7) << 3;
  const bh8 qh0 = *(const bh8*)&sHi[qrow*64 + (kb0 ^ qsw)];
  const bh8 qh1 = *(const bh8*)&sHi[qrow*64 + (kb1 ^ qsw)];
  const bh8 ql0 = *(const bh8*)&sLo[qrow*64 + (kb0 ^ qsw)];
  const bh8 ql1 = *(const bh8*)&sLo[qrow*64 + (kb1 ^ qsw)];
  const float qq = rrb[qblk + qrow];

  float bv[K]; int bi[K];
  #pragma unroll
  for (int j = 0; j < K; j++){ bv[j] = NEG_BIG; bi[j] = n0; }
  float tau = NEG_BIG;                         // shared (4-partition) running K-th value
  u64* qbase = &sQ[tid*(CAP+1)];
  int qcnt = 0;

  // drain FIFOs into the sorted chain; tau NOT touched here (mid-tile safe)
  auto drainq = [&](){
    int k = 0;
    while (__any(k < qcnt)){
      if (k < qcnt){
        u64 e = qbase[k];
        float d = __uint_as_float((unsigned)(e >> 32));
        int j = (int)(unsigned)e;
        topk_ins_t<K,false>(bv, bi, d, j);
      }
      k++;
    }
    qcnt = 0;
  };

  for (int t0 = n0; t0 < n0 + len; t0 += 64){
    __syncthreads();                           // previous tile's frag reads done
    {
      const float4* sh = (const float4*)(hib + (size_t)t0*64);
      const float4* sl = (const float4*)(lob + (size_t)t0*64);
      float4* dh = (float4*)sHi; float4* dl = (float4*)sLo;
      for (int i = tid; i < 512; i += 256){ dh[i] = sh[i]; dl[i] = sl[i]; }
      if (tid < 64) sRR[tid] = rrb[t0 + tid];
    }
    __syncthreads();
    for (int m = 0; m < 4; m++){
      const int rrow = m*16 + lm;              // A-frag row owned by this lane
      const int sw = (rrow & 7) << 3;
      const bh8 ah0 = *(const bh8*)&sHi[rrow*64 + (kb0 ^ sw)];
      const bh8 ah1 = *(const bh8*)&sHi[rrow*64 + (kb1 ^ sw)];
      const bh8 al0 = *(const bh8*)&sLo[rrow*64 + (kb0 ^ sw)];
      const bh8 al1 = *(const bh8*)&sLo[rrow*64 + (kb1 ^ sw)];
      fx4 acc = {0.f, 0.f, 0.f, 0.f};
      acc = __builtin_amdgcn_mfma_f32_16x16x32_bf16(ah0, qh0, acc, 0, 0, 0);
      acc = __builtin_amdgcn_mfma_f32_16x16x32_bf16(ah1, qh1, acc, 0, 0, 0);
      acc = __builtin_amdgcn_mfma_f32_16x16x32_bf16(ah0, ql0, acc, 0, 0, 0);
      acc = __builtin_amdgcn_mfma_f32_16x16x32_bf16(ah1, ql1, acc, 0, 0, 0);
      acc = __builtin_amdgcn_mfma_f32_16x16x32_bf16(al0, qh0, acc, 0, 0, 0);
      acc = __builtin_amdgcn_mfma_f32_16x16x32_bf16(al1, qh1, acc, 0, 0, 0);
      const float4 rr4 = *(const float4*)&sRR[m*16 + 4*g];   // broadcast within 16-lane group
      const float rrv[4] = {rr4.x, rr4.y, rr4.z, rr4.w};
      const int jb = t0 + m*16 + 4*g;          // C/D rows: lane holds rows 4g+i
      if (__any(qcnt >= CAP-4)) drainq();      // guarantees room for 4 pushes
      #pragma unroll
      for (int i = 0; i < 4; i++){
        float d = fmaf(2.f, acc[i], -(qq + rrv[i]));
        if (d >= tau){                         // >= keeps boundary ties (exactness)
          qbase[qcnt] = (((u64)__float_as_uint(d)) << 32) | (unsigned)(jb + i);
          qcnt++;
        }
      }
    }
    // per-tile drain + shared-threshold refresh
    drainq();
    {
      float t = bv[K-1];
      t = fmaxf(t, __shfl_xor(t, 16));
      t = fmaxf(t, __shfl_xor(t, 32));
      tau = t;
    }
  }
  const int q = qblk + qrow;
  const size_t rowo = (((size_t)b*N + q)*(size_t)(NC*4) + (size_t)(cid*4 + g))*(size_t)K;
  float* ov = cval + rowo; int* oi = cidx + rowo;
  #pragma unroll
  for (int j = 0; j < K; j++){ ov[j] = bv[j]; oi[j] = bi[j]; }
}

// 1-thread-per-row merge, kept for K=1 only (T=NC trivial).
template<int K, bool TB>
__global__ void knn_merge_kernel(const float* __restrict__ cval, const int* __restrict__ cidx,
                                 int M, int NC, int* __restrict__ idxo){
  int i = blockIdx.x*256 + threadIdx.x;   // b*M + m
  if (i >= 4*M) return;
  const float* cv = cval + (size_t)i*NC*K;
  const int*   ci = cidx + (size_t)i*NC*K;
  float bv[K]; int bi[K];
  #pragma unroll
  for (int j = 0; j < K; j++){ bv[j] = NEG_BIG; bi[j] = 0; }
  int T = NC*K;
  for (int t = 0; t < T; t++)
    topk_ins_t<K,TB>(bv, bi, cv[t], ci[t]);
  int* orow = idxo + (size_t)i*K;
  #pragma unroll
  for (int j = 0; j < K; j++) orow[j] = bi[j];
}

// Wave-cooperative 16-lane multiway merge of NC (<=16) SORTED-descending chunks.
// r11 lesson: the 1-thread-per-row merge at M=1024 ran 16 blocks (0.7% occupancy,
// 193 us).  Chunks are sorted, so top-K = K-step multiway merge: lane j holds chunk
// j's head; per step a 4-deep shfl_xor u64-max picks the winner (key = (value desc,
// index asc) — exact for all producers since chunk lists keep equal values in
// ascending-j order and chunks are disjoint index ranges; keys instantaneously
// unique so the winner is unique), winner advances, lane 0 writes.
template<int K>
__global__ void knn_wmerge_kernel(const float* __restrict__ cval, const int* __restrict__ cidx,
                                  int M, int NC, int* __restrict__ idxo){
  int tid = threadIdx.x;
  int j   = tid & 15;                       // lane within 16-lane group
  int row = blockIdx.x*16 + (tid >> 4);     // b*M + m
  if (row >= 4*M) return;                   // whole 16-lane group exits together
  const float* cv = cval + (size_t)row*NC*K;
  const int*   ci = cidx + (size_t)row*NC*K;
  int h = 0;
  u64 key = 0;                              // 0 = exhausted/inactive sentinel
  if (j < NC){
    key = dkey(cv[j*K], ci[j*K]);
    h = 1;
  }
  int* orow = idxo + (size_t)row*K;
  #pragma unroll
  for (int s = 0; s < K; s++){
    u64 m0 = key;
    m0 = maxu64(m0, shfl_xor_u64(m0, 1));
    m0 = maxu64(m0, shfl_xor_u64(m0, 2));
    m0 = maxu64(m0, shfl_xor_u64(m0, 4));
    m0 = maxu64(m0, shfl_xor_u64(m0, 8));
    if (j == 0) orow[s] = key_j(m0);
    if (key == m0 && key != 0){             // unique winner advances its head
      if (h < K){ key = dkey(cv[j*K + h], ci[j*K + h]); h++; }
      else key = 0;
    }
  }
}

// ---------------- edge conv ----------------
__global__ void pq_kernel(const float* __restrict__ xT, int pitch, int C,
                          const float* __restrict__ WaT,
                          float* __restrict__ P, int N){
  int o = threadIdx.x & 63;
  int n = blockIdx.x*4 + (threadIdx.x >> 6);
  int b = blockIdx.y;
  if (n >= N) return;
  const float* row = xT + ((size_t)b*N + n)*pitch;
  float ap = 0.f;
  for (int c = 0; c < C; c++) ap = fmaf(WaT[c*64 + o], row[c], ap);
  P[((size_t)b*N + n)*64 + o] = ap;
}

// 4 points per 256-thread block: shared W1 tile, per-point sH. N % 4 == 0.
__global__ void edge2_kernel(const float* __restrict__ P, const float* __restrict__ featT,
                             int pitch, int C, const float* __restrict__ WqT,
                             const int* __restrict__ idx, const float* __restrict__ W1T,
                             float* __restrict__ outT, int N, int mask){
  __shared__ float sW[64*64];     // [c][o]
  __shared__ float sH[4*20*64];   // [t][kk][c]
  __shared__ float sx[4*64];
  int tid = threadIdx.x;
  int o = tid & 63, t = tid >> 6;
  int n = blockIdx.x*4 + t;
  int b = blockIdx.y;
  const float4* w4 = (const float4*)W1T;
  float4* s4 = (float4*)sW;
  for (int i = tid; i < 1024; i += 256) s4[i] = w4[i];
  if (o < C) sx[t*64 + o] = featT[((size_t)b*N + n)*pitch + o];
  __syncthreads();
  float qv = 0.f;
  for (int c = 0; c < C; c++) qv = fmaf(WqT[c*64 + o], sx[t*64 + c], qv);
  const float* Pb = P + (size_t)b*N*64;
  const int* irow = idx + ((size_t)b*N + n)*20;
  float* sHt = sH + t*1280;
  for (int kk = 0; kk < 20; kk++){
    int j = irow[kk] & mask;
    float h = Pb[(size_t)j*64 + o] + qv;
    sHt[kk*64 + o] = h >= 0.f ? h : 0.2f*h;
  }
  __syncthreads();
  float acc[20];
  #pragma unroll
  for (int kk = 0; kk < 20; kk++) acc[kk] = 0.f;
  for (int c = 0; c < 64; c += 4){
    float w0 = sW[c*64+o], w1 = sW[(c+1)*64+o], w2 = sW[(c+2)*64+o], w3 = sW[(c+3)*64+o];
    #pragma unroll
    for (int kk = 0; kk < 20; kk++){
      float4 h4 = *(const float4*)&sHt[kk*64 + c];
      float a = acc[kk];
      a = fmaf(w0, h4.x, a); a = fmaf(w1, h4.y, a);
      a = fmaf(w2, h4.z, a); a = fmaf(w3, h4.w, a);
      acc[kk] = a;
    }
  }
  float m = NEG_BIG;
  #pragma unroll
  for (int kk = 0; kk < 20; kk++) m = fmaxf(m, acc[kk]);
  outT[((size_t)b*N + n)*64 + o] = lrelu(m);
}

// 4 points per 256-thread block. N % 4 == 0.
__global__ void edge1_kernel(const float* __restrict__ P, const float* __restrict__ featT,
                             int pitch, int C, const float* __restrict__ WqT,
                             const int* __restrict__ idx, float* __restrict__ outT,
                             int N, int K, int mask){
  __shared__ float sx[4*64];
  int tid = threadIdx.x;
  int o = tid & 63, t = tid >> 6;
  int n = blockIdx.x*4 + t;
  int b = blockIdx.y;
  if (o < C) sx[t*64 + o] = featT[((size_t)b*N + n)*pitch + o];
  __syncthreads();
  float qv = 0.f;
  for (int c = 0; c < C; c++) qv = fmaf(WqT[c*64 + o], sx[t*64 + c], qv);
  const float* Pb = P + (size_t)b*N*64;
  const int* irow = idx + ((size_t)b*N + n)*K;
  float m = NEG_BIG;
  for (int kk = 0; kk < K; kk++){
    int j = irow[kk] & mask;
    m = fmaxf(m, Pb[(size_t)j*64 + o] + qv);
  }
  outT[((size_t)b*N + n)*64 + o] = lrelu(m);
}

__global__ void gmax_kernel(const float* __restrict__ inT, const int* __restrict__ idx,
                            float* __restrict__ outT, int Nin, int M, int K, int mask){
  int o = threadIdx.x; int m = blockIdx.x; int b = blockIdx.y;
  const float* ib = inT + (size_t)b*Nin*64;
  const int* irow = idx + ((size_t)b*M + m)*K;
  float v = NEG_BIG;
  for (int kk = 0; kk < K; kk++){
    int j = irow[kk] & mask;
    v = fmaxf(v, ib[(size_t)j*64 + o]);
  }
  outT[((size_t)b*M + m)*64 + o] = v;
}

__global__ void reluadd_kernel(float* __restrict__ x, const float* __restrict__ f, int total){
  int i = blockIdx.x*256 + threadIdx.x;
  if (i >= total) return;
  float v = x[i] + f[i];
  x[i] = v > 0.f ? v : 0.f;
}

// ---------------- global feature path ----------------
#define PSTRIDE 85
__launch_bounds__(256, 4)
__global__ void pool_kernel(const float* __restrict__ xT, const void* __restrict__ W,
                            const int* __restrict__ dtf, float* __restrict__ partial,
                            int N, int npts, int segbase){
  __shared__ __align__(16) float sX[32*64];   // 8 KB
  int tid = threadIdx.x;
  int ot = blockIdx.x, chunk = blockIdx.y, b = blockIdx.z;
  int isbf = *dtf;
  int o = ot*256 + tid;
  float wr[64];
  #pragma unroll
  for (int c = 0; c < 64; c++) wr[c] = ldx(W, (size_t)o*64 + c, isbf);
  int n0 = chunk * npts;
  float m = NEG_BIG;
  for (int s0 = 0; s0 < npts; s0 += 32){
    __syncthreads();
    const float4* src = (const float4*)(xT + ((size_t)b*N + n0 + s0)*64);
    float4* dst = (float4*)sX;
    for (int i = tid; i < 512; i += 256) dst[i] = src[i];
    __syncthreads();
    for (int t = 0; t < 32; t += 4){
      float a0 = 0.f, a1 = 0.f, a2 = 0.f, a3 = 0.f;
      #pragma unroll
      for (int c4 = 0; c4 < 16; c4++){
        float4 x0 = *(const float4*)&sX[(t+0)*64 + c4*4];
        float4 x1 = *(const float4*)&sX[(t+1)*64 + c4*4];
        float4 x2 = *(const float4*)&sX[(t+2)*64 + c4*4];
        float4 x3 = *(const float4*)&sX[(t+3)*64 + c4*4];
        float w0 = wr[c4*4+0], w1 = wr[c4*4+1], w2 = wr[c4*4+2], w3 = wr[c4*4+3];
        a0 = fmaf(w0, x0.x, a0); a0 = fmaf(w1, x0.y, a0); a0 = fmaf(w2, x0.z, a0); a0 = fmaf(w3, x0.w, a0);
        a1 = fmaf(w0, x1.x, a1); a1 = fmaf(w1, x1.y, a1); a1 = fmaf(w2, x1.z, a1); a1 = fmaf(w3, x1.w, a1);
        a2 = fmaf(w0, x2.x, a2); a2 = fmaf(w1, x2.y, a2); a2 = fmaf(w2, x2.z, a2); a2 = fmaf(w3, x2.w, a2);
        a3 = fmaf(w0, x3.x, a3); a3 = fmaf(w1, x3.y, a3); a3 = fmaf(w2, x3.z, a3); a3 = fmaf(w3, x3.w, a3);
      }
      m = fmaxf(m, fmaxf(fmaxf(a0,a1), fmaxf(a2,a3)));
    }
  }
  partial[((size_t)b*1024 + o)*PSTRIDE + segbase + chunk] = m;
}

__global__ void gred_kernel(const float* __restrict__ partial, float* __restrict__ g, int S){
  int i = blockIdx.x*256 + threadIdx.x;
  if (i >= 4*1024) return;
  const float* p = partial + (size_t)i*PSTRIDE;
  float m = NEG_BIG;
  for (int s = 0; s < S; s++) m = fmaxf(m, p[s]);
  g[i] = lrelu(m);
}

__global__ void gw_kernel(const float* __restrict__ g, const void* __restrict__ W13,
                          const int* __restrict__ dtf, float* __restrict__ gW){
  int o = blockIdx.x, b = blockIdx.y;
  int lane = threadIdx.x;
  int isbf = *dtf;
  const float* gb = g + b*1024;
  float acc = 0.f;
  for (int c = lane; c < 1024; c += 64)
    acc = fmaf(ldx(W13, (size_t)o*1088 + c, isbf), gb[c], acc);
  for (int s = 32; s > 0; s >>= 1) acc += __shfl_down(acc, s, 64);
  if (lane == 0) gW[b*256 + o] = acc;
}

// ---------------- decoder MLPs (fused unpool gather) ----------------
__global__ void mlp_kernel(const float* __restrict__ base,
    const float* __restrict__ in1, const int* __restrict__ idx1, int N1, int C1,
    const float* __restrict__ W1T,
    const float* __restrict__ in2, int C2, const float* __restrict__ W2T,
    float* __restrict__ outT, int N, int Cout){
  __shared__ float sIn[4*320];
  int o = threadIdx.x, b = blockIdx.y;
  int n0 = blockIdx.x*4;
  int Cin = C1 + C2;
  int mask1 = N1 - 1;
  for (int t = 0; t < 4; t++){
    int n = n0 + t;
    int r1 = idx1 ? (idx1[(size_t)b*N + n] & mask1) : n;
    const float* p1 = in1 + ((size_t)b*N1 + r1)*C1;
    for (int c = o; c < C1; c += Cout) sIn[t*Cin + c] = p1[c];
    if (in2){
      const float* p2 = in2 + ((size_t)b*N + n)*C2;
      for (int c = o; c < C2; c += Cout) sIn[t*Cin + C1 + c] = p2[c];
    }
  }
  __syncthreads();
  float init = base ? base[b*Cout + o] : 0.f;
  float a0 = init, a1 = init, a2 = init, a3 = init;
  for (int c = 0; c < C1; c++){
    float wv = W1T[c*Cout + o];
    a0 = fmaf(wv, sIn[0*Cin + c], a0);
    a1 = fmaf(wv, sIn[1*Cin + c], a1);
    a2 = fmaf(wv, sIn[2*Cin + c], a2);
    a3 = fmaf(wv, sIn[3*Cin + c], a3);
  }
  for (int c = 0; c < C2; c++){
    float wv = W2T[c*Cout + o];
    a0 = fmaf(wv, sIn[0*Cin + C1 + c], a0);
    a1 = fmaf(wv, sIn[1*Cin + C1 + c], a1);
    a2 = fmaf(wv, sIn[2*Cin + C1 + c], a2);
    a3 = fmaf(wv, sIn[3*Cin + C1 + c], a3);
  }
  size_t ob = ((size_t)b*N + n0)*Cout + o;
  outT[ob]          = lrelu(a0);
  outT[ob + Cout]   = lrelu(a1);
  outT[ob + 2*Cout] = lrelu(a2);
  outT[ob + 3*Cout] = lrelu(a3);
}

__global__ void dec0_kernel(const float* __restrict__ h1T, const int* __restrict__ idxU0,
                            const float* __restrict__ x0T, const float* __restrict__ W16T,
                            const void* __restrict__ W17, const int* __restrict__ dtf,
                            void* __restrict__ out){
  __shared__ float sIn[4*320];
  __shared__ float sH0[4*128];
  int o = threadIdx.x;   // 128 threads
  int b = blockIdx.y; int n0 = blockIdx.x*4;
  for (int t = 0; t < 4; t++){
    int n = n0 + t;
    int r1 = idxU0[(size_t)b*4096 + n] & 1023;
    const float* p1 = h1T + ((size_t)b*1024 + r1)*256;
    for (int c = o; c < 256; c += 128) sIn[t*320 + c] = p1[c];
    const float* p2 = x0T + ((size_t)b*4096 + n)*64;
    if (o < 64) sIn[t*320 + 256 + o] = p2[o];
  }
  __syncthreads();
  float a0 = 0.f, a1 = 0.f, a2 = 0.f, a3 = 0.f;
  for (int c = 0; c < 256; c++){
    float wv = W16T[c*128 + o];
    a0 = fmaf(wv, sIn[0*320 + c], a0);
    a1 = fmaf(wv, sIn[1*320 + c], a1);
    a2 = fmaf(wv, sIn[2*320 + c], a2);
    a3 = fmaf(wv, sIn[3*320 + c], a3);
  }
  for (int c = 0; c < 64; c++){
    float wv = W16T[(256 + c)*128 + o];
    a0 = fmaf(wv, sIn[0*320 + 256 + c], a0);
    a1 = fmaf(wv, sIn[1*320 + 256 + c], a1);
    a2 = fmaf(wv, sIn[2*320 + 256 + c], a2);
    a3 = fmaf(wv, sIn[3*320 + 256 + c], a3);
  }
  sH0[0*128 + o] = lrelu(a0);
  sH0[1*128 + o] = lrelu(a1);
  sH0[2*128 + o] = lrelu(a2);
  sH0[3*128 + o] = lrelu(a3);
  __syncthreads();
  if (o < 52){
    int isbf = *dtf;
    int p = o / 13, cc = o % 13;
    float acc = 0.f;
    for (int c2 = 0; c2 < 128; c2++)
      acc = fmaf(ldx(W17, (size_t)cc*128 + c2, isbf), sH0[p*128 + c2], acc);
    if (!(acc == acc && fabsf(acc) < 1e30f)) acc = 0.f;
    stout(out, ((size_t)b*13 + cc)*4096 + (n0 + p), acc, isbf);
  }
}

// ---------------- host ----------------
extern "C" void kernel_launch(void* const* d_in, const int* in_sizes, int n_in,
                              void* d_out, int out_size, void* d_ws, size_t ws_size,
                              hipStream_t stream){
  (void)in_sizes; (void)n_in; (void)out_size;
  const int B = 4;
  const void* X       = d_in[0];
  const void* w_ec1_0 = d_in[1];
  const void* w_ec1_1 = d_in[2];
  const void* w_ec2_0 = d_in[3];
  const void* w_ec2_1 = d_in[4];
  const void* w_ec4_0 = d_in[5];
  const void* w_ec4_1 = d_in[6];
  const void* w_ec5_0 = d_in[7];
  const void* w_ec5_1 = d_in[8];
  const void* w_ec7   = d_in[9];
  const void* w_ec8   = d_in[10];
  const void* w_ec10  = d_in[11];
  const void* w_ec11  = d_in[12];
  const void* w_pn3   = d_in[13];
  const void* w_pn6   = d_in[14];
  const void* w_pn9   = d_in[15];
  const void* w_pn12  = d_in[16];
  const void* w_pn13  = d_in[17];
  const void* w_pn14  = d_in[18];
  const void* w_pn15  = d_in[19];
  const void* w_pn16  = d_in[20];
  const void* w_c17   = d_in[21];
  void* out = d_out;

  // ---- workspace layout (fp32 words; lifetime-aliased) ----
  float* wsf = (float*)d_ws;
  size_t off = 0;
  auto alloc = [&](size_t n)->float*{
    float* p = wsf + off; off += (n + 63) & ~(size_t)63; return p;
  };
  int*   dtf = (int*)alloc(64);
  float* xfT = alloc(4*4096*9);
  float* rr  = alloc(4*4096);
  float* partial = alloc(4*1024*85);
  float* g   = alloc(4*1024);
  float* gW  = alloc(4*256);
  int*   idx = (int*)alloc(4*4096*20);
  int*   idxU2 = (int*)alloc(4*256);
  int*   idxU1 = (int*)alloc(4*1024);
  int*   idxU0 = (int*)alloc(4*4096);
  float* ec1a = alloc(9*64);  float* ec1q = alloc(9*64);  float* ec1w1 = alloc(64*64);
  float* ec2a = alloc(64*64); float* ec2q = alloc(64*64); float* ec2w1 = alloc(64*64);
  float* ec4a = alloc(64*64); float* ec4q = alloc(64*64); float* ec4w1 = alloc(64*64);
  float* ec5a = alloc(64*64); float* ec5q = alloc(64*64); float* ec5w1 = alloc(64*64);
  float* ec7a = alloc(64*64); float* ec7q = alloc(64*64);
  float* ec8a = alloc(64*64); float* ec8q = alloc(64*64);
  float* ec10a = alloc(64*64); float* ec10q = alloc(64*64);
  float* ec11a = alloc(64*64); float* ec11q = alloc(64*64);
  float* wp13 = alloc(64*256);
  float* wt14 = alloc(320*256);
  float* wt15 = alloc(320*256);
  float* wt16 = alloc(320*128);
  float* P   = alloc(4*4096*64);
  float* hA  = alloc(4*4096*64);    // decoder: h1T alias (exact size)
  float* x0T = alloc(4*4096*64);
  float* x1T = alloc(4*1024*64);
  float* x2T = alloc(4*256*64);
  float* x3T = alloc(4*64*64);
  float* n1f = alloc(4*1024*64);    // decoder: h3T + head of h2T
  float* n2f = alloc(4*256*64);     // contiguous after n1f; h2T tail
  float* n3f = alloc(4*64*64);
  u16*   bhi = (u16*)alloc(4*4096*64/2);   // bf16 hi split (pre-swizzled), 2 MB
  u16*   blo = (u16*)alloc(4*4096*64/2);   // bf16 lo split (pre-swizzled), 2 MB
  float* h1T = hA;
  float* h3T = n1f;
  float* h2T = n1f + 65536;

  // ws-aware candidate sizing (ws_size constant across calls)
  size_t rem = (ws_size/4 > off + 256) ? (ws_size/4 - off - 256) : 0;
  size_t half = rem / 2;
  int NCbig = (half >= (size_t)4*4096*16*20) ? 16 :
              (half >= (size_t)4*4096*8*20)  ? 8  : 4;
  size_t E = (size_t)4*4096*20*NCbig;
  float* cval = alloc(E);
  int*   cidx = (int*)alloc(E);

  detect_kernel<<<dim3(1), 256, 0, stream>>>((const unsigned int*)X, dtf);

  // ---- weight prep ----
  w0_kernel<<<dim3(3), 256, 0, stream>>>(w_ec1_0, dtf, 9, ec1a, ec1q);
  w0_kernel<<<dim3(16), 256, 0, stream>>>(w_ec2_0, dtf, 64, ec2a, ec2q);
  w0_kernel<<<dim3(16), 256, 0, stream>>>(w_ec4_0, dtf, 64, ec4a, ec4q);
  w0_kernel<<<dim3(16), 256, 0, stream>>>(w_ec5_0, dtf, 64, ec5a, ec5q);
  w0_kernel<<<dim3(16), 256, 0, stream>>>(w_ec7, dtf, 64, ec7a, ec7q);
  w0_kernel<<<dim3(16), 256, 0, stream>>>(w_ec8, dtf, 64, ec8a, ec8q);
  w0_kernel<<<dim3(16), 256, 0, stream>>>(w_ec10, dtf, 64, ec10a, ec10q);
  w0_kernel<<<dim3(16), 256, 0, stream>>>(w_ec11, dtf, 64, ec11a, ec11q);
  wt_kernel<<<dim3(16), 256, 0, stream>>>(w_ec1_1, dtf, 64, 64, 0, 64, ec1w1);
  wt_kernel<<<dim3(16), 256, 0, stream>>>(w_ec2_1, dtf, 64, 64, 0, 64, ec2w1);
  wt_kernel<<<dim3(16), 256, 0, stream>>>(w_ec4_1, dtf, 64, 64, 0, 64, ec4w1);
  wt_kernel<<<dim3(16), 256, 0, stream>>>(w_ec5_1, dtf, 64, 64, 0, 64, ec5w1);
  wt_kernel<<<dim3(64), 256, 0, stream>>>(w_pn13, dtf, 256, 1088, 1024, 64, wp13);
  wt_kernel<<<dim3(320), 256, 0, stream>>>(w_pn14, dtf, 256, 320, 0, 320, wt14);
  wt_kernel<<<dim3(320), 256, 0, stream>>>(w_pn15, dtf, 256, 320, 0, 320, wt15);
  wt_kernel<<<dim3(160), 256, 0, stream>>>(w_pn16, dtf, 128, 320, 0, 320, wt16);

  xconv_kernel<<<dim3(64), 256, 0, stream>>>(X, dtf, xfT);
  nodecopy_kernel<<<dim3(64), 256, 0, stream>>>(X, dtf, out);

  const size_t xbs = (size_t)4096*9;
  // coord-space kNN on xfT (pitch 9). len=N/NC must be multiple of 64.
  auto knn_f = [&](int C, int K, int M, int N, int NC, int* io){
    rownorm_kernel<<<dim3((N+255)/256, B), 256, 0, stream>>>(xfT, 9, xbs, C, N, rr);
    dim3 gd((M+255)/256, NC, B);
    if (C == 9)      knn_chunk_kernel<9,20,64><<<gd,256,0,stream>>>(xfT,9,xbs,xfT,9,xbs,rr,M,N,NC,cval,cidx);
    else if (K==20)  knn_chunk_kernel<3,20,64><<<gd,256,0,stream>>>(xfT,9,xbs,xfT,9,xbs,rr,M,N,NC,cval,cidx);
    else             knn_chunk_kernel<3,1,64><<<gd,256,0,stream>>>(xfT,9,xbs,xfT,9,xbs,rr,M,N,NC,cval,cidx);
    if (K == 20)     knn_wmerge_kernel<20><<<dim3((4*M+15)/16), 256, 0, stream>>>(cval,cidx,M,NC,io);
    else             knn_merge_kernel<1,false><<<dim3((4*M+255)/256), 256, 0, stream>>>(cval,cidx,M,NC,io);
  };
  // feature-space self-kNN (C=64).
  auto knn_b = [&](int K, const float* fT, int N, int NC, int* io){
    rownorm_kernel<<<dim3((N+255)/256, B), 256, 0, stream>>>(fT, 64, (size_t)N*64, 64, N, rr);
    if (K == 20 && N >= 1024){
      int NCm = NCbig / 4; if (NCm < 1) NCm = 1;     // NC*4 virtual chunks must fit cval
      int cap = (N == 4096) ? 2 : 4;
      if (NCm > cap) NCm = cap;
      bfsplit_kernel<<<dim3((4*N*64)/256), 256, 0, stream>>>(fT, N, bhi, blo);
      knnmf_kernel<20><<<dim3(N/64, NCm, B), 256, 0, stream>>>(bhi, blo, rr, N, NCm, cval, cidx);
      knn_wmerge_kernel<20><<<dim3((4*N+15)/16), 256, 0, stream>>>(cval, cidx, N, NCm*4, io);
    } else {
      dim3 gd(N/64, NC, B);
      if (K == 20) knn64_kernel<20><<<gd,64,0,stream>>>(fT, rr, N, NC, cval, cidx);
      else         knn64_kernel<10><<<gd,64,0,stream>>>(fT, rr, N, NC, cval, cidx);
      dim3 gm((4*N+15)/16);
      if (K == 20) knn_wmerge_kernel<20><<<gm,256,0,stream>>>(cval,cidx,N,NC,io);
      else         knn_wmerge_kernel<10><<<gm,256,0,stream>>>(cval,cidx,N,NC,io);
    }
  };
  auto edge2_b = [&](const float* fT, int N, int NC, float* wa, float* wq, float* w1, float* oT){
    knn_b(20, fT, N, NC, idx);
    pq_kernel<<<dim3((N+3)/4, B), 256, 0, stream>>>(fT, 64, 64, wa, P, N);
    edge2_kernel<<<dim3(N/4, B), 256, 0, stream>>>(P, fT, 64, 64, wq, idx, w1, oT, N, N-1);
  };
  auto edge1_b = [&](const float* fT, int N, int NC, int K, float* wa, float* wq, float* oT){
    knn_b(K, fT, N, NC, idx);
    pq_kernel<<<dim3((N+3)/4, B), 256, 0, stream>>>(fT, 64, 64, wa, P, N);
    edge1_kernel<<<dim3(N/4, B), 256, 0, stream>>>(P, fT, 64, 64, wq, idx, oT, N, K, N-1);
  };

  // level 0
  int nc9 = (NCbig < 8) ? NCbig : 8;                     // len 512
  knn_f(9, 20, 4096, 4096, nc9, idx);
  pq_kernel<<<dim3(1024, B), 256, 0, stream>>>(xfT, 9, 9, ec1a, P, 4096);
  edge2_kernel<<<dim3(1024, B), 256, 0, stream>>>(P, xfT, 9, 9, ec1q, idx, ec1w1, hA, 4096, 4095);
  edge2_b(hA, 4096, NCbig, ec2a, ec2q, ec2w1, x0T);
  pool_kernel<<<dim3(4,64,4), 256, 0, stream>>>(x0T, w_pn3, dtf, partial, 4096, 64, 0);
  // rand_pool 1
  knn_f(3, 20, 1024, 4096, 16, idx);                     // len 256
  gmax_kernel<<<dim3(1024, B), 64, 0, stream>>>(x0T, idx, n1f, 4096, 1024, 20, 4095);
  // level 1
  edge2_b(n1f, 1024, 16, ec4a, ec4q, ec4w1, hA);
  edge2_b(hA, 1024, 16, ec5a, ec5q, ec5w1, x1T);
  pool_kernel<<<dim3(4,16,4), 256, 0, stream>>>(x1T, w_pn6, dtf, partial, 1024, 64, 64);
  reluadd_kernel<<<dim3(1024), 256, 0, stream>>>(x1T, n1f, 4*1024*64);
  // rand_pool 2
  knn_f(3, 20, 256, 1024, 16, idx);                      // len 64
  gmax_kernel<<<dim3(256, B), 64, 0, stream>>>(x1T, idx, n2f, 1024, 256, 20, 1023);
  // level 2
  edge1_b(n2f, 256, 16, 20, ec7a, ec7q, hA);             // len 16
  edge1_b(hA, 256, 16, 20, ec8a, ec8q, x2T);
  pool_kernel<<<dim3(4,4,4), 256, 0, stream>>>(x2T, w_pn9, dtf, partial, 256, 64, 80);
  reluadd_kernel<<<dim3(256), 256, 0, stream>>>(x2T, n2f, 4*256*64);
  // rand_pool 3
  knn_f(3, 20, 64, 256, 4, idx);                         // len 64 (chunk TN bound)
  gmax_kernel<<<dim3(64, B), 64, 0, stream>>>(x2T, idx, n3f, 256, 64, 20, 255);
  // level 3
  edge1_b(n3f, 64, 8, 10, ec10a, ec10q, hA);             // len 8
  edge1_b(hA, 64, 8, 10, ec11a, ec11q, x3T);
  pool_kernel<<<dim3(4,1,4), 256, 0, stream>>>(x3T, w_pn12, dtf, partial, 64, 64, 84);
  reluadd_kernel<<<dim3(64), 256, 0, stream>>>(x3T, n3f, 4*64*64);
  // ---- idx, P, hA, n1f, n2f dead -> h3T/h2T/h1T aliases live ----
  gred_kernel<<<dim3(16), 256, 0, stream>>>(partial, g, 85);
  gw_kernel<<<dim3(256, 4), 64, 0, stream>>>(g, w_pn13, dtf, gW);
  mlp_kernel<<<dim3(16, B), 256, 0, stream>>>(gW, x3T, nullptr, 64, 64, wp13,
                                              nullptr, 0, nullptr, h3T, 64, 256);
  knn_f(3, 1, 256, 64, 1, idxU2);                        // len 64
  mlp_kernel<<<dim3(64, B), 256, 0, stream>>>(nullptr, h3T, idxU2, 64, 256, wt14,
                                              x2T, 64, wt14 + 256*256, h2T, 256, 256);
  knn_f(3, 1, 1024, 256, 4, idxU1);                      // len 64
  mlp_kernel<<<dim3(256, B), 256, 0, stream>>>(nullptr, h2T, idxU1, 256, 256, wt15,
                                               x1T, 64, wt15 + 256*256, h1T, 1024, 256);
  knn_f(3, 1, 4096, 1024, 4, idxU0);                     // len 256
  dec0_kernel<<<dim3(1024, B), 128, 0, stream>>>(h1T, idxU0, x0T, wt16, w_c17, dtf, out);
}

// Round 13
// 1721.805 us; speedup vs baseline: 1.9361x; 1.0333x over previous
//
#include <hip/hip_runtime.h>
#include <hip/hip_bf16.h>
#include <float.h>

typedef __hip_bfloat16 bf16;
typedef unsigned short u16;
typedef unsigned long long u64;
typedef __attribute__((ext_vector_type(8))) short bh8;   // 8 bf16 = 4 VGPRs (MFMA A/B frag)
typedef __attribute__((ext_vector_type(4))) float fx4;   // MFMA C/D frag

#define NEG_BIG (-1.0e30f)

__device__ __forceinline__ bf16 f2b(float v){ return __float2bfloat16(v); }
__device__ __forceinline__ float lrelu(float x){ return x >= 0.f ? x : 0.2f*x; }

// round-to-nearest-even fp32 -> bf16 bits
__device__ __forceinline__ u16 f2bf_rne(float x){
  unsigned u = __float_as_uint(x);
  unsigned r = (u + 0x7FFFu + ((u >> 16) & 1u)) >> 16;
  return (u16)r;
}

// dtype-flexible sanitized load from a raw INPUT buffer (element index)
__device__ __forceinline__ float ldx(const void* p, size_t i, int isbf){
  float v = isbf ? __bfloat162float(((const bf16*)p)[i]) : ((const float*)p)[i];
  return (v == v && fabsf(v) < 1e30f) ? v : 0.f;
}
// dtype-flexible store to the OUTPUT buffer (element index)
__device__ __forceinline__ void stout(void* p, size_t i, float v, int isbf){
  if (isbf) ((bf16*)p)[i] = f2b(v);
  else      ((float*)p)[i] = v;
}

// ---- packed sort key for the wave-merge ONLY (r7/r8 lesson: never pack in the
// per-candidate filter path; here it's ~36 packs per output row — negligible).
// key = ord(d)<<32 | ~j : (value desc, index asc) lexicographic == u64 '>'.
__device__ __forceinline__ u64 dkey(float d, int j){
  unsigned u = __float_as_uint(d);
  u ^= (unsigned)(((int)u) >> 31) | 0x80000000u;
  return ((u64)u << 32) | (u64)(~(unsigned)j);
}
__device__ __forceinline__ int key_j(u64 k){ return (int)~(unsigned)k; }
__device__ __forceinline__ u64 shfl_xor_u64(u64 v, int m){
  unsigned lo = (unsigned)v, hi = (unsigned)(v >> 32);
  lo = __shfl_xor(lo, m); hi = __shfl_xor(hi, m);
  return ((u64)hi << 32) | (u64)lo;
}
__device__ __forceinline__ u64 maxu64(u64 a, u64 b){ return a > b ? a : b; }

// carry-chain sorted top-K insert (bv descending, bv[K-1] = min).
template<int K, bool TB>
__device__ __forceinline__ void topk_ins_t(float (&bv)[K], int (&bi)[K], float d, int j){
  bool gate = TB ? (d > bv[K-1] || (d == bv[K-1] && j < bi[K-1])) : (d > bv[K-1]);
  if (gate){
    bool gt[K];
    #pragma unroll
    for (int s = 0; s < K; s++)
      gt[s] = TB ? (d > bv[s] || (d == bv[s] && j < bi[s])) : (d > bv[s]);
    #pragma unroll
    for (int s = K-1; s > 0; s--){
      float nv = gt[s-1] ? bv[s-1] : d;
      int   ni = gt[s-1] ? bi[s-1] : j;
      bv[s] = gt[s] ? nv : bv[s];
      bi[s] = gt[s] ? ni : bi[s];
    }
    if (gt[0]){ bv[0] = d; bi[0] = j; }
  }
}
template<int K>
__device__ __forceinline__ void topk_ins(float (&bv)[K], int (&bi)[K], float d, int j){
  topk_ins_t<K,false>(bv, bi, d, j);
}

// ---------------- input dtype detector ----------------
__global__ void detect_kernel(const unsigned int* __restrict__ X, int* __restrict__ flag){
  __shared__ int cnt;
  if (threadIdx.x == 0) cnt = 0;
  __syncthreads();
  int hits = 0;
  for (int i = threadIdx.x; i < 8192; i += 256){
    unsigned w = X[i];
    unsigned lo = w & 0xFFFFu;
    unsigned e = (lo >> 7) & 0xFFu;
    if ((e >= 0x76u && e <= 0x84u) || lo == 0u) hits++;
  }
  atomicAdd(&cnt, hits);
  __syncthreads();
  if (threadIdx.x == 0) flag[0] = (cnt > 4096) ? 1 : 0;
}

// ---------------- weight prep ----------------
__global__ void wt_kernel(const void* __restrict__ W, const int* __restrict__ dtf,
                          int Cout, int pitch, int coff, int Cin, float* __restrict__ WT){
  int i = blockIdx.x*256 + threadIdx.x;
  if (i >= Cin*Cout) return;
  int isbf = *dtf;
  int c = i / Cout, o = i - c*Cout;
  WT[i] = ldx(W, (size_t)o*pitch + coff + c, isbf);
}

__global__ void w0_kernel(const void* __restrict__ W0, const int* __restrict__ dtf,
                          int C, float* __restrict__ WaT, float* __restrict__ WqT){
  int i = blockIdx.x*256 + threadIdx.x;
  if (i >= C*64) return;
  int isbf = *dtf;
  int c = i >> 6, o = i & 63;
  float a = ldx(W0, (size_t)o*2*C + c, isbf);
  float q = ldx(W0, (size_t)o*2*C + C + c, isbf);
  WaT[i] = a; WqT[i] = q - a;
}

__global__ void xconv_kernel(const void* __restrict__ x, const int* __restrict__ dtf,
                             float* __restrict__ xfT){
  int i = blockIdx.x*256 + threadIdx.x;
  if (i >= 4*4096) return;
  int isbf = *dtf;
  int b = i >> 12, n = i & 4095;
  for (int c = 0; c < 9; c++)
    xfT[((size_t)b*4096 + n)*9 + c] = ldx(x, ((size_t)b*9 + c)*4096 + n, isbf);
}

__global__ void nodecopy_kernel(const void* __restrict__ x, const int* __restrict__ dtf,
                                void* __restrict__ out){
  int i = blockIdx.x*256 + threadIdx.x;
  int isbf = *dtf;
  if (i < 12288){
    int b = i / 3072, r = i % 3072; int c = r / 1024, m = r % 1024;
    stout(out, 212992 + i, ldx(x, ((size_t)b*9 + c)*4096 + m, isbf), isbf);
  } else if (i < 15360){
    int j = i - 12288; int b = j / 768, r = j % 768; int c = r / 256, m = r % 256;
    stout(out, 212992 + i, ldx(x, ((size_t)b*9 + c)*4096 + m, isbf), isbf);
  } else if (i < 16128){
    int j = i - 15360; int b = j / 192, r = j % 192; int c = r / 64, m = r % 64;
    stout(out, 212992 + i, ldx(x, ((size_t)b*9 + c)*4096 + m, isbf), isbf);
  }
}

// ---------------- kNN ----------------
__global__ void rownorm_kernel(const float* __restrict__ T, int pitch, size_t bs,
                               int C, int N, float* __restrict__ rr){
  int n = blockIdx.x*256 + threadIdx.x;
  int b = blockIdx.y;
  if (n >= N) return;
  const float* row = T + (size_t)b*bs + (size_t)n*pitch;
  float s = 0.f;
  for (int c = 0; c < C; c++) s = fmaf(row[c], row[c], s);
  rr[b*N + n] = s;
}

// small-C chunked kNN (C=3/9; per-thread query in registers, refs staged in LDS).
// Refs staged TRANSPOSED [c][t]: wave-uniform ds_read_b128 broadcasts (4 cands/read).
// K>=8: tau-gated per-thread LDS FIFO (CAP=8) + per-tile drains + overflow guard.
// REQUIREMENT: len = N/NC must be a multiple of TN.
template<int C, int K, int TN>
__global__ void knn_chunk_kernel(const float* __restrict__ qT, int qpitch, size_t qbs,
                                 const float* __restrict__ rT, int rpitch, size_t rbs,
                                 const float* __restrict__ rr, int M, int N, int NC,
                                 float* __restrict__ cval, int* __restrict__ cidx){
  constexpr bool FIFO = (K >= 8);
  constexpr int CAP = 8;
  __shared__ __align__(16) float sRT[C*TN];   // [c][t]
  __shared__ __align__(16) float sN[TN];
  __shared__ u64 sQ[FIFO ? 256*(CAP+1) : 1];  // per-thread FIFO, stride 9 u64 (18 KB)
  int tid = threadIdx.x;
  int m = blockIdx.x*256 + tid;
  int cid = blockIdx.y, b = blockIdx.z;
  int len = N / NC;
  int n0 = cid * len;
  bool active = (m < M);
  float q[C]; float qq = 0.f;
  if (active){
    const float* qrow = qT + (size_t)b*qbs + (size_t)m*qpitch;
    #pragma unroll
    for (int c = 0; c < C; c++){ q[c] = qrow[c]; qq = fmaf(q[c], q[c], qq); }
  }
  float bv[K]; int bi[K];
  #pragma unroll
  for (int j = 0; j < K; j++){ bv[j] = NEG_BIG; bi[j] = n0; }
  float tau = NEG_BIG;
  u64* qb = FIFO ? &sQ[tid*(CAP+1)] : (u64*)nullptr;
  int qcnt = 0;
  const float* rbase = rT + (size_t)b*rbs;
  const float* rrb = rr + b*N;

  auto drain = [&](){
    int k = 0;
    while (__any(k < qcnt)){
      if (k < qcnt){
        u64 e = qb[k];
        float d = __uint_as_float((unsigned)(e >> 32));
        int j = (int)(unsigned)e;
        topk_ins_t<K,false>(bv, bi, d, j);
      }
      k++;
    }
    qcnt = 0;
    tau = bv[K-1];
  };

  for (int t0 = 0; t0 < len; t0 += TN){
    __syncthreads();
    for (int i = tid; i < TN*C; i += 256){
      int c = i / TN, t = i - c*TN;
      sRT[i] = rbase[(size_t)(n0 + t0 + t)*rpitch + c];
    }
    for (int i = tid; i < TN; i += 256) sN[i] = rrb[n0 + t0 + i];
    __syncthreads();
    if (active){
      for (int t = 0; t < TN; t += 4){
        float a0 = 0.f, a1 = 0.f, a2 = 0.f, a3 = 0.f;
        #pragma unroll
        for (int c = 0; c < C; c++){
          float4 rv = *(const float4*)&sRT[c*TN + t];
          float qc = q[c];
          a0 = fmaf(qc, rv.x, a0); a1 = fmaf(qc, rv.y, a1);
          a2 = fmaf(qc, rv.z, a2); a3 = fmaf(qc, rv.w, a3);
        }
        float4 nn = *(const float4*)&sN[t];
        int jb = n0 + t0 + t;
        float d0 = 2.f*a0 - qq - nn.x;
        float d1 = 2.f*a1 - qq - nn.y;
        float d2 = 2.f*a2 - qq - nn.z;
        float d3 = 2.f*a3 - qq - nn.w;
        if constexpr (FIFO){
          if (__any(qcnt >= CAP-4)) drain();    // guarantees room for 4
          if (d0 > tau){ qb[qcnt] = (((u64)__float_as_uint(d0))<<32) | (unsigned)(jb+0); qcnt++; }
          if (d1 > tau){ qb[qcnt] = (((u64)__float_as_uint(d1))<<32) | (unsigned)(jb+1); qcnt++; }
          if (d2 > tau){ qb[qcnt] = (((u64)__float_as_uint(d2))<<32) | (unsigned)(jb+2); qcnt++; }
          if (d3 > tau){ qb[qcnt] = (((u64)__float_as_uint(d3))<<32) | (unsigned)(jb+3); qcnt++; }
        } else {
          topk_ins<K>(bv, bi, d0, jb+0);
          topk_ins<K>(bv, bi, d1, jb+1);
          topk_ins<K>(bv, bi, d2, jb+2);
          topk_ins<K>(bv, bi, d3, jb+3);
        }
      }
    }
    if constexpr (FIFO){ drain(); }             // inactive lanes: qcnt==0, no-op
  }
  if (active){
    float* ov = cval + ((size_t)((size_t)b*M + m)*NC + cid)*K;
    int*   oi = cidx + ((size_t)((size_t)b*M + m)*NC + cid)*K;
    #pragma unroll
    for (int j = 0; j < K; j++){ ov[j] = bv[j]; oi[j] = bi[j]; }
  }
}

// C=64 self-kNN scan (legacy path, kept for N<=256): 1-wave blocks, queries in VGPRs.
template<int K>
__launch_bounds__(64, 2)
__global__ void knn64_kernel(const float* __restrict__ fT, const float* __restrict__ rr,
                             int N, int NC, float* __restrict__ cval, int* __restrict__ cidx){
  int lane = threadIdx.x;
  int q0 = blockIdx.x*64;
  int cid = blockIdx.y, b = blockIdx.z;
  int m = q0 + lane;
  int len = N / NC;
  int n0 = cid*len;
  float4 q4[16];
  {
    const float4* qp = (const float4*)(fT + ((size_t)b*N + m)*64);
    #pragma unroll
    for (int i = 0; i < 16; i++) q4[i] = qp[i];
  }
  float qq = rr[(size_t)b*N + m];   // self-kNN (M==N)
  float bv[K]; int bi[K];
  #pragma unroll
  for (int j = 0; j < K; j++){ bv[j] = NEG_BIG; bi[j] = n0; }
  const float4* rbase = (const float4*)(fT + ((size_t)b*N + n0)*64);
  const float* rrb = rr + (size_t)b*N + n0;
  for (int t0 = 0; t0 < len; t0 += 4){
    const float4* r4 = rbase + (size_t)t0*16;
    float a0=0.f, a1=0.f, a2=0.f, a3=0.f;
    #pragma unroll
    for (int ct = 0; ct < 16; ct++){
      float4 v0 = r4[ct], v1 = r4[16+ct], v2 = r4[32+ct], v3 = r4[48+ct];
      float4 qv = q4[ct];
      a0 = fmaf(qv.x,v0.x,a0); a0 = fmaf(qv.y,v0.y,a0); a0 = fmaf(qv.z,v0.z,a0); a0 = fmaf(qv.w,v0.w,a0);
      a1 = fmaf(qv.x,v1.x,a1); a1 = fmaf(qv.y,v1.y,a1); a1 = fmaf(qv.z,v1.z,a1); a1 = fmaf(qv.w,v1.w,a1);
      a2 = fmaf(qv.x,v2.x,a2); a2 = fmaf(qv.y,v2.y,a2); a2 = fmaf(qv.z,v2.z,a2); a2 = fmaf(qv.w,v2.w,a2);
      a3 = fmaf(qv.x,v3.x,a3); a3 = fmaf(qv.y,v3.y,a3); a3 = fmaf(qv.z,v3.z,a3); a3 = fmaf(qv.w,v3.w,a3);
    }
    topk_ins<K>(bv, bi, 2.f*a0 - qq - rrb[t0+0], n0+t0+0);
    topk_ins<K>(bv, bi, 2.f*a1 - qq - rrb[t0+1], n0+t0+1);
    topk_ins<K>(bv, bi, 2.f*a2 - qq - rrb[t0+2], n0+t0+2);
    topk_ins<K>(bv, bi, 2.f*a3 - qq - rrb[t0+3], n0+t0+3);
  }
  float* ov = cval + ((size_t)((size_t)b*N + m)*NC + cid)*K;
  int*   oi = cidx + ((size_t)((size_t)b*N + m)*NC + cid)*K;
  #pragma unroll
  for (int j = 0; j < K; j++){ ov[j] = bv[j]; oi[j] = bi[j]; }
}

// fp32 -> (hi, lo) bf16 split, stored PRE-SWIZZLED (c ^= (row&7)<<3) so that the
// kNN MFMA kernel can stage LDS tiles with linear copies and read ds_read_b128
// fragments bank-conflict-optimally (G4/T2 recipe).
__global__ void bfsplit_kernel(const float* __restrict__ fT, int N,
                               u16* __restrict__ hi, u16* __restrict__ lo){
  int i = blockIdx.x*256 + threadIdx.x;      // over 4*N*64
  if (i >= 4*N*64) return;
  int c = i & 63;
  int n = i >> 6;                            // combined row b*N + ln; N % 8 == 0 so n&7 == ln&7
  float x = fT[i];
  u16 h = f2bf_rne(x);
  float hf = __uint_as_float((unsigned)h << 16);
  u16 l = f2bf_rne(x - hf);
  size_t o = ((size_t)n << 6) + (c ^ ((n & 7) << 3));
  hi[o] = h; lo[o] = l;
}

// MFMA feature-space self-kNN (C=64).  exact-ish distances via bf16 hi/lo split:
// inner = hi·hi + hi·lo + lo·hi (3x mfma_f32_16x16x32_bf16, fp32 accum, rel err ~2^-17).
// D[ref][query] orientation: lane = (g=l>>4, lm=l&15) holds query (qblk+w*16+lm)'s
// distances for refs {tile + m*16 + 4g + i}.
// Selection: shared float tau (max over 4 partition-lanes of bv[K-1], per-tile
// shfl_xor refresh) gates candidates into a per-thread CAP=8 LDS FIFO (occupancy;
// guard before each m-step drains when near-full; mid-tile drains leave tau valid).
template<int K>
__launch_bounds__(256, 4)
__global__ void knnmf_kernel(const u16* __restrict__ hi, const u16* __restrict__ lo,
                             const float* __restrict__ rr, int N, int NC,
                             float* __restrict__ cval, int* __restrict__ cidx){
  constexpr int CAP = 8;
  __shared__ __align__(16) u16 sHi[64*64];     // 8 KB, swizzled rows
  __shared__ __align__(16) u16 sLo[64*64];     // 8 KB
  __shared__ float sRR[64];
  __shared__ u64 sQ[256*(CAP+1)];              // per-thread 8-entry FIFO, stride 9 (18 KB)

  const int tid  = threadIdx.x;
  const int lane = tid & 63, w = tid >> 6;
  const int g    = lane >> 4;                  // 0..3
  const int lm   = lane & 15;
  const int qblk = blockIdx.x * 64;
  const int cid  = blockIdx.y, b = blockIdx.z;
  const int len  = N / NC, n0 = cid * len;

  const u16*  hib = hi + (size_t)b*N*64;
  const u16*  lob = lo + (size_t)b*N*64;
  const float* rrb = rr + (size_t)b*N;

  // ---- stage this block's 64 query rows, pull B-fragments into registers ----
  {
    const float4* sh = (const float4*)(hib + (size_t)qblk*64);
    const float4* sl = (const float4*)(lob + (size_t)qblk*64);
    float4* dh = (float4*)sHi; float4* dl = (float4*)sLo;
    for (int i = tid; i < 512; i += 256){ dh[i] = sh[i]; dl[i] = sl[i]; }
  }
  __syncthreads();
  const int qrow = w*16 + lm;                  // wave w owns queries qblk + w*16 .. +15
  const int kb0 = 8*g, kb1 = 32 + 8*g;         // frag k-offsets: k = koff + 8*(lane>>4) + i
  const int qsw = (qrow & 7) << 3;
  const bh8 qh0 = *(const bh8*)&sHi[qrow*64 + (kb0 ^ qsw)];
  const bh8 qh1 = *(const bh8*)&sHi[qrow*64 + (kb1 ^ qsw)];
  const bh8 ql0 = *(const bh8*)&sLo[qrow*64 + (kb0 ^ qsw)];
  const bh8 ql1 = *(const bh8*)&sLo[qrow*64 + (kb1 ^ qsw)];
  const float qq = rrb[qblk + qrow];

  float bv[K]; int bi[K];
  #pragma unroll
  for (int j = 0; j < K; j++){ bv[j] = NEG_BIG; bi[j] = n0; }
  float tau = NEG_BIG;                         // shared (4-partition) running K-th value
  u64* qbase = &sQ[tid*(CAP+1)];
  int qcnt = 0;

  // drain FIFOs into the sorted chain; tau NOT touched here (mid-tile safe)
  auto drainq = [&](){
    int k = 0;
    while (__any(k < qcnt)){
      if (k < qcnt){
        u64 e = qbase[k];
        float d = __uint_as_float((unsigned)(e >> 32));
        int j = (int)(unsigned)e;
        topk_ins_t<K,false>(bv, bi, d, j);
      }
      k++;
    }
    qcnt = 0;
  };

  for (int t0 = n0; t0 < n0 + len; t0 += 64){
    __syncthreads();                           // previous tile's frag reads done
    {
      const float4* sh = (const float4*)(hib + (size_t)t0*64);
      const float4* sl = (const float4*)(lob + (size_t)t0*64);
      float4* dh = (float4*)sHi; float4* dl = (float4*)sLo;
      for (int i = tid; i < 512; i += 256){ dh[i] = sh[i]; dl[i] = sl[i]; }
      if (tid < 64) sRR[tid] = rrb[t0 + tid];
    }
    __syncthreads();
    for (int m = 0; m < 4; m++){
      const int rrow = m*16 + lm;              // A-frag row owned by this lane
      const int sw = (rrow & 7) << 3;
      const bh8 ah0 = *(const bh8*)&sHi[rrow*64 + (kb0 ^ sw)];
      const bh8 ah1 = *(const bh8*)&sHi[rrow*64 + (kb1 ^ sw)];
      const bh8 al0 = *(const bh8*)&sLo[rrow*64 + (kb0 ^ sw)];
      const bh8 al1 = *(const bh8*)&sLo[rrow*64 + (kb1 ^ sw)];
      fx4 acc = {0.f, 0.f, 0.f, 0.f};
      acc = __builtin_amdgcn_mfma_f32_16x16x32_bf16(ah0, qh0, acc, 0, 0, 0);
      acc = __builtin_amdgcn_mfma_f32_16x16x32_bf16(ah1, qh1, acc, 0, 0, 0);
      acc = __builtin_amdgcn_mfma_f32_16x16x32_bf16(ah0, ql0, acc, 0, 0, 0);
      acc = __builtin_amdgcn_mfma_f32_16x16x32_bf16(ah1, ql1, acc, 0, 0, 0);
      acc = __builtin_amdgcn_mfma_f32_16x16x32_bf16(al0, qh0, acc, 0, 0, 0);
      acc = __builtin_amdgcn_mfma_f32_16x16x32_bf16(al1, qh1, acc, 0, 0, 0);
      const float4 rr4 = *(const float4*)&sRR[m*16 + 4*g];   // broadcast within 16-lane group
      const float rrv[4] = {rr4.x, rr4.y, rr4.z, rr4.w};
      const int jb = t0 + m*16 + 4*g;          // C/D rows: lane holds rows 4g+i
      if (__any(qcnt >= CAP-4)) drainq();      // guarantees room for 4 pushes
      #pragma unroll
      for (int i = 0; i < 4; i++){
        float d = fmaf(2.f, acc[i], -(qq + rrv[i]));
        if (d >= tau){                         // >= keeps boundary ties (exactness)
          qbase[qcnt] = (((u64)__float_as_uint(d)) << 32) | (unsigned)(jb + i);
          qcnt++;
        }
      }
    }
    // per-tile drain + shared-threshold refresh
    drainq();
    {
      float t = bv[K-1];
      t = fmaxf(t, __shfl_xor(t, 16));
      t = fmaxf(t, __shfl_xor(t, 32));
      tau = t;
    }
  }
  const int q = qblk + qrow;
  const size_t rowo = (((size_t)b*N + q)*(size_t)(NC*4) + (size_t)(cid*4 + g))*(size_t)K;
  float* ov = cval + rowo; int* oi = cidx + rowo;
  #pragma unroll
  for (int j = 0; j < K; j++){ ov[j] = bv[j]; oi[j] = bi[j]; }
}

// 1-thread-per-row merge, kept for K=1 only (T=NC trivial).
template<int K, bool TB>
__global__ void knn_merge_kernel(const float* __restrict__ cval, const int* __restrict__ cidx,
                                 int M, int NC, int* __restrict__ idxo){
  int i = blockIdx.x*256 + threadIdx.x;   // b*M + m
  if (i >= 4*M) return;
  const float* cv = cval + (size_t)i*NC*K;
  const int*   ci = cidx + (size_t)i*NC*K;
  float bv[K]; int bi[K];
  #pragma unroll
  for (int j = 0; j < K; j++){ bv[j] = NEG_BIG; bi[j] = 0; }
  int T = NC*K;
  for (int t = 0; t < T; t++)
    topk_ins_t<K,TB>(bv, bi, cv[t], ci[t]);
  int* orow = idxo + (size_t)i*K;
  #pragma unroll
  for (int j = 0; j < K; j++) orow[j] = bi[j];
}

// Wave-cooperative 16-lane multiway merge of NC (<=16) SORTED-descending chunks.
// r11 lesson: 1-thread-per-row merge at M=1024 ran 16 blocks (0.7% occupancy, 193us).
template<int K>
__global__ void knn_wmerge_kernel(const float* __restrict__ cval, const int* __restrict__ cidx,
                                  int M, int NC, int* __restrict__ idxo){
  int tid = threadIdx.x;
  int j   = tid & 15;                       // lane within 16-lane group
  int row = blockIdx.x*16 + (tid >> 4);     // b*M + m
  if (row >= 4*M) return;                   // whole 16-lane group exits together
  const float* cv = cval + (size_t)row*NC*K;
  const int*   ci = cidx + (size_t)row*NC*K;
  int h = 0;
  u64 key = 0;                              // 0 = exhausted/inactive sentinel
  if (j < NC){
    key = dkey(cv[j*K], ci[j*K]);
    h = 1;
  }
  int* orow = idxo + (size_t)row*K;
  #pragma unroll
  for (int s = 0; s < K; s++){
    u64 m0 = key;
    m0 = maxu64(m0, shfl_xor_u64(m0, 1));
    m0 = maxu64(m0, shfl_xor_u64(m0, 2));
    m0 = maxu64(m0, shfl_xor_u64(m0, 4));
    m0 = maxu64(m0, shfl_xor_u64(m0, 8));
    if (j == 0) orow[s] = key_j(m0);
    if (key == m0 && key != 0){             // unique winner advances its head
      if (h < K){ key = dkey(cv[j*K + h], ci[j*K + h]); h++; }
      else key = 0;
    }
  }
}

// ---------------- edge conv ----------------
__global__ void pq_kernel(const float* __restrict__ xT, int pitch, int C,
                          const float* __restrict__ WaT,
                          float* __restrict__ P, int N){
  int o = threadIdx.x & 63;
  int n = blockIdx.x*4 + (threadIdx.x >> 6);
  int b = blockIdx.y;
  if (n >= N) return;
  const float* row = xT + ((size_t)b*N + n)*pitch;
  float ap = 0.f;
  for (int c = 0; c < C; c++) ap = fmaf(WaT[c*64 + o], row[c], ap);
  P[((size_t)b*N + n)*64 + o] = ap;
}

// 4 points per 256-thread block: shared W1 tile, per-point sH. N % 4 == 0.
__global__ void edge2_kernel(const float* __restrict__ P, const float* __restrict__ featT,
                             int pitch, int C, const float* __restrict__ WqT,
                             const int* __restrict__ idx, const float* __restrict__ W1T,
                             float* __restrict__ outT, int N, int mask){
  __shared__ float sW[64*64];     // [c][o]
  __shared__ float sH[4*20*64];   // [t][kk][c]
  __shared__ float sx[4*64];
  int tid = threadIdx.x;
  int o = tid & 63, t = tid >> 6;
  int n = blockIdx.x*4 + t;
  int b = blockIdx.y;
  const float4* w4 = (const float4*)W1T;
  float4* s4 = (float4*)sW;
  for (int i = tid; i < 1024; i += 256) s4[i] = w4[i];
  if (o < C) sx[t*64 + o] = featT[((size_t)b*N + n)*pitch + o];
  __syncthreads();
  float qv = 0.f;
  for (int c = 0; c < C; c++) qv = fmaf(WqT[c*64 + o], sx[t*64 + c], qv);
  const float* Pb = P + (size_t)b*N*64;
  const int* irow = idx + ((size_t)b*N + n)*20;
  float* sHt = sH + t*1280;
  for (int kk = 0; kk < 20; kk++){
    int j = irow[kk] & mask;
    float h = Pb[(size_t)j*64 + o] + qv;
    sHt[kk*64 + o] = h >= 0.f ? h : 0.2f*h;
  }
  __syncthreads();
  float acc[20];
  #pragma unroll
  for (int kk = 0; kk < 20; kk++) acc[kk] = 0.f;
  for (int c = 0; c < 64; c += 4){
    float w0 = sW[c*64+o], w1 = sW[(c+1)*64+o], w2 = sW[(c+2)*64+o], w3 = sW[(c+3)*64+o];
    #pragma unroll
    for (int kk = 0; kk < 20; kk++){
      float4 h4 = *(const float4*)&sHt[kk*64 + c];
      float a = acc[kk];
      a = fmaf(w0, h4.x, a); a = fmaf(w1, h4.y, a);
      a = fmaf(w2, h4.z, a); a = fmaf(w3, h4.w, a);
      acc[kk] = a;
    }
  }
  float m = NEG_BIG;
  #pragma unroll
  for (int kk = 0; kk < 20; kk++) m = fmaxf(m, acc[kk]);
  outT[((size_t)b*N + n)*64 + o] = lrelu(m);
}

// 4 points per 256-thread block. N % 4 == 0.
__global__ void edge1_kernel(const float* __restrict__ P, const float* __restrict__ featT,
                             int pitch, int C, const float* __restrict__ WqT,
                             const int* __restrict__ idx, float* __restrict__ outT,
                             int N, int K, int mask){
  __shared__ float sx[4*64];
  int tid = threadIdx.x;
  int o = tid & 63, t = tid >> 6;
  int n = blockIdx.x*4 + t;
  int b = blockIdx.y;
  if (o < C) sx[t*64 + o] = featT[((size_t)b*N + n)*pitch + o];
  __syncthreads();
  float qv = 0.f;
  for (int c = 0; c < C; c++) qv = fmaf(WqT[c*64 + o], sx[t*64 + c], qv);
  const float* Pb = P + (size_t)b*N*64;
  const int* irow = idx + ((size_t)b*N + n)*K;
  float m = NEG_BIG;
  for (int kk = 0; kk < K; kk++){
    int j = irow[kk] & mask;
    m = fmaxf(m, Pb[(size_t)j*64 + o] + qv);
  }
  outT[((size_t)b*N + n)*64 + o] = lrelu(m);
}

__global__ void gmax_kernel(const float* __restrict__ inT, const int* __restrict__ idx,
                            float* __restrict__ outT, int Nin, int M, int K, int mask){
  int o = threadIdx.x; int m = blockIdx.x; int b = blockIdx.y;
  const float* ib = inT + (size_t)b*Nin*64;
  const int* irow = idx + ((size_t)b*M + m)*K;
  float v = NEG_BIG;
  for (int kk = 0; kk < K; kk++){
    int j = irow[kk] & mask;
    v = fmaxf(v, ib[(size_t)j*64 + o]);
  }
  outT[((size_t)b*M + m)*64 + o] = v;
}

__global__ void reluadd_kernel(float* __restrict__ x, const float* __restrict__ f, int total){
  int i = blockIdx.x*256 + threadIdx.x;
  if (i >= total) return;
  float v = x[i] + f[i];
  x[i] = v > 0.f ? v : 0.f;
}

// ---------------- global feature path ----------------
// r12 lesson: the per-thread W-row load from the RAW weight (lane stride 256B) was
// wave-uncoalesced -> ~16x line amplification at 4 blocks/CU (FETCH 377MB vs ~20MB
// ideal).  W is now PRE-TRANSPOSED to [c][o] (WT, fp32, sanitized identically via
// wt_kernel -> values bit-identical); wr load becomes lane-contiguous coalesced.
#define PSTRIDE 85
__launch_bounds__(256, 4)
__global__ void pool_kernel(const float* __restrict__ xT, const float* __restrict__ WT,
                            float* __restrict__ partial,
                            int N, int npts, int segbase){
  __shared__ __align__(16) float sX[32*64];   // 8 KB
  int tid = threadIdx.x;
  int ot = blockIdx.x, chunk = blockIdx.y, b = blockIdx.z;
  int o = ot*256 + tid;
  float wr[64];
  #pragma unroll
  for (int c = 0; c < 64; c++) wr[c] = WT[(size_t)c*1024 + o];   // coalesced
  int n0 = chunk * npts;
  float m = NEG_BIG;
  for (int s0 = 0; s0 < npts; s0 += 32){
    __syncthreads();
    const float4* src = (const float4*)(xT + ((size_t)b*N + n0 + s0)*64);
    float4* dst = (float4*)sX;
    for (int i = tid; i < 512; i += 256) dst[i] = src[i];
    __syncthreads();
    for (int t = 0; t < 32; t += 4){
      float a0 = 0.f, a1 = 0.f, a2 = 0.f, a3 = 0.f;
      #pragma unroll
      for (int c4 = 0; c4 < 16; c4++){
        float4 x0 = *(const float4*)&sX[(t+0)*64 + c4*4];
        float4 x1 = *(const float4*)&sX[(t+1)*64 + c4*4];
        float4 x2 = *(const float4*)&sX[(t+2)*64 + c4*4];
        float4 x3 = *(const float4*)&sX[(t+3)*64 + c4*4];
        float w0 = wr[c4*4+0], w1 = wr[c4*4+1], w2 = wr[c4*4+2], w3 = wr[c4*4+3];
        a0 = fmaf(w0, x0.x, a0); a0 = fmaf(w1, x0.y, a0); a0 = fmaf(w2, x0.z, a0); a0 = fmaf(w3, x0.w, a0);
        a1 = fmaf(w0, x1.x, a1); a1 = fmaf(w1, x1.y, a1); a1 = fmaf(w2, x1.z, a1); a1 = fmaf(w3, x1.w, a1);
        a2 = fmaf(w0, x2.x, a2); a2 = fmaf(w1, x2.y, a2); a2 = fmaf(w2, x2.z, a2); a2 = fmaf(w3, x2.w, a2);
        a3 = fmaf(w0, x3.x, a3); a3 = fmaf(w1, x3.y, a3); a3 = fmaf(w2, x3.z, a3); a3 = fmaf(w3, x3.w, a3);
      }
      m = fmaxf(m, fmaxf(fmaxf(a0,a1), fmaxf(a2,a3)));
    }
  }
  partial[((size_t)b*1024 + o)*PSTRIDE + segbase + chunk] = m;
}

__global__ void gred_kernel(const float* __restrict__ partial, float* __restrict__ g, int S){
  int i = blockIdx.x*256 + threadIdx.x;
  if (i >= 4*1024) return;
  const float* p = partial + (size_t)i*PSTRIDE;
  float m = NEG_BIG;
  for (int s = 0; s < S; s++) m = fmaxf(m, p[s]);
  g[i] = lrelu(m);
}

__global__ void gw_kernel(const float* __restrict__ g, const void* __restrict__ W13,
                          const int* __restrict__ dtf, float* __restrict__ gW){
  int o = blockIdx.x, b = blockIdx.y;
  int lane = threadIdx.x;
  int isbf = *dtf;
  const float* gb = g + b*1024;
  float acc = 0.f;
  for (int c = lane; c < 1024; c += 64)
    acc = fmaf(ldx(W13, (size_t)o*1088 + c, isbf), gb[c], acc);
  for (int s = 32; s > 0; s >>= 1) acc += __shfl_down(acc, s, 64);
  if (lane == 0) gW[b*256 + o] = acc;
}

// ---------------- decoder MLPs (fused unpool gather) ----------------
__global__ void mlp_kernel(const float* __restrict__ base,
    const float* __restrict__ in1, const int* __restrict__ idx1, int N1, int C1,
    const float* __restrict__ W1T,
    const float* __restrict__ in2, int C2, const float* __restrict__ W2T,
    float* __restrict__ outT, int N, int Cout){
  __shared__ float sIn[4*320];
  int o = threadIdx.x, b = blockIdx.y;
  int n0 = blockIdx.x*4;
  int Cin = C1 + C2;
  int mask1 = N1 - 1;
  for (int t = 0; t < 4; t++){
    int n = n0 + t;
    int r1 = idx1 ? (idx1[(size_t)b*N + n] & mask1) : n;
    const float* p1 = in1 + ((size_t)b*N1 + r1)*C1;
    for (int c = o; c < C1; c += Cout) sIn[t*Cin + c] = p1[c];
    if (in2){
      const float* p2 = in2 + ((size_t)b*N + n)*C2;
      for (int c = o; c < C2; c += Cout) sIn[t*Cin + C1 + c] = p2[c];
    }
  }
  __syncthreads();
  float init = base ? base[b*Cout + o] : 0.f;
  float a0 = init, a1 = init, a2 = init, a3 = init;
  for (int c = 0; c < C1; c++){
    float wv = W1T[c*Cout + o];
    a0 = fmaf(wv, sIn[0*Cin + c], a0);
    a1 = fmaf(wv, sIn[1*Cin + c], a1);
    a2 = fmaf(wv, sIn[2*Cin + c], a2);
    a3 = fmaf(wv, sIn[3*Cin + c], a3);
  }
  for (int c = 0; c < C2; c++){
    float wv = W2T[c*Cout + o];
    a0 = fmaf(wv, sIn[0*Cin + C1 + c], a0);
    a1 = fmaf(wv, sIn[1*Cin + C1 + c], a1);
    a2 = fmaf(wv, sIn[2*Cin + C1 + c], a2);
    a3 = fmaf(wv, sIn[3*Cin + C1 + c], a3);
  }
  size_t ob = ((size_t)b*N + n0)*Cout + o;
  outT[ob]          = lrelu(a0);
  outT[ob + Cout]   = lrelu(a1);
  outT[ob + 2*Cout] = lrelu(a2);
  outT[ob + 3*Cout] = lrelu(a3);
}

__global__ void dec0_kernel(const float* __restrict__ h1T, const int* __restrict__ idxU0,
                            const float* __restrict__ x0T, const float* __restrict__ W16T,
                            const void* __restrict__ W17, const int* __restrict__ dtf,
                            void* __restrict__ out){
  __shared__ float sIn[4*320];
  __shared__ float sH0[4*128];
  int o = threadIdx.x;   // 128 threads
  int b = blockIdx.y; int n0 = blockIdx.x*4;
  for (int t = 0; t < 4; t++){
    int n = n0 + t;
    int r1 = idxU0[(size_t)b*4096 + n] & 1023;
    const float* p1 = h1T + ((size_t)b*1024 + r1)*256;
    for (int c = o; c < 256; c += 128) sIn[t*320 + c] = p1[c];
    const float* p2 = x0T + ((size_t)b*4096 + n)*64;
    if (o < 64) sIn[t*320 + 256 + o] = p2[o];
  }
  __syncthreads();
  float a0 = 0.f, a1 = 0.f, a2 = 0.f, a3 = 0.f;
  for (int c = 0; c < 256; c++){
    float wv = W16T[c*128 + o];
    a0 = fmaf(wv, sIn[0*320 + c], a0);
    a1 = fmaf(wv, sIn[1*320 + c], a1);
    a2 = fmaf(wv, sIn[2*320 + c], a2);
    a3 = fmaf(wv, sIn[3*320 + c], a3);
  }
  for (int c = 0; c < 64; c++){
    float wv = W16T[(256 + c)*128 + o];
    a0 = fmaf(wv, sIn[0*320 + 256 + c], a0);
    a1 = fmaf(wv, sIn[1*320 + 256 + c], a1);
    a2 = fmaf(wv, sIn[2*320 + 256 + c], a2);
    a3 = fmaf(wv, sIn[3*320 + 256 + c], a3);
  }
  sH0[0*128 + o] = lrelu(a0);
  sH0[1*128 + o] = lrelu(a1);
  sH0[2*128 + o] = lrelu(a2);
  sH0[3*128 + o] = lrelu(a3);
  __syncthreads();
  if (o < 52){
    int isbf = *dtf;
    int p = o / 13, cc = o % 13;
    float acc = 0.f;
    for (int c2 = 0; c2 < 128; c2++)
      acc = fmaf(ldx(W17, (size_t)cc*128 + c2, isbf), sH0[p*128 + c2], acc);
    if (!(acc == acc && fabsf(acc) < 1e30f)) acc = 0.f;
    stout(out, ((size_t)b*13 + cc)*4096 + (n0 + p), acc, isbf);
  }
}

// ---------------- host ----------------
extern "C" void kernel_launch(void* const* d_in, const int* in_sizes, int n_in,
                              void* d_out, int out_size, void* d_ws, size_t ws_size,
                              hipStream_t stream){
  (void)in_sizes; (void)n_in; (void)out_size;
  const int B = 4;
  const void* X       = d_in[0];
  const void* w_ec1_0 = d_in[1];
  const void* w_ec1_1 = d_in[2];
  const void* w_ec2_0 = d_in[3];
  const void* w_ec2_1 = d_in[4];
  const void* w_ec4_0 = d_in[5];
  const void* w_ec4_1 = d_in[6];
  const void* w_ec5_0 = d_in[7];
  const void* w_ec5_1 = d_in[8];
  const void* w_ec7   = d_in[9];
  const void* w_ec8   = d_in[10];
  const void* w_ec10  = d_in[11];
  const void* w_ec11  = d_in[12];
  const void* w_pn3   = d_in[13];
  const void* w_pn6   = d_in[14];
  const void* w_pn9   = d_in[15];
  const void* w_pn12  = d_in[16];
  const void* w_pn13  = d_in[17];
  const void* w_pn14  = d_in[18];
  const void* w_pn15  = d_in[19];
  const void* w_pn16  = d_in[20];
  const void* w_c17   = d_in[21];
  void* out = d_out;

  // ---- workspace layout (fp32 words; lifetime-aliased) ----
  float* wsf = (float*)d_ws;
  size_t off = 0;
  auto alloc = [&](size_t n)->float*{
    float* p = wsf + off; off += (n + 63) & ~(size_t)63; return p;
  };
  int*   dtf = (int*)alloc(64);
  float* xfT = alloc(4*4096*9);
  float* rr  = alloc(4*4096);
  float* partial = alloc(4*1024*85);
  float* g   = alloc(4*1024);
  float* gW  = alloc(4*256);
  int*   idx = (int*)alloc(4*4096*20);
  int*   idxU2 = (int*)alloc(4*256);
  int*   idxU1 = (int*)alloc(4*1024);
  int*   idxU0 = (int*)alloc(4*4096);
  float* ec1a = alloc(9*64);  float* ec1q = alloc(9*64);  float* ec1w1 = alloc(64*64);
  float* ec2a = alloc(64*64); float* ec2q = alloc(64*64); float* ec2w1 = alloc(64*64);
  float* ec4a = alloc(64*64); float* ec4q = alloc(64*64); float* ec4w1 = alloc(64*64);
  float* ec5a = alloc(64*64); float* ec5q = alloc(64*64); float* ec5w1 = alloc(64*64);
  float* ec7a = alloc(64*64); float* ec7q = alloc(64*64);
  float* ec8a = alloc(64*64); float* ec8q = alloc(64*64);
  float* ec10a = alloc(64*64); float* ec10q = alloc(64*64);
  float* ec11a = alloc(64*64); float* ec11q = alloc(64*64);
  float* wp13 = alloc(64*256);
  float* wt14 = alloc(320*256);
  float* wt15 = alloc(320*256);
  float* wt16 = alloc(320*128);
  float* wpl3 = alloc(64*1024);   // pool weights pre-transposed [c][o]
  float* wpl6 = alloc(64*1024);
  float* wpl9 = alloc(64*1024);
  float* wpl12 = alloc(64*1024);
  float* P   = alloc(4*4096*64);
  float* hA  = alloc(4*4096*64);    // decoder: h1T alias (exact size)
  float* x0T = alloc(4*4096*64);
  float* x1T = alloc(4*1024*64);
  float* x2T = alloc(4*256*64);
  float* x3T = alloc(4*64*64);
  float* n1f = alloc(4*1024*64);    // decoder: h3T + head of h2T
  float* n2f = alloc(4*256*64);     // contiguous after n1f; h2T tail
  float* n3f = alloc(4*64*64);
  u16*   bhi = (u16*)alloc(4*4096*64/2);   // bf16 hi split (pre-swizzled), 2 MB
  u16*   blo = (u16*)alloc(4*4096*64/2);   // bf16 lo split (pre-swizzled), 2 MB
  float* h1T = hA;
  float* h3T = n1f;
  float* h2T = n1f + 65536;

  // ws-aware candidate sizing (ws_size constant across calls)
  size_t rem = (ws_size/4 > off + 256) ? (ws_size/4 - off - 256) : 0;
  size_t half = rem / 2;
  int NCbig = (half >= (size_t)4*4096*16*20) ? 16 :
              (half >= (size_t)4*4096*8*20)  ? 8  : 4;
  size_t E = (size_t)4*4096*20*NCbig;
  float* cval = alloc(E);
  int*   cidx = (int*)alloc(E);

  detect_kernel<<<dim3(1), 256, 0, stream>>>((const unsigned int*)X, dtf);

  // ---- weight prep ----
  w0_kernel<<<dim3(3), 256, 0, stream>>>(w_ec1_0, dtf, 9, ec1a, ec1q);
  w0_kernel<<<dim3(16), 256, 0, stream>>>(w_ec2_0, dtf, 64, ec2a, ec2q);
  w0_kernel<<<dim3(16), 256, 0, stream>>>(w_ec4_0, dtf, 64, ec4a, ec4q);
  w0_kernel<<<dim3(16), 256, 0, stream>>>(w_ec5_0, dtf, 64, ec5a, ec5q);
  w0_kernel<<<dim3(16), 256, 0, stream>>>(w_ec7, dtf, 64, ec7a, ec7q);
  w0_kernel<<<dim3(16), 256, 0, stream>>>(w_ec8, dtf, 64, ec8a, ec8q);
  w0_kernel<<<dim3(16), 256, 0, stream>>>(w_ec10, dtf, 64, ec10a, ec10q);
  w0_kernel<<<dim3(16), 256, 0, stream>>>(w_ec11, dtf, 64, ec11a, ec11q);
  wt_kernel<<<dim3(16), 256, 0, stream>>>(w_ec1_1, dtf, 64, 64, 0, 64, ec1w1);
  wt_kernel<<<dim3(16), 256, 0, stream>>>(w_ec2_1, dtf, 64, 64, 0, 64, ec2w1);
  wt_kernel<<<dim3(16), 256, 0, stream>>>(w_ec4_1, dtf, 64, 64, 0, 64, ec4w1);
  wt_kernel<<<dim3(16), 256, 0, stream>>>(w_ec5_1, dtf, 64, 64, 0, 64, ec5w1);
  wt_kernel<<<dim3(64), 256, 0, stream>>>(w_pn13, dtf, 256, 1088, 1024, 64, wp13);
  wt_kernel<<<dim3(320), 256, 0, stream>>>(w_pn14, dtf, 256, 320, 0, 320, wt14);
  wt_kernel<<<dim3(320), 256, 0, stream>>>(w_pn15, dtf, 256, 320, 0, 320, wt15);
  wt_kernel<<<dim3(160), 256, 0, stream>>>(w_pn16, dtf, 128, 320, 0, 320, wt16);
  wt_kernel<<<dim3(256), 256, 0, stream>>>(w_pn3, dtf, 1024, 64, 0, 64, wpl3);
  wt_kernel<<<dim3(256), 256, 0, stream>>>(w_pn6, dtf, 1024, 64, 0, 64, wpl6);
  wt_kernel<<<dim3(256), 256, 0, stream>>>(w_pn9, dtf, 1024, 64, 0, 64, wpl9);
  wt_kernel<<<dim3(256), 256, 0, stream>>>(w_pn12, dtf, 1024, 64, 0, 64, wpl12);

  xconv_kernel<<<dim3(64), 256, 0, stream>>>(X, dtf, xfT);
  nodecopy_kernel<<<dim3(64), 256, 0, stream>>>(X, dtf, out);

  const size_t xbs = (size_t)4096*9;
  // coord-space kNN on xfT (pitch 9). len=N/NC must be multiple of 64.
  auto knn_f = [&](int C, int K, int M, int N, int NC, int* io){
    rownorm_kernel<<<dim3((N+255)/256, B), 256, 0, stream>>>(xfT, 9, xbs, C, N, rr);
    dim3 gd((M+255)/256, NC, B);
    if (C == 9)      knn_chunk_kernel<9,20,64><<<gd,256,0,stream>>>(xfT,9,xbs,xfT,9,xbs,rr,M,N,NC,cval,cidx);
    else if (K==20)  knn_chunk_kernel<3,20,64><<<gd,256,0,stream>>>(xfT,9,xbs,xfT,9,xbs,rr,M,N,NC,cval,cidx);
    else             knn_chunk_kernel<3,1,64><<<gd,256,0,stream>>>(xfT,9,xbs,xfT,9,xbs,rr,M,N,NC,cval,cidx);
    if (K == 20)     knn_wmerge_kernel<20><<<dim3((4*M+15)/16), 256, 0, stream>>>(cval,cidx,M,NC,io);
    else             knn_merge_kernel<1,false><<<dim3((4*M+255)/256), 256, 0, stream>>>(cval,cidx,M,NC,io);
  };
  // feature-space self-kNN (C=64).
  auto knn_b = [&](int K, const float* fT, int N, int NC, int* io){
    rownorm_kernel<<<dim3((N+255)/256, B), 256, 0, stream>>>(fT, 64, (size_t)N*64, 64, N, rr);
    if (K == 20 && N >= 1024){
      int NCm = NCbig / 4; if (NCm < 1) NCm = 1;     // NC*4 virtual chunks must fit cval
      int cap = (N == 4096) ? 2 : 4;
      if (NCm > cap) NCm = cap;
      bfsplit_kernel<<<dim3((4*N*64)/256), 256, 0, stream>>>(fT, N, bhi, blo);
      knnmf_kernel<20><<<dim3(N/64, NCm, B), 256, 0, stream>>>(bhi, blo, rr, N, NCm, cval, cidx);
      knn_wmerge_kernel<20><<<dim3((4*N+15)/16), 256, 0, stream>>>(cval, cidx, N, NCm*4, io);
    } else {
      dim3 gd(N/64, NC, B);
      if (K == 20) knn64_kernel<20><<<gd,64,0,stream>>>(fT, rr, N, NC, cval, cidx);
      else         knn64_kernel<10><<<gd,64,0,stream>>>(fT, rr, N, NC, cval, cidx);
      dim3 gm((4*N+15)/16);
      if (K == 20) knn_wmerge_kernel<20><<<gm,256,0,stream>>>(cval,cidx,N,NC,io);
      else         knn_wmerge_kernel<10><<<gm,256,0,stream>>>(cval,cidx,N,NC,io);
    }
  };
  auto edge2_b = [&](const float* fT, int N, int NC, float* wa, float* wq, float* w1, float* oT){
    knn_b(20, fT, N, NC, idx);
    pq_kernel<<<dim3((N+3)/4, B), 256, 0, stream>>>(fT, 64, 64, wa, P, N);
    edge2_kernel<<<dim3(N/4, B), 256, 0, stream>>>(P, fT, 64, 64, wq, idx, w1, oT, N, N-1);
  };
  auto edge1_b = [&](const float* fT, int N, int NC, int K, float* wa, float* wq, float* oT){
    knn_b(K, fT, N, NC, idx);
    pq_kernel<<<dim3((N+3)/4, B), 256, 0, stream>>>(fT, 64, 64, wa, P, N);
    edge1_kernel<<<dim3(N/4, B), 256, 0, stream>>>(P, fT, 64, 64, wq, idx, oT, N, K, N-1);
  };

  // level 0
  int nc9 = (NCbig < 8) ? NCbig : 8;                     // len 512
  knn_f(9, 20, 4096, 4096, nc9, idx);
  pq_kernel<<<dim3(1024, B), 256, 0, stream>>>(xfT, 9, 9, ec1a, P, 4096);
  edge2_kernel<<<dim3(1024, B), 256, 0, stream>>>(P, xfT, 9, 9, ec1q, idx, ec1w1, hA, 4096, 4095);
  edge2_b(hA, 4096, NCbig, ec2a, ec2q, ec2w1, x0T);
  pool_kernel<<<dim3(4,64,4), 256, 0, stream>>>(x0T, wpl3, partial, 4096, 64, 0);
  // rand_pool 1
  knn_f(3, 20, 1024, 4096, 16, idx);                     // len 256
  gmax_kernel<<<dim3(1024, B), 64, 0, stream>>>(x0T, idx, n1f, 4096, 1024, 20, 4095);
  // level 1
  edge2_b(n1f, 1024, 16, ec4a, ec4q, ec4w1, hA);
  edge2_b(hA, 1024, 16, ec5a, ec5q, ec5w1, x1T);
  pool_kernel<<<dim3(4,16,4), 256, 0, stream>>>(x1T, wpl6, partial, 1024, 64, 64);
  reluadd_kernel<<<dim3(1024), 256, 0, stream>>>(x1T, n1f, 4*1024*64);
  // rand_pool 2
  knn_f(3, 20, 256, 1024, 16, idx);                      // len 64
  gmax_kernel<<<dim3(256, B), 64, 0, stream>>>(x1T, idx, n2f, 1024, 256, 20, 1023);
  // level 2
  edge1_b(n2f, 256, 16, 20, ec7a, ec7q, hA);             // len 16
  edge1_b(hA, 256, 16, 20, ec8a, ec8q, x2T);
  pool_kernel<<<dim3(4,4,4), 256, 0, stream>>>(x2T, wpl9, partial, 256, 64, 80);
  reluadd_kernel<<<dim3(256), 256, 0, stream>>>(x2T, n2f, 4*256*64);
  // rand_pool 3
  knn_f(3, 20, 64, 256, 4, idx);                         // len 64 (chunk TN bound)
  gmax_kernel<<<dim3(64, B), 64, 0, stream>>>(x2T, idx, n3f, 256, 64, 20, 255);
  // level 3
  edge1_b(n3f, 64, 8, 10, ec10a, ec10q, hA);             // len 8
  edge1_b(hA, 64, 8, 10, ec11a, ec11q, x3T);
  pool_kernel<<<dim3(4,1,4), 256, 0, stream>>>(x3T, wpl12, partial, 64, 64, 84);
  reluadd_kernel<<<dim3(64), 256, 0, stream>>>(x3T, n3f, 4*64*64);
  // ---- idx, P, hA, n1f, n2f dead -> h3T/h2T/h1T aliases live ----
  gred_kernel<<<dim3(16), 256, 0, stream>>>(partial, g, 85);
  gw_kernel<<<dim3(256, 4), 64, 0, stream>>>(g, w_pn13, dtf, gW);
  mlp_kernel<<<dim3(16, B), 256, 0, stream>>>(gW, x3T, nullptr, 64, 64, wp13,
                                              nullptr, 0, nullptr, h3T, 64, 256);
  knn_f(3, 1, 256, 64, 1, idxU2);                        // len 64
  mlp_kernel<<<dim3(64, B), 256, 0, stream>>>(nullptr, h3T, idxU2, 64, 256, wt14,
                                              x2T, 64, wt14 + 256*256, h2T, 256, 256);
  knn_f(3, 1, 1024, 256, 4, idxU1);                      // len 64
  mlp_kernel<<<dim3(256, B), 256, 0, stream>>>(nullptr, h2T, idxU1, 256, 256, wt15,
                                               x1T, 64, wt15 + 256*256, h1T, 1024, 256);
  knn_f(3, 1, 4096, 1024, 4, idxU0);                     // len 256
  dec0_kernel<<<dim3(1024, B), 128, 0, stream>>>(h1T, idxU0, x0T, wt16, w_c17, dtf, out);
}